// Round 7
// baseline (475.250 us; speedup 1.0000x reference)
//
#include <hip/hip_runtime.h>

#define DIV_UP(a,b) (((a)+(b)-1)/(b))

typedef float f4v __attribute__((ext_vector_type(4)));

// bucket = tgt >> 7  (128 nodes per bucket)
constexpr int BSHIFT = 7;
constexpr int BNODES = 128;
constexpr int CHUNK_E = 16384;   // edges per partition block (measured best: round 5)

// ---------------- CSR build via bucket counting sort ----------------
__global__ void zero_int_k(int* p, int n) {
    int i = blockIdx.x * blockDim.x + threadIdx.x;
    if (i < n) p[i] = 0;
}

__global__ void bucket_hist_k(const int* __restrict__ col, int* __restrict__ bhist, int E, int nb) {
    __shared__ int lh[1024];
    for (int i = threadIdx.x; i < 1024; i += blockDim.x) lh[i] = 0;
    __syncthreads();
    int stride = gridDim.x * blockDim.x;
    for (int e = blockIdx.x * blockDim.x + threadIdx.x; e < E; e += stride)
        atomicAdd(&lh[col[e] >> BSHIFT], 1);
    __syncthreads();
    for (int i = threadIdx.x; i < nb; i += blockDim.x) {
        int v = lh[i];
        if (v) atomicAdd(&bhist[i], v);
    }
}

// exclusive scan of nb (<=1024) bucket counts -> bcur
__global__ void bucket_scan_k(const int* __restrict__ bhist, int* __restrict__ bcur, int nb) {
    __shared__ int lds[256];
    int base = threadIdx.x * 4;
    int v[4]; int s = 0;
#pragma unroll
    for (int j = 0; j < 4; j++) { v[j] = (base + j < nb) ? bhist[base + j] : 0; s += v[j]; }
    lds[threadIdx.x] = s; __syncthreads();
    for (int off = 1; off < 256; off <<= 1) {
        int t = (threadIdx.x >= off) ? lds[threadIdx.x - off] : 0;
        __syncthreads();
        lds[threadIdx.x] += t;
        __syncthreads();
    }
    int excl = lds[threadIdx.x] - s;
#pragma unroll
    for (int j = 0; j < 4; j++) {
        if (base + j < nb) bcur[base + j] = excl;
        excl += v[j];
    }
}

// block-batched partition: LDS histogram -> bulk range reservation -> LDS-cursor scatter
__global__ void partition_k(const int* __restrict__ row, const int* __restrict__ col,
                            int* __restrict__ bcur, int* __restrict__ part, int E, int nb) {
    __shared__ int lh[1024];
    for (int i = threadIdx.x; i < nb; i += blockDim.x) lh[i] = 0;
    __syncthreads();
    int base = blockIdx.x * CHUNK_E;
    int end = min(E, base + CHUNK_E);
    for (int e = base + threadIdx.x; e < end; e += blockDim.x)
        atomicAdd(&lh[col[e] >> BSHIFT], 1);
    __syncthreads();
    for (int i = threadIdx.x; i < nb; i += blockDim.x) {
        int c = lh[i];
        lh[i] = c ? atomicAdd(&bcur[i], c) : 0;
    }
    __syncthreads();
    for (int e = base + threadIdx.x; e < end; e += blockDim.x) {
        int r = row[e], c = col[e];
        int p = atomicAdd(&lh[c >> BSHIFT], 1);
        part[p] = (r << BSHIFT) | (c & (BNODES - 1));
    }
}

// one block per bucket: count local degrees, scan, emit dinv/cur, scatter csr
__global__ void csr_build_k(const int* __restrict__ part, const int* __restrict__ bcur,
                            int* __restrict__ cur, float* __restrict__ dinv,
                            int* __restrict__ csr, int N) {
    __shared__ int ldeg[BNODES];
    __shared__ int lofs[BNODES];
    __shared__ int ebounds[2];
    int b = blockIdx.x;
    int tid = threadIdx.x;
    if (tid == 0) { ebounds[0] = b ? bcur[b - 1] : 0; ebounds[1] = bcur[b]; }
    if (tid < BNODES) ldeg[tid] = 0;
    __syncthreads();
    int e0 = ebounds[0], e1 = ebounds[1];
    for (int e = e0 + tid; e < e1; e += blockDim.x)
        atomicAdd(&ldeg[part[e] & (BNODES - 1)], 1);
    __syncthreads();
    if (tid < BNODES) lofs[tid] = ldeg[tid];
    __syncthreads();
    for (int off = 1; off < BNODES; off <<= 1) {
        int t = (tid >= off && tid < BNODES) ? lofs[tid - off] : 0;
        __syncthreads();
        if (tid < BNODES) lofs[tid] += t;
        __syncthreads();
    }
    if (tid < BNODES) {
        int node = b * BNODES + tid;
        int d = ldeg[tid];
        int incl = lofs[tid];
        if (node < N) {
            cur[node] = e0 + incl;
            dinv[node] = rsqrtf(1.0f + (float)d);
        }
        ldeg[tid] = e0 + incl - d;
    }
    __syncthreads();
    for (int e = e0 + tid; e < e1; e += blockDim.x) {
        int v = part[e];
        int p = atomicAdd(&ldeg[v & (BNODES - 1)], 1);
        csr[p] = v >> BSHIFT;
    }
}

// ---------------- sliced gather: layout [NS][n][8], one dispatch per slice s ----------
// out_raw = dinv * (self + sum src).  EPI 0: store raw.  EPI 1: relu(raw+b)*dinv.
// 2 threads per node (half = 16B each); nt-store output to preserve L2 residency of input.
template<int EPI>
__global__ void __launch_bounds__(256) gather_slice_k(
        const float* __restrict__ hs, const float* __restrict__ dinv,
        const int* __restrict__ cur, const int* __restrict__ csr,
        const float* __restrict__ b, float* __restrict__ out, int n, int s) {
    int t2 = blockIdx.x * 256 + threadIdx.x;
    int node = t2 >> 1, half = t2 & 1;
    if (node >= n) return;
    const float* sb = hs + (size_t)s * n * 8 + half * 4;   // slice base (+half)
    float di = dinv[node];
    float4 acc = *reinterpret_cast<const float4*>(sb + (size_t)node * 8);
    int e0 = node ? cur[node - 1] : 0;
    int e1 = cur[node];
    int e = e0;
    for (; e + 1 < e1; e += 2) {
        int s0 = csr[e], s1 = csr[e + 1];
        float4 v0 = *reinterpret_cast<const float4*>(sb + (size_t)s0 * 8);
        float4 v1 = *reinterpret_cast<const float4*>(sb + (size_t)s1 * 8);
        acc.x += v0.x + v1.x; acc.y += v0.y + v1.y;
        acc.z += v0.z + v1.z; acc.w += v0.w + v1.w;
    }
    if (e < e1) {
        int s0 = csr[e];
        float4 v0 = *reinterpret_cast<const float4*>(sb + (size_t)s0 * 8);
        acc.x += v0.x; acc.y += v0.y; acc.z += v0.z; acc.w += v0.w;
    }
    acc.x *= di; acc.y *= di; acc.z *= di; acc.w *= di;
    if (EPI == 1) {
        int bo = s * 8 + half * 4;
        acc.x = fmaxf(acc.x + b[bo + 0], 0.f) * di;
        acc.y = fmaxf(acc.y + b[bo + 1], 0.f) * di;
        acc.z = fmaxf(acc.z + b[bo + 2], 0.f) * di;
        acc.w = fmaxf(acc.w + b[bo + 3], 0.f) * di;
    }
    f4v vv = {acc.x, acc.y, acc.z, acc.w};
    float* op = out + (size_t)s * n * 8 + (size_t)node * 8 + half * 4;
    __builtin_nontemporal_store(vv, reinterpret_cast<f4v*>(op));
}

// ---------------- plain gather for D=4 (normal layout) ----------------
__global__ void gather4_k(const float* __restrict__ hs, const float* __restrict__ dinv,
                          const int* __restrict__ cur, const int* __restrict__ csr,
                          float* __restrict__ out, int n) {
    int node = blockIdx.x * blockDim.x + threadIdx.x;
    if (node >= n) return;
    float di = dinv[node];
    float4 acc = reinterpret_cast<const float4*>(hs)[node];
    int e0 = node ? cur[node - 1] : 0;
    int e1 = cur[node];
    int e = e0;
    for (; e + 1 < e1; e += 2) {
        int s0 = csr[e], s1 = csr[e + 1];
        float4 v0 = reinterpret_cast<const float4*>(hs)[s0];
        float4 v1 = reinterpret_cast<const float4*>(hs)[s1];
        acc.x += v0.x + v1.x; acc.y += v0.y + v1.y;
        acc.z += v0.z + v1.z; acc.w += v0.w + v1.w;
    }
    if (e < e1) {
        float4 v0 = reinterpret_cast<const float4*>(hs)[csr[e]];
        acc.x += v0.x; acc.y += v0.y; acc.z += v0.z; acc.w += v0.w;
    }
    acc.x *= di; acc.y *= di; acc.z *= di; acc.w *= di;
    reinterpret_cast<float4*>(out)[node] = acc;
}

// ---------------- LDS-tiled skinny matmul, sliced-layout aware ----------------
// SLIN/SLOUT: 0 = row-major [n][D]; 1 = sliced [D/8][n][8]
template<int IN, int OUT, bool RELU, bool BIAS, bool SCALE, int SLIN, int SLOUT>
__global__ void __launch_bounds__(256) matmul_k(
        const float* __restrict__ x, const float* __restrict__ W,
        const float* __restrict__ b, const float* __restrict__ dinv,
        float* __restrict__ y, int n) {
    constexpr int TN  = 64;
    constexpr int RS  = IN + 4;
    constexpr int OPT = OUT / 4;
    constexpr int NQ  = IN / 4;
    __shared__ float xs[TN * RS];
    __shared__ float Ws[IN * OUT];
    __shared__ float bs[OUT];

    for (int i = threadIdx.x; i < IN * OUT; i += 256) Ws[i] = W[i];
    if (BIAS) for (int i = threadIdx.x; i < OUT; i += 256) bs[i] = b[i];

    int base = blockIdx.x * TN;
    for (int i = threadIdx.x; i < TN * NQ; i += 256) {
        int r = i / NQ, c4 = i % NQ;
        float4 v = make_float4(0.f, 0.f, 0.f, 0.f);
        if (base + r < n) {
            const float* src;
            if (SLIN) src = x + ((size_t)(c4 >> 1) * n + base + r) * 8 + (c4 & 1) * 4;
            else      src = x + (size_t)(base + r) * IN + c4 * 4;
            v = *reinterpret_cast<const float4*>(src);
        }
        *reinterpret_cast<float4*>(&xs[r * RS + c4 * 4]) = v;
    }
    __syncthreads();

    int node = threadIdx.x >> 2;
    int g    = threadIdx.x & 3;
    int j0   = g * OPT;
    int gnode = base + node;
    if (gnode >= n) return;

    float acc[OPT];
#pragma unroll
    for (int jj = 0; jj < OPT; jj++) acc[jj] = 0.f;

    const float* xrow = &xs[node * RS];
#pragma unroll
    for (int k4 = 0; k4 < NQ; k4++) {
        float4 xv = *reinterpret_cast<const float4*>(&xrow[k4 * 4]);
        float xk[4] = {xv.x, xv.y, xv.z, xv.w};
#pragma unroll
        for (int kk = 0; kk < 4; kk++) {
            const float* wrow = &Ws[(k4 * 4 + kk) * OUT + j0];
#pragma unroll
            for (int jj = 0; jj < OPT; jj++)
                acc[jj] += xk[kk] * wrow[jj];
        }
    }

    float di = SCALE ? dinv[gnode] : 1.f;
    float vout[OPT];
#pragma unroll
    for (int jj = 0; jj < OPT; jj++) {
        float v = acc[jj] + (BIAS ? bs[j0 + jj] : 0.f);
        if (RELU) v = fmaxf(v, 0.f);
        if (SCALE) v *= di;
        vout[jj] = v;
    }
    if (OPT % 4 == 0) {
#pragma unroll
        for (int q = 0; q < OPT / 4; q++) {
            int jj = j0 + q * 4;
            float* p;
            if (SLOUT) p = y + ((size_t)(jj >> 3) * n + gnode) * 8 + (jj & 7);
            else       p = y + (size_t)gnode * OUT + jj;
            *reinterpret_cast<float4*>(p) =
                make_float4(vout[q*4+0], vout[q*4+1], vout[q*4+2], vout[q*4+3]);
        }
    } else {
#pragma unroll
        for (int jj = 0; jj < OPT; jj++) y[(size_t)gnode * OUT + j0 + jj] = vout[jj];
    }
}

// ---------------- pooling + log_softmax ----------------
__device__ inline unsigned fkey(float x) {
    unsigned u = __float_as_uint(x);
    return (u & 0x80000000u) ? ~u : (u | 0x80000000u);
}
__device__ inline float funkey(unsigned k) {
    unsigned u = (k & 0x80000000u) ? (k & 0x7FFFFFFFu) : ~k;
    return __uint_as_float(u);
}

__global__ void pool_init_k(unsigned* pooled, int total) {
    int i = blockIdx.x * blockDim.x + threadIdx.x;
    if (i < total) pooled[i] = 0u;
}

__global__ void pool_max_k(const float* __restrict__ h4, const float* __restrict__ b4,
                           const int* __restrict__ batch, unsigned* __restrict__ pooled,
                           int n, int num_graphs) {
    __shared__ unsigned lds[128 * 4];
    for (int i = threadIdx.x; i < num_graphs * 4; i += blockDim.x) lds[i] = 0u;
    __syncthreads();
    int i = blockIdx.x * blockDim.x + threadIdx.x;
    if (i < n) {
        int g = batch[i];
        float4 v = reinterpret_cast<const float4*>(h4)[i];
        atomicMax(&lds[g*4+0], fkey(v.x + b4[0]));
        atomicMax(&lds[g*4+1], fkey(v.y + b4[1]));
        atomicMax(&lds[g*4+2], fkey(v.z + b4[2]));
        atomicMax(&lds[g*4+3], fkey(v.w + b4[3]));
    }
    __syncthreads();
    for (int i2 = threadIdx.x; i2 < num_graphs * 4; i2 += blockDim.x) {
        unsigned k = lds[i2];
        if (k) atomicMax(&pooled[i2], k);
    }
}

__global__ void logsoftmax_k(const unsigned* __restrict__ pooled, float* __restrict__ out, int G) {
    int g = blockIdx.x * blockDim.x + threadIdx.x;
    if (g >= G) return;
    float v[4];
#pragma unroll
    for (int j = 0; j < 4; j++) v[j] = funkey(pooled[g*4+j]);
    float m = fmaxf(fmaxf(v[0], v[1]), fmaxf(v[2], v[3]));
    float s = 0.f;
#pragma unroll
    for (int j = 0; j < 4; j++) s += expf(v[j] - m);
    float l = logf(s);
#pragma unroll
    for (int j = 0; j < 4; j++) out[g*4+j] = v[j] - m - l;
}

// ---------------- launch ----------------
extern "C" void kernel_launch(void* const* d_in, const int* in_sizes, int n_in,
                              void* d_out, int out_size, void* d_ws, size_t ws_size,
                              hipStream_t stream) {
    const float* x     = (const float*)d_in[0];
    const int*   ei    = (const int*)d_in[1];
    const int*   batch = (const int*)d_in[2];
    const float* W1 = (const float*)d_in[3];
    const float* b1 = (const float*)d_in[4];
    const float* W2 = (const float*)d_in[5];
    const float* b2 = (const float*)d_in[6];
    const float* W3 = (const float*)d_in[7];
    const float* b3 = (const float*)d_in[8];
    const float* W4 = (const float*)d_in[9];
    const float* b4 = (const float*)d_in[10];

    const int N = in_sizes[2];          // 100000
    const int E = in_sizes[1] / 2;      // 3.2M
    const int G = 128;
    const int* row = ei;
    const int* col = ei + E;
    const int NB = DIV_UP(N, BNODES);   // 782 buckets

    // workspace layout
    float* ws    = (float*)d_ws;
    float* dinv  = ws;                              // N floats
    int*   cur   = (int*)(dinv + N);                // N ints (inclusive seg ends)
    int*   bhist = cur + N;                         // 1024 ints
    int*   bcur  = bhist + 1024;                    // 1024 ints
    int*   csr   = bcur + 1024;                     // E ints
    float* f16a  = (float*)(csr + E);               // N*16
    float* f16b  = f16a + (size_t)N * 16;           // N*16
    float* f32a  = f16b + (size_t)N * 16;           // N*32
    float* f32b  = f32a + (size_t)N * 32;           // N*32
    unsigned* pooled = (unsigned*)(f32b + (size_t)N * 32);  // 512
    int* part = (int*)f32a;                         // alias, dead before f32a use
    float* f64 = f16a;                              // N*64 spans f16a..f32a end
    float* f4a = f32b;                              // after L3 matmul, f32b free
    float* f4b = f32b + (size_t)N * 4;

    const int B = 256;
    const int gridN = DIV_UP(N, B);
    const int gridM = DIV_UP(N, 64);    // tiled matmul: 64 nodes/block
    const int gridS = DIV_UP(2 * N, B); // sliced gather: 2 threads/node

    // CSR build
    zero_int_k<<<DIV_UP(1024, B), B, 0, stream>>>(bhist, 1024);
    bucket_hist_k<<<512, B, 0, stream>>>(col, bhist, E, NB);
    bucket_scan_k<<<1, 256, 0, stream>>>(bhist, bcur, NB);
    partition_k<<<DIV_UP(E, CHUNK_E), B, 0, stream>>>(row, col, bcur, part, E, NB);
    csr_build_k<<<NB, B, 0, stream>>>(part, bcur, cur, dinv, csr, N);

    // L1: y1s = (x@W1)*dinv -> f16b [sliced 2] ; gather+bias+relu+scale -> f16a [sliced 2]
    matmul_k<128,16,false,false,true,0,1><<<gridM, B, 0, stream>>>(x, W1, nullptr, dinv, f16b, N);
    for (int s = 0; s < 2; s++)
        gather_slice_k<1><<<gridS, B, 0, stream>>>(f16b, dinv, cur, csr, b1, f16a, N, s);

    // L2: gather f16a -> f16b [sliced 2] ; matmul 16->32 +b2,relu,*dinv -> f32a [sliced 4]
    for (int s = 0; s < 2; s++)
        gather_slice_k<0><<<gridS, B, 0, stream>>>(f16a, dinv, cur, csr, nullptr, f16b, N, s);
    matmul_k<16,32,true,true,true,1,1><<<gridM, B, 0, stream>>>(f16b, W2, b2, dinv, f32a, N);

    // L3: gather f32a -> f32b [sliced 4] ; matmul 32->64 +b3,relu,*dinv -> f64 [normal]
    for (int s = 0; s < 4; s++)
        gather_slice_k<0><<<gridS, B, 0, stream>>>(f32a, dinv, cur, csr, nullptr, f32b, N, s);
    matmul_k<32,64,true,true,true,1,0><<<gridM, B, 0, stream>>>(f32b, W3, b3, dinv, f64, N);

    // L4: y4 = h3s@W4 -> f4a [normal] ; gather raw -> f4b
    matmul_k<64,4,false,false,false,0,0><<<gridM, B, 0, stream>>>(f64, W4, nullptr, nullptr, f4a, N);
    gather4_k<<<gridN, B, 0, stream>>>(f4a, dinv, cur, csr, f4b, N);

    // pool (adds b4) + log_softmax
    pool_init_k<<<DIV_UP(G*4, B), B, 0, stream>>>(pooled, G*4);
    pool_max_k<<<gridN, B, 0, stream>>>(f4b, b4, batch, pooled, N, G);
    logsoftmax_k<<<1, 128, 0, stream>>>(pooled, (float*)d_out, G);
}

// Round 8
// 325.131 us; speedup vs baseline: 1.4617x; 1.4617x over previous
//
#include <hip/hip_runtime.h>

#define DIV_UP(a,b) (((a)+(b)-1)/(b))

// bucket = tgt >> 7  (128 nodes per bucket)
constexpr int BSHIFT = 7;
constexpr int BNODES = 128;
constexpr int CHUNK_E = 16384;   // edges per partition block
constexpr int PTH = 512;         // partition block threads

// ---------------- CSR build via bucket counting sort ----------------
__global__ void zero_int_k(int* p, int n) {
    int i = blockIdx.x * blockDim.x + threadIdx.x;
    if (i < n) p[i] = 0;
}

__global__ void bucket_hist_k(const int* __restrict__ col, int* __restrict__ bhist, int E, int nb) {
    __shared__ int lh[1024];
    for (int i = threadIdx.x; i < 1024; i += blockDim.x) lh[i] = 0;
    __syncthreads();
    int stride = gridDim.x * blockDim.x;
    for (int e = blockIdx.x * blockDim.x + threadIdx.x; e < E; e += stride)
        atomicAdd(&lh[col[e] >> BSHIFT], 1);
    __syncthreads();
    for (int i = threadIdx.x; i < nb; i += blockDim.x) {
        int v = lh[i];
        if (v) atomicAdd(&bhist[i], v);
    }
}

// exclusive scan of nb (<=1024) bucket counts -> bcur
__global__ void bucket_scan_k(const int* __restrict__ bhist, int* __restrict__ bcur, int nb) {
    __shared__ int lds[256];
    int base = threadIdx.x * 4;
    int v[4]; int s = 0;
#pragma unroll
    for (int j = 0; j < 4; j++) { v[j] = (base + j < nb) ? bhist[base + j] : 0; s += v[j]; }
    lds[threadIdx.x] = s; __syncthreads();
    for (int off = 1; off < 256; off <<= 1) {
        int t = (threadIdx.x >= off) ? lds[threadIdx.x - off] : 0;
        __syncthreads();
        lds[threadIdx.x] += t;
        __syncthreads();
    }
    int excl = lds[threadIdx.x] - s;
#pragma unroll
    for (int j = 0; j < 4; j++) {
        if (base + j < nb) bcur[base + j] = excl;
        excl += v[j];
    }
}

// LDS-ranked partition (counting-sort pass): hist -> local scan -> bulk reserve ->
// rank into LDS-sorted chunk -> coalesced linear sweep to global.
// pack (src<<7)|(tgt&127) in 4B (src < 2^17 ok: N=100000 < 131072)
__global__ void __launch_bounds__(PTH) partition_k(
        const int* __restrict__ row, const int* __restrict__ col,
        int* __restrict__ bcur, int* __restrict__ part, int E, int nb) {
    __shared__ int lh[1024];               // counts -> cursors
    __shared__ int lbase[1024];            // local exclusive bases
    __shared__ int delta[1024];            // scan temp (512) -> global_base - local_base
    __shared__ unsigned sorted[CHUNK_E];   // 64 KB
    __shared__ unsigned short bid[CHUNK_E];// 32 KB
    int tid = threadIdx.x;
    for (int i = tid; i < 1024; i += PTH) lh[i] = 0;
    __syncthreads();
    int base = blockIdx.x * CHUNK_E;
    int end = min(E, base + CHUNK_E);
    for (int e = base + tid; e < end; e += PTH)
        atomicAdd(&lh[col[e] >> BSHIFT], 1);
    __syncthreads();
    // block-wide exclusive scan of lh[0..1024) -> lbase (2 elems/thread, HS over 512 partials)
    int v0 = lh[2 * tid], v1 = lh[2 * tid + 1];
    int s = v0 + v1;
    delta[tid] = s;
    __syncthreads();
    for (int off = 1; off < PTH; off <<= 1) {
        int t = (tid >= off) ? delta[tid - off] : 0;
        __syncthreads();
        delta[tid] += t;
        __syncthreads();
    }
    int excl = delta[tid] - s;
    lbase[2 * tid] = excl;
    lbase[2 * tid + 1] = excl + v0;
    __syncthreads();
    // bulk-reserve global runs; delta[b] = global_base - local_base; reset cursors
    for (int i = tid; i < nb; i += PTH) {
        int c = lh[i];
        int g = c ? atomicAdd(&bcur[i], c) : 0;
        delta[i] = g - lbase[i];
    }
    __syncthreads();
    for (int i = tid; i < nb; i += PTH) lh[i] = lbase[i];
    __syncthreads();
    // rank into LDS-sorted chunk
    for (int e = base + tid; e < end; e += PTH) {
        int r = row[e], c = col[e];
        int b = c >> BSHIFT;
        int slot = atomicAdd(&lh[b], 1);
        sorted[slot] = (unsigned)((r << BSHIFT) | (c & (BNODES - 1)));
        bid[slot] = (unsigned short)b;
    }
    __syncthreads();
    // coalesced sweep: consecutive i -> consecutive global within each bucket run
    int cnt = end - base;
    for (int i = tid; i < cnt; i += PTH) {
        int b = bid[i];
        part[delta[b] + i] = (int)sorted[i];
    }
}

// one block per bucket: count local degrees, scan, emit dinv/cur, scatter csr
__global__ void csr_build_k(const int* __restrict__ part, const int* __restrict__ bcur,
                            int* __restrict__ cur, float* __restrict__ dinv,
                            int* __restrict__ csr, int N) {
    __shared__ int ldeg[BNODES];
    __shared__ int lofs[BNODES];
    __shared__ int ebounds[2];
    int b = blockIdx.x;
    int tid = threadIdx.x;
    if (tid == 0) { ebounds[0] = b ? bcur[b - 1] : 0; ebounds[1] = bcur[b]; }
    if (tid < BNODES) ldeg[tid] = 0;
    __syncthreads();
    int e0 = ebounds[0], e1 = ebounds[1];
    for (int e = e0 + tid; e < e1; e += blockDim.x)
        atomicAdd(&ldeg[part[e] & (BNODES - 1)], 1);
    __syncthreads();
    if (tid < BNODES) lofs[tid] = ldeg[tid];
    __syncthreads();
    for (int off = 1; off < BNODES; off <<= 1) {
        int t = (tid >= off && tid < BNODES) ? lofs[tid - off] : 0;
        __syncthreads();
        if (tid < BNODES) lofs[tid] += t;
        __syncthreads();
    }
    if (tid < BNODES) {
        int node = b * BNODES + tid;
        int d = ldeg[tid];
        int incl = lofs[tid];
        if (node < N) {
            cur[node] = e0 + incl;                       // inclusive end
            dinv[node] = rsqrtf(1.0f + (float)d);        // +1 self loop
        }
        ldeg[tid] = e0 + incl - d;                       // becomes write cursor
    }
    __syncthreads();
    for (int e = e0 + tid; e < e1; e += blockDim.x) {
        int v = part[e];
        int p = atomicAdd(&ldeg[v & (BNODES - 1)], 1);
        csr[p] = v >> BSHIFT;
    }
}

// ---------------- gather propagation (inputs pre-scaled by dinv) ----------------
// out_raw = dinv[t] * ( hs[t] + sum_{edges} hs[src] )   == (D^-1/2 A_hat D^-1/2 h)[t]
// EPI 0: store out_raw.   EPI 1: store relu(out_raw + b) * dinv[t]  (ready for next layer)
template<int D, int EPI>
__global__ void gather_prop_k(const float* __restrict__ hs, const float* __restrict__ dinv,
                              const int* __restrict__ cur, const int* __restrict__ csr,
                              const float* __restrict__ b, float* __restrict__ out, int n) {
    constexpr int TPN = D / 4;
    int tid = blockIdx.x * blockDim.x + threadIdx.x;
    int node = tid / TPN, t = tid % TPN;
    if (node >= n) return;
    float di = dinv[node];
    float4 acc = reinterpret_cast<const float4*>(hs + (size_t)node * D)[t];
    int e0 = node ? cur[node - 1] : 0;
    int e1 = cur[node];
    int e = e0;
    for (; e + 1 < e1; e += 2) {
        int s0 = csr[e], s1 = csr[e + 1];
        float4 v0 = reinterpret_cast<const float4*>(hs + (size_t)s0 * D)[t];
        float4 v1 = reinterpret_cast<const float4*>(hs + (size_t)s1 * D)[t];
        acc.x += v0.x + v1.x; acc.y += v0.y + v1.y;
        acc.z += v0.z + v1.z; acc.w += v0.w + v1.w;
    }
    if (e < e1) {
        int s0 = csr[e];
        float4 v0 = reinterpret_cast<const float4*>(hs + (size_t)s0 * D)[t];
        acc.x += v0.x; acc.y += v0.y; acc.z += v0.z; acc.w += v0.w;
    }
    acc.x *= di; acc.y *= di; acc.z *= di; acc.w *= di;
    if (EPI == 1) {
        acc.x = fmaxf(acc.x + b[t*4+0], 0.f) * di;
        acc.y = fmaxf(acc.y + b[t*4+1], 0.f) * di;
        acc.z = fmaxf(acc.z + b[t*4+2], 0.f) * di;
        acc.w = fmaxf(acc.w + b[t*4+3], 0.f) * di;
    }
    reinterpret_cast<float4*>(out + (size_t)node * D)[t] = acc;
}

// ---------------- LDS-tiled skinny matmul: y[n,OUT] = x[n,IN] @ W (+b, relu, *dinv) ----
template<int IN, int OUT, bool RELU, bool BIAS, bool SCALE>
__global__ void __launch_bounds__(256) matmul_k(
        const float* __restrict__ x, const float* __restrict__ W,
        const float* __restrict__ b, const float* __restrict__ dinv,
        float* __restrict__ y, int n) {
    constexpr int TN  = 64;           // nodes per block
    constexpr int RS  = IN + 4;       // padded row stride
    constexpr int OPT = OUT / 4;      // outputs per thread (4 threads per node)
    constexpr int NQ  = IN / 4;       // float4 per row
    __shared__ float xs[TN * RS];
    __shared__ float Ws[IN * OUT];
    __shared__ float bs[OUT];

    for (int i = threadIdx.x; i < IN * OUT; i += 256) Ws[i] = W[i];
    if (BIAS) for (int i = threadIdx.x; i < OUT; i += 256) bs[i] = b[i];

    int base = blockIdx.x * TN;
    for (int i = threadIdx.x; i < TN * NQ; i += 256) {
        int r = i / NQ, c = i % NQ;
        float4 v = make_float4(0.f, 0.f, 0.f, 0.f);
        if (base + r < n) v = reinterpret_cast<const float4*>(x + (size_t)(base + r) * IN)[c];
        *reinterpret_cast<float4*>(&xs[r * RS + c * 4]) = v;
    }
    __syncthreads();

    int node = threadIdx.x >> 2;          // 0..63
    int g    = threadIdx.x & 3;           // 0..3
    int j0   = g * OPT;
    if (base + node >= n) return;

    float acc[OPT];
#pragma unroll
    for (int jj = 0; jj < OPT; jj++) acc[jj] = 0.f;

    const float* xrow = &xs[node * RS];
#pragma unroll
    for (int k4 = 0; k4 < NQ; k4++) {
        float4 xv = *reinterpret_cast<const float4*>(&xrow[k4 * 4]);
        float xk[4] = {xv.x, xv.y, xv.z, xv.w};
#pragma unroll
        for (int kk = 0; kk < 4; kk++) {
            const float* wrow = &Ws[(k4 * 4 + kk) * OUT + j0];
#pragma unroll
            for (int jj = 0; jj < OPT; jj++)
                acc[jj] += xk[kk] * wrow[jj];
        }
    }

    float di = SCALE ? dinv[base + node] : 1.f;
    float vout[OPT];
#pragma unroll
    for (int jj = 0; jj < OPT; jj++) {
        float v = acc[jj] + (BIAS ? bs[j0 + jj] : 0.f);
        if (RELU) v = fmaxf(v, 0.f);
        if (SCALE) v *= di;
        vout[jj] = v;
    }
    float* yr = y + (size_t)(base + node) * OUT + j0;
    if (OPT % 4 == 0) {
#pragma unroll
        for (int q = 0; q < OPT / 4; q++)
            *reinterpret_cast<float4*>(yr + q * 4) =
                make_float4(vout[q*4+0], vout[q*4+1], vout[q*4+2], vout[q*4+3]);
    } else {
#pragma unroll
        for (int jj = 0; jj < OPT; jj++) yr[jj] = vout[jj];
    }
}

// ---------------- pooling + log_softmax ----------------
__device__ inline unsigned fkey(float x) {
    unsigned u = __float_as_uint(x);
    return (u & 0x80000000u) ? ~u : (u | 0x80000000u);
}
__device__ inline float funkey(unsigned k) {
    unsigned u = (k & 0x80000000u) ? (k & 0x7FFFFFFFu) : ~k;
    return __uint_as_float(u);
}

__global__ void pool_init_k(unsigned* pooled, int total) {
    int i = blockIdx.x * blockDim.x + threadIdx.x;
    if (i < total) pooled[i] = 0u;
}

__global__ void pool_max_k(const float* __restrict__ h4, const float* __restrict__ b4,
                           const int* __restrict__ batch, unsigned* __restrict__ pooled,
                           int n, int num_graphs) {
    __shared__ unsigned lds[128 * 4];
    for (int i = threadIdx.x; i < num_graphs * 4; i += blockDim.x) lds[i] = 0u;
    __syncthreads();
    int i = blockIdx.x * blockDim.x + threadIdx.x;
    if (i < n) {
        int g = batch[i];
        float4 v = reinterpret_cast<const float4*>(h4)[i];
        atomicMax(&lds[g*4+0], fkey(v.x + b4[0]));
        atomicMax(&lds[g*4+1], fkey(v.y + b4[1]));
        atomicMax(&lds[g*4+2], fkey(v.z + b4[2]));
        atomicMax(&lds[g*4+3], fkey(v.w + b4[3]));
    }
    __syncthreads();
    for (int i2 = threadIdx.x; i2 < num_graphs * 4; i2 += blockDim.x) {
        unsigned k = lds[i2];
        if (k) atomicMax(&pooled[i2], k);
    }
}

__global__ void logsoftmax_k(const unsigned* __restrict__ pooled, float* __restrict__ out, int G) {
    int g = blockIdx.x * blockDim.x + threadIdx.x;
    if (g >= G) return;
    float v[4];
#pragma unroll
    for (int j = 0; j < 4; j++) v[j] = funkey(pooled[g*4+j]);
    float m = fmaxf(fmaxf(v[0], v[1]), fmaxf(v[2], v[3]));
    float s = 0.f;
#pragma unroll
    for (int j = 0; j < 4; j++) s += expf(v[j] - m);
    float l = logf(s);
#pragma unroll
    for (int j = 0; j < 4; j++) out[g*4+j] = v[j] - m - l;
}

// ---------------- launch ----------------
extern "C" void kernel_launch(void* const* d_in, const int* in_sizes, int n_in,
                              void* d_out, int out_size, void* d_ws, size_t ws_size,
                              hipStream_t stream) {
    const float* x     = (const float*)d_in[0];
    const int*   ei    = (const int*)d_in[1];
    const int*   batch = (const int*)d_in[2];
    const float* W1 = (const float*)d_in[3];
    const float* b1 = (const float*)d_in[4];
    const float* W2 = (const float*)d_in[5];
    const float* b2 = (const float*)d_in[6];
    const float* W3 = (const float*)d_in[7];
    const float* b3 = (const float*)d_in[8];
    const float* W4 = (const float*)d_in[9];
    const float* b4 = (const float*)d_in[10];

    const int N = in_sizes[2];          // 100000
    const int E = in_sizes[1] / 2;      // 3.2M
    const int G = 128;
    const int* row = ei;
    const int* col = ei + E;
    const int NB = DIV_UP(N, BNODES);   // 782 buckets

    // workspace layout
    float* ws    = (float*)d_ws;
    float* dinv  = ws;                              // N floats
    int*   cur   = (int*)(dinv + N);                // N ints (inclusive seg ends)
    int*   bhist = cur + N;                         // 1024 ints
    int*   bcur  = bhist + 1024;                    // 1024 ints
    int*   csr   = bcur + 1024;                     // E ints
    float* f16a  = (float*)(csr + E);               // N*16
    float* f16b  = f16a + (size_t)N * 16;           // N*16
    float* f32a  = f16b + (size_t)N * 16;           // N*32
    float* f32b  = f32a + (size_t)N * 32;           // N*32
    unsigned* pooled = (unsigned*)(f32b + (size_t)N * 32);  // 512
    // part aliases f32a region (dead before any f32 use); E=3.2M <= 32N=3.2M ok
    int* part = (int*)f32a;
    float* f64 = f16a;                              // 64N spans f16a..f32a end
    float* f4a = f32b;                              // after L3 matmul, f32b free
    float* f4b = f32b + (size_t)N * 4;

    const int B = 256;
    const int gridN = DIV_UP(N, B);
    const int gridM = DIV_UP(N, 64);    // tiled matmul: 64 nodes/block

    // CSR build: hist -> scan -> LDS-ranked partition -> per-bucket finalize (emits dinv)
    zero_int_k<<<DIV_UP(1024, B), B, 0, stream>>>(bhist, 1024);
    bucket_hist_k<<<512, B, 0, stream>>>(col, bhist, E, NB);
    bucket_scan_k<<<1, 256, 0, stream>>>(bhist, bcur, NB);
    partition_k<<<DIV_UP(E, CHUNK_E), PTH, 0, stream>>>(row, col, bcur, part, E, NB);
    csr_build_k<<<NB, B, 0, stream>>>(part, bcur, cur, dinv, csr, N);

    // L1: y1 = (x@W1)*dinv -> f16b ; gather+bias+relu+scale -> f16a
    matmul_k<128,16,false,false,true><<<gridM, B, 0, stream>>>(x, W1, nullptr, dinv, f16b, N);
    gather_prop_k<16,1><<<DIV_UP(N*4, B), B, 0, stream>>>(f16b, dinv, cur, csr, b1, f16a, N);

    // L2: gather f16a -> f16b (raw agg) ; matmul 16->32 +b2,relu,*dinv -> f32a
    gather_prop_k<16,0><<<DIV_UP(N*4, B), B, 0, stream>>>(f16a, dinv, cur, csr, nullptr, f16b, N);
    matmul_k<16,32,true,true,true><<<gridM, B, 0, stream>>>(f16b, W2, b2, dinv, f32a, N);

    // L3: gather f32a -> f32b ; matmul 32->64 +b3,relu,*dinv -> f64 (= f16a..f32a)
    gather_prop_k<32,0><<<DIV_UP(N*8, B), B, 0, stream>>>(f32a, dinv, cur, csr, nullptr, f32b, N);
    matmul_k<32,64,true,true,true><<<gridM, B, 0, stream>>>(f32b, W3, b3, dinv, f64, N);

    // L4: y4 = h3s@W4 (already dinv-scaled input) -> f4a ; gather raw -> f4b
    matmul_k<64,4,false,false,false><<<gridM, B, 0, stream>>>(f64, W4, nullptr, nullptr, f4a, N);
    gather_prop_k<4,0><<<DIV_UP(N, B), B, 0, stream>>>(f4a, dinv, cur, csr, nullptr, f4b, N);

    // pool (adds b4) + log_softmax
    pool_init_k<<<DIV_UP(G*4, B), B, 0, stream>>>(pooled, G*4);
    pool_max_k<<<gridN, B, 0, stream>>>(f4b, b4, batch, pooled, N, G);
    logsoftmax_k<<<1, 128, 0, stream>>>(pooled, (float*)d_out, G);
}

// Round 9
// 283.481 us; speedup vs baseline: 1.6765x; 1.1469x over previous
//
#include <hip/hip_runtime.h>

#define DIV_UP(a,b) (((a)+(b)-1)/(b))

// bucket = tgt >> 7  (128 nodes per bucket)
constexpr int BSHIFT = 7;
constexpr int BNODES = 128;
constexpr int CHUNK_E = 16384;   // edges per partition block
constexpr int PTH = 512;         // partition block threads
constexpr int SCH = 8;           // source chunks for CSR segment ordering
constexpr int SCSH = 14;         // src >> 14 -> chunk id (16K nodes per chunk)

// ---------------- CSR build via bucket counting sort ----------------
__global__ void zero_int_k(int* p, int n) {
    int i = blockIdx.x * blockDim.x + threadIdx.x;
    if (i < n) p[i] = 0;
}

__global__ void bucket_hist_k(const int* __restrict__ col, int* __restrict__ bhist, int E, int nb) {
    __shared__ int lh[1024];
    for (int i = threadIdx.x; i < 1024; i += blockDim.x) lh[i] = 0;
    __syncthreads();
    int stride = gridDim.x * blockDim.x;
    for (int e = blockIdx.x * blockDim.x + threadIdx.x; e < E; e += stride)
        atomicAdd(&lh[col[e] >> BSHIFT], 1);
    __syncthreads();
    for (int i = threadIdx.x; i < nb; i += blockDim.x) {
        int v = lh[i];
        if (v) atomicAdd(&bhist[i], v);
    }
}

// exclusive scan of nb (<=1024) bucket counts -> bcur
__global__ void bucket_scan_k(const int* __restrict__ bhist, int* __restrict__ bcur, int nb) {
    __shared__ int lds[256];
    int base = threadIdx.x * 4;
    int v[4]; int s = 0;
#pragma unroll
    for (int j = 0; j < 4; j++) { v[j] = (base + j < nb) ? bhist[base + j] : 0; s += v[j]; }
    lds[threadIdx.x] = s; __syncthreads();
    for (int off = 1; off < 256; off <<= 1) {
        int t = (threadIdx.x >= off) ? lds[threadIdx.x - off] : 0;
        __syncthreads();
        lds[threadIdx.x] += t;
        __syncthreads();
    }
    int excl = lds[threadIdx.x] - s;
#pragma unroll
    for (int j = 0; j < 4; j++) {
        if (base + j < nb) bcur[base + j] = excl;
        excl += v[j];
    }
}

// LDS-ranked partition (counting-sort pass): hist -> local scan -> bulk reserve ->
// rank into LDS-sorted chunk -> coalesced linear sweep to global.
// pack (src<<7)|(tgt&127) in 4B (src < 2^17 ok: N=100000 < 131072)
__global__ void __launch_bounds__(PTH) partition_k(
        const int* __restrict__ row, const int* __restrict__ col,
        int* __restrict__ bcur, int* __restrict__ part, int E, int nb) {
    __shared__ int lh[1024];               // counts -> cursors
    __shared__ int lbase[1024];            // local exclusive bases
    __shared__ int delta[1024];            // scan temp (512) -> global_base - local_base
    __shared__ unsigned sorted[CHUNK_E];   // 64 KB
    __shared__ unsigned short bid[CHUNK_E];// 32 KB
    int tid = threadIdx.x;
    for (int i = tid; i < 1024; i += PTH) lh[i] = 0;
    __syncthreads();
    int base = blockIdx.x * CHUNK_E;
    int end = min(E, base + CHUNK_E);
    for (int e = base + tid; e < end; e += PTH)
        atomicAdd(&lh[col[e] >> BSHIFT], 1);
    __syncthreads();
    // block-wide exclusive scan of lh[0..1024) -> lbase
    int v0 = lh[2 * tid], v1 = lh[2 * tid + 1];
    int s = v0 + v1;
    delta[tid] = s;
    __syncthreads();
    for (int off = 1; off < PTH; off <<= 1) {
        int t = (tid >= off) ? delta[tid - off] : 0;
        __syncthreads();
        delta[tid] += t;
        __syncthreads();
    }
    int excl = delta[tid] - s;
    lbase[2 * tid] = excl;
    lbase[2 * tid + 1] = excl + v0;
    __syncthreads();
    // bulk-reserve global runs; delta[b] = global_base - local_base; reset cursors
    for (int i = tid; i < nb; i += PTH) {
        int c = lh[i];
        int g = c ? atomicAdd(&bcur[i], c) : 0;
        delta[i] = g - lbase[i];
    }
    __syncthreads();
    for (int i = tid; i < nb; i += PTH) lh[i] = lbase[i];
    __syncthreads();
    // rank into LDS-sorted chunk
    for (int e = base + tid; e < end; e += PTH) {
        int r = row[e], c = col[e];
        int b = c >> BSHIFT;
        int slot = atomicAdd(&lh[b], 1);
        sorted[slot] = (unsigned)((r << BSHIFT) | (c & (BNODES - 1)));
        bid[slot] = (unsigned short)b;
    }
    __syncthreads();
    // coalesced sweep: consecutive i -> consecutive global within each bucket run
    int cnt = end - base;
    for (int i = tid; i < cnt; i += PTH) {
        int b = bid[i];
        part[delta[b] + i] = (int)sorted[i];
    }
}

// one block per bucket: (target, src-chunk) counting sort, emit dinv/cur, scatter csr.
// Segments come out ordered by src-chunk -> coherent src sweep in the gathers (L2 locality).
__global__ void __launch_bounds__(256) csr_build_k(
        const int* __restrict__ part, const int* __restrict__ bcur,
        int* __restrict__ cur, float* __restrict__ dinv,
        int* __restrict__ csr, int N) {
    __shared__ int cnt[BNODES * SCH];   // 1024 cells: (tgt&127)*8 + src_chunk
    __shared__ int scan_t[256];
    __shared__ int ebounds[2];
    int b = blockIdx.x;
    int tid = threadIdx.x;
    if (tid == 0) { ebounds[0] = b ? bcur[b - 1] : 0; ebounds[1] = bcur[b]; }
    for (int i = tid; i < BNODES * SCH; i += 256) cnt[i] = 0;
    __syncthreads();
    int e0 = ebounds[0], e1 = ebounds[1];
    for (int e = e0 + tid; e < e1; e += 256) {
        unsigned v = (unsigned)part[e];
        int cell = (int)(v & (BNODES - 1)) * SCH + (int)(v >> (BSHIFT + SCSH));
        atomicAdd(&cnt[cell], 1);
    }
    __syncthreads();
    // exclusive scan of cnt[1024]: 4 cells/thread + HS over 256 partials
    int base4 = tid * 4;
    int c0 = cnt[base4], c1 = cnt[base4+1], c2 = cnt[base4+2], c3 = cnt[base4+3];
    int s = c0 + c1 + c2 + c3;
    scan_t[tid] = s;
    __syncthreads();
    for (int off = 1; off < 256; off <<= 1) {
        int t = (tid >= off) ? scan_t[tid - off] : 0;
        __syncthreads();
        scan_t[tid] += t;
        __syncthreads();
    }
    int excl = scan_t[tid] - s;
    cnt[base4]     = excl;
    cnt[base4 + 1] = excl + c0;
    cnt[base4 + 2] = excl + c0 + c1;
    cnt[base4 + 3] = excl + c0 + c1 + c2;
    __syncthreads();
    // per-target degree / cur / dinv
    if (tid < BNODES) {
        int node = b * BNODES + tid;
        int segstart = cnt[tid * SCH];
        int segend   = (tid == BNODES - 1) ? (e1 - e0) : cnt[(tid + 1) * SCH];
        if (node < N) {
            cur[node]  = e0 + segend;                            // inclusive end
            dinv[node] = rsqrtf(1.0f + (float)(segend - segstart)); // +1 self loop
        }
    }
    __syncthreads();
    // scatter via (tgt, src-chunk) cursors
    for (int e = e0 + tid; e < e1; e += 256) {
        unsigned v = (unsigned)part[e];
        int cell = (int)(v & (BNODES - 1)) * SCH + (int)(v >> (BSHIFT + SCSH));
        int p = atomicAdd(&cnt[cell], 1);
        csr[e0 + p] = (int)(v >> BSHIFT);
    }
}

// ---------------- gather propagation (inputs pre-scaled by dinv) ----------------
// out_raw = dinv[t] * ( hs[t] + sum_{edges} hs[src] )   == (D^-1/2 A_hat D^-1/2 h)[t]
// EPI 0: store out_raw.   EPI 1: store relu(out_raw + b) * dinv[t]  (ready for next layer)
template<int D, int EPI>
__global__ void gather_prop_k(const float* __restrict__ hs, const float* __restrict__ dinv,
                              const int* __restrict__ cur, const int* __restrict__ csr,
                              const float* __restrict__ b, float* __restrict__ out, int n) {
    constexpr int TPN = D / 4;
    int tid = blockIdx.x * blockDim.x + threadIdx.x;
    int node = tid / TPN, t = tid % TPN;
    if (node >= n) return;
    float di = dinv[node];
    float4 acc = reinterpret_cast<const float4*>(hs + (size_t)node * D)[t];
    int e0 = node ? cur[node - 1] : 0;
    int e1 = cur[node];
    int e = e0;
    for (; e + 1 < e1; e += 2) {
        int s0 = csr[e], s1 = csr[e + 1];
        float4 v0 = reinterpret_cast<const float4*>(hs + (size_t)s0 * D)[t];
        float4 v1 = reinterpret_cast<const float4*>(hs + (size_t)s1 * D)[t];
        acc.x += v0.x + v1.x; acc.y += v0.y + v1.y;
        acc.z += v0.z + v1.z; acc.w += v0.w + v1.w;
    }
    if (e < e1) {
        int s0 = csr[e];
        float4 v0 = reinterpret_cast<const float4*>(hs + (size_t)s0 * D)[t];
        acc.x += v0.x; acc.y += v0.y; acc.z += v0.z; acc.w += v0.w;
    }
    acc.x *= di; acc.y *= di; acc.z *= di; acc.w *= di;
    if (EPI == 1) {
        acc.x = fmaxf(acc.x + b[t*4+0], 0.f) * di;
        acc.y = fmaxf(acc.y + b[t*4+1], 0.f) * di;
        acc.z = fmaxf(acc.z + b[t*4+2], 0.f) * di;
        acc.w = fmaxf(acc.w + b[t*4+3], 0.f) * di;
    }
    reinterpret_cast<float4*>(out + (size_t)node * D)[t] = acc;
}

// ---------------- LDS-tiled skinny matmul: y[n,OUT] = x[n,IN] @ W (+b, relu, *dinv) ----
template<int IN, int OUT, bool RELU, bool BIAS, bool SCALE>
__global__ void __launch_bounds__(256) matmul_k(
        const float* __restrict__ x, const float* __restrict__ W,
        const float* __restrict__ b, const float* __restrict__ dinv,
        float* __restrict__ y, int n) {
    constexpr int TN  = 64;           // nodes per block
    constexpr int RS  = IN + 4;       // padded row stride
    constexpr int OPT = OUT / 4;      // outputs per thread (4 threads per node)
    constexpr int NQ  = IN / 4;       // float4 per row
    __shared__ float xs[TN * RS];
    __shared__ float Ws[IN * OUT];
    __shared__ float bs[OUT];

    for (int i = threadIdx.x; i < IN * OUT; i += 256) Ws[i] = W[i];
    if (BIAS) for (int i = threadIdx.x; i < OUT; i += 256) bs[i] = b[i];

    int base = blockIdx.x * TN;
    for (int i = threadIdx.x; i < TN * NQ; i += 256) {
        int r = i / NQ, c = i % NQ;
        float4 v = make_float4(0.f, 0.f, 0.f, 0.f);
        if (base + r < n) v = reinterpret_cast<const float4*>(x + (size_t)(base + r) * IN)[c];
        *reinterpret_cast<float4*>(&xs[r * RS + c * 4]) = v;
    }
    __syncthreads();

    int node = threadIdx.x >> 2;          // 0..63
    int g    = threadIdx.x & 3;           // 0..3
    int j0   = g * OPT;
    if (base + node >= n) return;

    float acc[OPT];
#pragma unroll
    for (int jj = 0; jj < OPT; jj++) acc[jj] = 0.f;

    const float* xrow = &xs[node * RS];
#pragma unroll
    for (int k4 = 0; k4 < NQ; k4++) {
        float4 xv = *reinterpret_cast<const float4*>(&xrow[k4 * 4]);
        float xk[4] = {xv.x, xv.y, xv.z, xv.w};
#pragma unroll
        for (int kk = 0; kk < 4; kk++) {
            const float* wrow = &Ws[(k4 * 4 + kk) * OUT + j0];
#pragma unroll
            for (int jj = 0; jj < OPT; jj++)
                acc[jj] += xk[kk] * wrow[jj];
        }
    }

    float di = SCALE ? dinv[base + node] : 1.f;
    float vout[OPT];
#pragma unroll
    for (int jj = 0; jj < OPT; jj++) {
        float v = acc[jj] + (BIAS ? bs[j0 + jj] : 0.f);
        if (RELU) v = fmaxf(v, 0.f);
        if (SCALE) v *= di;
        vout[jj] = v;
    }
    float* yr = y + (size_t)(base + node) * OUT + j0;
    if (OPT % 4 == 0) {
#pragma unroll
        for (int q = 0; q < OPT / 4; q++)
            *reinterpret_cast<float4*>(yr + q * 4) =
                make_float4(vout[q*4+0], vout[q*4+1], vout[q*4+2], vout[q*4+3]);
    } else {
#pragma unroll
        for (int jj = 0; jj < OPT; jj++) yr[jj] = vout[jj];
    }
}

// ---------------- pooling + log_softmax ----------------
__device__ inline unsigned fkey(float x) {
    unsigned u = __float_as_uint(x);
    return (u & 0x80000000u) ? ~u : (u | 0x80000000u);
}
__device__ inline float funkey(unsigned k) {
    unsigned u = (k & 0x80000000u) ? (k & 0x7FFFFFFFu) : ~k;
    return __uint_as_float(u);
}

__global__ void pool_init_k(unsigned* pooled, int total) {
    int i = blockIdx.x * blockDim.x + threadIdx.x;
    if (i < total) pooled[i] = 0u;
}

__global__ void pool_max_k(const float* __restrict__ h4, const float* __restrict__ b4,
                           const int* __restrict__ batch, unsigned* __restrict__ pooled,
                           int n, int num_graphs) {
    __shared__ unsigned lds[128 * 4];
    for (int i = threadIdx.x; i < num_graphs * 4; i += blockDim.x) lds[i] = 0u;
    __syncthreads();
    int i = blockIdx.x * blockDim.x + threadIdx.x;
    if (i < n) {
        int g = batch[i];
        float4 v = reinterpret_cast<const float4*>(h4)[i];
        atomicMax(&lds[g*4+0], fkey(v.x + b4[0]));
        atomicMax(&lds[g*4+1], fkey(v.y + b4[1]));
        atomicMax(&lds[g*4+2], fkey(v.z + b4[2]));
        atomicMax(&lds[g*4+3], fkey(v.w + b4[3]));
    }
    __syncthreads();
    for (int i2 = threadIdx.x; i2 < num_graphs * 4; i2 += blockDim.x) {
        unsigned k = lds[i2];
        if (k) atomicMax(&pooled[i2], k);
    }
}

__global__ void logsoftmax_k(const unsigned* __restrict__ pooled, float* __restrict__ out, int G) {
    int g = blockIdx.x * blockDim.x + threadIdx.x;
    if (g >= G) return;
    float v[4];
#pragma unroll
    for (int j = 0; j < 4; j++) v[j] = funkey(pooled[g*4+j]);
    float m = fmaxf(fmaxf(v[0], v[1]), fmaxf(v[2], v[3]));
    float s = 0.f;
#pragma unroll
    for (int j = 0; j < 4; j++) s += expf(v[j] - m);
    float l = logf(s);
#pragma unroll
    for (int j = 0; j < 4; j++) out[g*4+j] = v[j] - m - l;
}

// ---------------- launch ----------------
extern "C" void kernel_launch(void* const* d_in, const int* in_sizes, int n_in,
                              void* d_out, int out_size, void* d_ws, size_t ws_size,
                              hipStream_t stream) {
    const float* x     = (const float*)d_in[0];
    const int*   ei    = (const int*)d_in[1];
    const int*   batch = (const int*)d_in[2];
    const float* W1 = (const float*)d_in[3];
    const float* b1 = (const float*)d_in[4];
    const float* W2 = (const float*)d_in[5];
    const float* b2 = (const float*)d_in[6];
    const float* W3 = (const float*)d_in[7];
    const float* b3 = (const float*)d_in[8];
    const float* W4 = (const float*)d_in[9];
    const float* b4 = (const float*)d_in[10];

    const int N = in_sizes[2];          // 100000
    const int E = in_sizes[1] / 2;      // 3.2M
    const int G = 128;
    const int* row = ei;
    const int* col = ei + E;
    const int NB = DIV_UP(N, BNODES);   // 782 buckets

    // workspace layout
    float* ws    = (float*)d_ws;
    float* dinv  = ws;                              // N floats
    int*   cur   = (int*)(dinv + N);                // N ints (inclusive seg ends)
    int*   bhist = cur + N;                         // 1024 ints
    int*   bcur  = bhist + 1024;                    // 1024 ints
    int*   csr   = bcur + 1024;                     // E ints
    float* f16a  = (float*)(csr + E);               // N*16
    float* f16b  = f16a + (size_t)N * 16;           // N*16
    float* f32a  = f16b + (size_t)N * 16;           // N*32
    float* f32b  = f32a + (size_t)N * 32;           // N*32
    unsigned* pooled = (unsigned*)(f32b + (size_t)N * 32);  // 512
    // part aliases f32a region (dead before any f32 use); E=3.2M <= 32N=3.2M ok
    int* part = (int*)f32a;
    float* f64 = f16a;                              // 64N spans f16a..f32a end
    float* f4a = f32b;                              // after L3 matmul, f32b free
    float* f4b = f32b + (size_t)N * 4;

    const int B = 256;
    const int gridN = DIV_UP(N, B);
    const int gridM = DIV_UP(N, 64);    // tiled matmul: 64 nodes/block

    // CSR build: hist -> scan -> LDS-ranked partition -> per-bucket (tgt,src-chunk) sort
    zero_int_k<<<DIV_UP(1024, B), B, 0, stream>>>(bhist, 1024);
    bucket_hist_k<<<512, B, 0, stream>>>(col, bhist, E, NB);
    bucket_scan_k<<<1, 256, 0, stream>>>(bhist, bcur, NB);
    partition_k<<<DIV_UP(E, CHUNK_E), PTH, 0, stream>>>(row, col, bcur, part, E, NB);
    csr_build_k<<<NB, 256, 0, stream>>>(part, bcur, cur, dinv, csr, N);

    // L1: y1 = (x@W1)*dinv -> f16b ; gather+bias+relu+scale -> f16a
    matmul_k<128,16,false,false,true><<<gridM, B, 0, stream>>>(x, W1, nullptr, dinv, f16b, N);
    gather_prop_k<16,1><<<DIV_UP(N*4, B), B, 0, stream>>>(f16b, dinv, cur, csr, b1, f16a, N);

    // L2: gather f16a -> f16b (raw agg) ; matmul 16->32 +b2,relu,*dinv -> f32a
    gather_prop_k<16,0><<<DIV_UP(N*4, B), B, 0, stream>>>(f16a, dinv, cur, csr, nullptr, f16b, N);
    matmul_k<16,32,true,true,true><<<gridM, B, 0, stream>>>(f16b, W2, b2, dinv, f32a, N);

    // L3: gather f32a -> f32b ; matmul 32->64 +b3,relu,*dinv -> f64 (= f16a..f32a)
    gather_prop_k<32,0><<<DIV_UP(N*8, B), B, 0, stream>>>(f32a, dinv, cur, csr, nullptr, f32b, N);
    matmul_k<32,64,true,true,true><<<gridM, B, 0, stream>>>(f32b, W3, b3, dinv, f64, N);

    // L4: y4 = h3s@W4 (already dinv-scaled input) -> f4a ; gather raw -> f4b
    matmul_k<64,4,false,false,false><<<gridM, B, 0, stream>>>(f64, W4, nullptr, nullptr, f4a, N);
    gather_prop_k<4,0><<<DIV_UP(N, B), B, 0, stream>>>(f4a, dinv, cur, csr, nullptr, f4b, N);

    // pool (adds b4) + log_softmax
    pool_init_k<<<DIV_UP(G*4, B), B, 0, stream>>>(pooled, G*4);
    pool_max_k<<<gridN, B, 0, stream>>>(f4b, b4, batch, pooled, N, G);
    logsoftmax_k<<<1, 128, 0, stream>>>(pooled, (float*)d_out, G);
}

// Round 10
// 267.040 us; speedup vs baseline: 1.7797x; 1.0616x over previous
//
#include <hip/hip_runtime.h>

#define DIV_UP(a,b) (((a)+(b)-1)/(b))

// bucket = tgt >> 7  (128 nodes per bucket)
constexpr int BSHIFT = 7;
constexpr int BNODES = 128;
constexpr int CHUNK_E = 16384;   // edges per partition block
constexpr int PTH = 512;         // partition block threads
constexpr int SCH = 8;           // source chunks for CSR segment ordering
constexpr int SCSH = 14;         // src >> 14 -> chunk id (16K nodes per chunk)

// ---------------- bf16 helpers (storage only; all math fp32) ----------------
__device__ inline unsigned short f2bf(float f) {
    unsigned u = __float_as_uint(f);
    u = u + 0x7FFFu + ((u >> 16) & 1u);   // round-to-nearest-even
    return (unsigned short)(u >> 16);
}
__device__ inline float bflo(unsigned u) { return __uint_as_float(u << 16); }
__device__ inline float bfhi(unsigned u) { return __uint_as_float(u & 0xFFFF0000u); }

// ---------------- CSR build via bucket counting sort ----------------
__global__ void zero_int_k(int* p, int n) {
    int i = blockIdx.x * blockDim.x + threadIdx.x;
    if (i < n) p[i] = 0;
}

__global__ void bucket_hist_k(const int* __restrict__ col, int* __restrict__ bhist, int E, int nb) {
    __shared__ int lh[1024];
    for (int i = threadIdx.x; i < 1024; i += blockDim.x) lh[i] = 0;
    __syncthreads();
    int stride = gridDim.x * blockDim.x;
    for (int e = blockIdx.x * blockDim.x + threadIdx.x; e < E; e += stride)
        atomicAdd(&lh[col[e] >> BSHIFT], 1);
    __syncthreads();
    for (int i = threadIdx.x; i < nb; i += blockDim.x) {
        int v = lh[i];
        if (v) atomicAdd(&bhist[i], v);
    }
}

// exclusive scan of nb (<=1024) bucket counts -> bcur
__global__ void bucket_scan_k(const int* __restrict__ bhist, int* __restrict__ bcur, int nb) {
    __shared__ int lds[256];
    int base = threadIdx.x * 4;
    int v[4]; int s = 0;
#pragma unroll
    for (int j = 0; j < 4; j++) { v[j] = (base + j < nb) ? bhist[base + j] : 0; s += v[j]; }
    lds[threadIdx.x] = s; __syncthreads();
    for (int off = 1; off < 256; off <<= 1) {
        int t = (threadIdx.x >= off) ? lds[threadIdx.x - off] : 0;
        __syncthreads();
        lds[threadIdx.x] += t;
        __syncthreads();
    }
    int excl = lds[threadIdx.x] - s;
#pragma unroll
    for (int j = 0; j < 4; j++) {
        if (base + j < nb) bcur[base + j] = excl;
        excl += v[j];
    }
}

// LDS-ranked partition (counting-sort pass)
__global__ void __launch_bounds__(PTH) partition_k(
        const int* __restrict__ row, const int* __restrict__ col,
        int* __restrict__ bcur, int* __restrict__ part, int E, int nb) {
    __shared__ int lh[1024];
    __shared__ int lbase[1024];
    __shared__ int delta[1024];
    __shared__ unsigned sorted[CHUNK_E];
    __shared__ unsigned short bid[CHUNK_E];
    int tid = threadIdx.x;
    for (int i = tid; i < 1024; i += PTH) lh[i] = 0;
    __syncthreads();
    int base = blockIdx.x * CHUNK_E;
    int end = min(E, base + CHUNK_E);
    for (int e = base + tid; e < end; e += PTH)
        atomicAdd(&lh[col[e] >> BSHIFT], 1);
    __syncthreads();
    int v0 = lh[2 * tid], v1 = lh[2 * tid + 1];
    int s = v0 + v1;
    delta[tid] = s;
    __syncthreads();
    for (int off = 1; off < PTH; off <<= 1) {
        int t = (tid >= off) ? delta[tid - off] : 0;
        __syncthreads();
        delta[tid] += t;
        __syncthreads();
    }
    int excl = delta[tid] - s;
    lbase[2 * tid] = excl;
    lbase[2 * tid + 1] = excl + v0;
    __syncthreads();
    for (int i = tid; i < nb; i += PTH) {
        int c = lh[i];
        int g = c ? atomicAdd(&bcur[i], c) : 0;
        delta[i] = g - lbase[i];
    }
    __syncthreads();
    for (int i = tid; i < nb; i += PTH) lh[i] = lbase[i];
    __syncthreads();
    for (int e = base + tid; e < end; e += PTH) {
        int r = row[e], c = col[e];
        int b = c >> BSHIFT;
        int slot = atomicAdd(&lh[b], 1);
        sorted[slot] = (unsigned)((r << BSHIFT) | (c & (BNODES - 1)));
        bid[slot] = (unsigned short)b;
    }
    __syncthreads();
    int cnt = end - base;
    for (int i = tid; i < cnt; i += PTH) {
        int b = bid[i];
        part[delta[b] + i] = (int)sorted[i];
    }
}

// one block per bucket: (target, src-chunk) counting sort -> csr ordered by src-chunk
__global__ void __launch_bounds__(256) csr_build_k(
        const int* __restrict__ part, const int* __restrict__ bcur,
        int* __restrict__ cur, float* __restrict__ dinv,
        int* __restrict__ csr, int N) {
    __shared__ int cnt[BNODES * SCH];
    __shared__ int scan_t[256];
    __shared__ int ebounds[2];
    int b = blockIdx.x;
    int tid = threadIdx.x;
    if (tid == 0) { ebounds[0] = b ? bcur[b - 1] : 0; ebounds[1] = bcur[b]; }
    for (int i = tid; i < BNODES * SCH; i += 256) cnt[i] = 0;
    __syncthreads();
    int e0 = ebounds[0], e1 = ebounds[1];
    for (int e = e0 + tid; e < e1; e += 256) {
        unsigned v = (unsigned)part[e];
        int cell = (int)(v & (BNODES - 1)) * SCH + (int)(v >> (BSHIFT + SCSH));
        atomicAdd(&cnt[cell], 1);
    }
    __syncthreads();
    int base4 = tid * 4;
    int c0 = cnt[base4], c1 = cnt[base4+1], c2 = cnt[base4+2], c3 = cnt[base4+3];
    int s = c0 + c1 + c2 + c3;
    scan_t[tid] = s;
    __syncthreads();
    for (int off = 1; off < 256; off <<= 1) {
        int t = (tid >= off) ? scan_t[tid - off] : 0;
        __syncthreads();
        scan_t[tid] += t;
        __syncthreads();
    }
    int excl = scan_t[tid] - s;
    cnt[base4]     = excl;
    cnt[base4 + 1] = excl + c0;
    cnt[base4 + 2] = excl + c0 + c1;
    cnt[base4 + 3] = excl + c0 + c1 + c2;
    __syncthreads();
    if (tid < BNODES) {
        int node = b * BNODES + tid;
        int segstart = cnt[tid * SCH];
        int segend   = (tid == BNODES - 1) ? (e1 - e0) : cnt[(tid + 1) * SCH];
        if (node < N) {
            cur[node]  = e0 + segend;
            dinv[node] = rsqrtf(1.0f + (float)(segend - segstart));
        }
    }
    __syncthreads();
    for (int e = e0 + tid; e < e1; e += 256) {
        unsigned v = (unsigned)part[e];
        int cell = (int)(v & (BNODES - 1)) * SCH + (int)(v >> (BSHIFT + SCSH));
        int p = atomicAdd(&cnt[cell], 1);
        csr[e0 + p] = (int)(v >> BSHIFT);
    }
}

// ---------------- gather propagation, fp32 rows (D=16 and D=4 paths) ----------------
template<int D, int EPI>
__global__ void gather_prop_k(const float* __restrict__ hs, const float* __restrict__ dinv,
                              const int* __restrict__ cur, const int* __restrict__ csr,
                              const float* __restrict__ b, float* __restrict__ out, int n) {
    constexpr int TPN = D / 4;
    int tid = blockIdx.x * blockDim.x + threadIdx.x;
    int node = tid / TPN, t = tid % TPN;
    if (node >= n) return;
    float di = dinv[node];
    float4 acc = reinterpret_cast<const float4*>(hs + (size_t)node * D)[t];
    int e0 = node ? cur[node - 1] : 0;
    int e1 = cur[node];
    int e = e0;
    for (; e + 1 < e1; e += 2) {
        int s0 = csr[e], s1 = csr[e + 1];
        float4 v0 = reinterpret_cast<const float4*>(hs + (size_t)s0 * D)[t];
        float4 v1 = reinterpret_cast<const float4*>(hs + (size_t)s1 * D)[t];
        acc.x += v0.x + v1.x; acc.y += v0.y + v1.y;
        acc.z += v0.z + v1.z; acc.w += v0.w + v1.w;
    }
    if (e < e1) {
        int s0 = csr[e];
        float4 v0 = reinterpret_cast<const float4*>(hs + (size_t)s0 * D)[t];
        acc.x += v0.x; acc.y += v0.y; acc.z += v0.z; acc.w += v0.w;
    }
    acc.x *= di; acc.y *= di; acc.z *= di; acc.w *= di;
    if (EPI == 1) {
        acc.x = fmaxf(acc.x + b[t*4+0], 0.f) * di;
        acc.y = fmaxf(acc.y + b[t*4+1], 0.f) * di;
        acc.z = fmaxf(acc.z + b[t*4+2], 0.f) * di;
        acc.w = fmaxf(acc.w + b[t*4+3], 0.f) * di;
    }
    reinterpret_cast<float4*>(out + (size_t)node * D)[t] = acc;
}

// ---------------- gather propagation, bf16 rows, D=32 (row = 64B = 1 line) ----------
// 4 threads per node, each owns 8 contiguous bf16 columns (one uint4 load per edge).
__global__ void __launch_bounds__(256) gather32_bf_k(
        const unsigned short* __restrict__ hb, const float* __restrict__ dinv,
        const int* __restrict__ cur, const int* __restrict__ csr,
        float* __restrict__ out, int n) {
    int tid4 = blockIdx.x * 256 + threadIdx.x;
    int node = tid4 >> 2, t = tid4 & 3;
    if (node >= n) return;
    const uint4* hb4 = reinterpret_cast<const uint4*>(hb);
    uint4 sv = hb4[(size_t)node * 4 + t];
    float a0 = bflo(sv.x), a1 = bfhi(sv.x), a2 = bflo(sv.y), a3 = bfhi(sv.y);
    float a4 = bflo(sv.z), a5 = bfhi(sv.z), a6 = bflo(sv.w), a7 = bfhi(sv.w);
    int e0 = node ? cur[node - 1] : 0;
    int e1 = cur[node];
    int e = e0;
    for (; e + 1 < e1; e += 2) {
        uint4 v = hb4[(size_t)csr[e] * 4 + t];
        uint4 w = hb4[(size_t)csr[e + 1] * 4 + t];
        a0 += bflo(v.x) + bflo(w.x); a1 += bfhi(v.x) + bfhi(w.x);
        a2 += bflo(v.y) + bflo(w.y); a3 += bfhi(v.y) + bfhi(w.y);
        a4 += bflo(v.z) + bflo(w.z); a5 += bfhi(v.z) + bfhi(w.z);
        a6 += bflo(v.w) + bflo(w.w); a7 += bfhi(v.w) + bfhi(w.w);
    }
    if (e < e1) {
        uint4 v = hb4[(size_t)csr[e] * 4 + t];
        a0 += bflo(v.x); a1 += bfhi(v.x); a2 += bflo(v.y); a3 += bfhi(v.y);
        a4 += bflo(v.z); a5 += bfhi(v.z); a6 += bflo(v.w); a7 += bfhi(v.w);
    }
    float di = dinv[node];
    float* op = out + (size_t)node * 32 + t * 8;
    *reinterpret_cast<float4*>(op)     = make_float4(a0*di, a1*di, a2*di, a3*di);
    *reinterpret_cast<float4*>(op + 4) = make_float4(a4*di, a5*di, a6*di, a7*di);
}

// ---------------- LDS-tiled skinny matmul with optional bf16 in/out ----------------
template<int IN, int OUT, bool RELU, bool BIAS, bool SCALE, bool IBF, bool OBF>
__global__ void __launch_bounds__(256) matmul_k(
        const void* __restrict__ xv, const float* __restrict__ W,
        const float* __restrict__ b, const float* __restrict__ dinv,
        void* __restrict__ yv, int n) {
    constexpr int TN  = 64;
    constexpr int RS  = IN + 4;
    constexpr int OPT = OUT / 4;
    constexpr int NQ  = IN / 4;
    __shared__ float xs[TN * RS];
    __shared__ float Ws[IN * OUT];
    __shared__ float bs[OUT];

    for (int i = threadIdx.x; i < IN * OUT; i += 256) Ws[i] = W[i];
    if (BIAS) for (int i = threadIdx.x; i < OUT; i += 256) bs[i] = b[i];

    int base = blockIdx.x * TN;
    if constexpr (!IBF) {
        const float* x = (const float*)xv;
        for (int i = threadIdx.x; i < TN * NQ; i += 256) {
            int r = i / NQ, c = i % NQ;
            float4 v = make_float4(0.f, 0.f, 0.f, 0.f);
            if (base + r < n) v = reinterpret_cast<const float4*>(x + (size_t)(base + r) * IN)[c];
            *reinterpret_cast<float4*>(&xs[r * RS + c * 4]) = v;
        }
    } else {
        constexpr int NU = IN / 8;   // uint4 (8 bf16) per row
        const uint4* x = (const uint4*)xv;
        for (int i = threadIdx.x; i < TN * NU; i += 256) {
            int r = i / NU, c = i % NU;
            uint4 v = make_uint4(0u, 0u, 0u, 0u);
            if (base + r < n) v = x[(size_t)(base + r) * NU + c];
            float* dst = &xs[r * RS + c * 8];
            dst[0] = bflo(v.x); dst[1] = bfhi(v.x);
            dst[2] = bflo(v.y); dst[3] = bfhi(v.y);
            dst[4] = bflo(v.z); dst[5] = bfhi(v.z);
            dst[6] = bflo(v.w); dst[7] = bfhi(v.w);
        }
    }
    __syncthreads();

    int node = threadIdx.x >> 2;
    int g    = threadIdx.x & 3;
    int j0   = g * OPT;
    int gnode = base + node;
    if (gnode >= n) return;

    float acc[OPT];
#pragma unroll
    for (int jj = 0; jj < OPT; jj++) acc[jj] = 0.f;

    const float* xrow = &xs[node * RS];
#pragma unroll
    for (int k4 = 0; k4 < NQ; k4++) {
        float4 xvv = *reinterpret_cast<const float4*>(&xrow[k4 * 4]);
        float xk[4] = {xvv.x, xvv.y, xvv.z, xvv.w};
#pragma unroll
        for (int kk = 0; kk < 4; kk++) {
            const float* wrow = &Ws[(k4 * 4 + kk) * OUT + j0];
#pragma unroll
            for (int jj = 0; jj < OPT; jj++)
                acc[jj] += xk[kk] * wrow[jj];
        }
    }

    float di = SCALE ? dinv[gnode] : 1.f;
    float vout[OPT];
#pragma unroll
    for (int jj = 0; jj < OPT; jj++) {
        float v = acc[jj] + (BIAS ? bs[j0 + jj] : 0.f);
        if (RELU) v = fmaxf(v, 0.f);
        if (SCALE) v *= di;
        vout[jj] = v;
    }
    if constexpr (OBF) {
        // pack OPT (multiple of 8) bf16 into uint4s; fully coalesced 16B stores
        unsigned short* yr = (unsigned short*)yv + (size_t)gnode * OUT + j0;
#pragma unroll
        for (int q = 0; q < OPT / 8; q++) {
            uint4 pk;
            pk.x = (unsigned)f2bf(vout[q*8+0]) | ((unsigned)f2bf(vout[q*8+1]) << 16);
            pk.y = (unsigned)f2bf(vout[q*8+2]) | ((unsigned)f2bf(vout[q*8+3]) << 16);
            pk.z = (unsigned)f2bf(vout[q*8+4]) | ((unsigned)f2bf(vout[q*8+5]) << 16);
            pk.w = (unsigned)f2bf(vout[q*8+6]) | ((unsigned)f2bf(vout[q*8+7]) << 16);
            reinterpret_cast<uint4*>(yr)[q] = pk;
        }
    } else {
        float* yr = (float*)yv + (size_t)gnode * OUT + j0;
        if (OPT % 4 == 0) {
#pragma unroll
            for (int q = 0; q < OPT / 4; q++)
                *reinterpret_cast<float4*>(yr + q * 4) =
                    make_float4(vout[q*4+0], vout[q*4+1], vout[q*4+2], vout[q*4+3]);
        } else {
#pragma unroll
            for (int jj = 0; jj < OPT; jj++) yr[jj] = vout[jj];
        }
    }
}

// ---------------- pooling + log_softmax ----------------
__device__ inline unsigned fkey(float x) {
    unsigned u = __float_as_uint(x);
    return (u & 0x80000000u) ? ~u : (u | 0x80000000u);
}
__device__ inline float funkey(unsigned k) {
    unsigned u = (k & 0x80000000u) ? (k & 0x7FFFFFFFu) : ~k;
    return __uint_as_float(u);
}

__global__ void pool_init_k(unsigned* pooled, int total) {
    int i = blockIdx.x * blockDim.x + threadIdx.x;
    if (i < total) pooled[i] = 0u;
}

__global__ void pool_max_k(const float* __restrict__ h4, const float* __restrict__ b4,
                           const int* __restrict__ batch, unsigned* __restrict__ pooled,
                           int n, int num_graphs) {
    __shared__ unsigned lds[128 * 4];
    for (int i = threadIdx.x; i < num_graphs * 4; i += blockDim.x) lds[i] = 0u;
    __syncthreads();
    int i = blockIdx.x * blockDim.x + threadIdx.x;
    if (i < n) {
        int g = batch[i];
        float4 v = reinterpret_cast<const float4*>(h4)[i];
        atomicMax(&lds[g*4+0], fkey(v.x + b4[0]));
        atomicMax(&lds[g*4+1], fkey(v.y + b4[1]));
        atomicMax(&lds[g*4+2], fkey(v.z + b4[2]));
        atomicMax(&lds[g*4+3], fkey(v.w + b4[3]));
    }
    __syncthreads();
    for (int i2 = threadIdx.x; i2 < num_graphs * 4; i2 += blockDim.x) {
        unsigned k = lds[i2];
        if (k) atomicMax(&pooled[i2], k);
    }
}

__global__ void logsoftmax_k(const unsigned* __restrict__ pooled, float* __restrict__ out, int G) {
    int g = blockIdx.x * blockDim.x + threadIdx.x;
    if (g >= G) return;
    float v[4];
#pragma unroll
    for (int j = 0; j < 4; j++) v[j] = funkey(pooled[g*4+j]);
    float m = fmaxf(fmaxf(v[0], v[1]), fmaxf(v[2], v[3]));
    float s = 0.f;
#pragma unroll
    for (int j = 0; j < 4; j++) s += expf(v[j] - m);
    float l = logf(s);
#pragma unroll
    for (int j = 0; j < 4; j++) out[g*4+j] = v[j] - m - l;
}

// ---------------- launch ----------------
extern "C" void kernel_launch(void* const* d_in, const int* in_sizes, int n_in,
                              void* d_out, int out_size, void* d_ws, size_t ws_size,
                              hipStream_t stream) {
    const float* x     = (const float*)d_in[0];
    const int*   ei    = (const int*)d_in[1];
    const int*   batch = (const int*)d_in[2];
    const float* W1 = (const float*)d_in[3];
    const float* b1 = (const float*)d_in[4];
    const float* W2 = (const float*)d_in[5];
    const float* b2 = (const float*)d_in[6];
    const float* W3 = (const float*)d_in[7];
    const float* b3 = (const float*)d_in[8];
    const float* W4 = (const float*)d_in[9];
    const float* b4 = (const float*)d_in[10];

    const int N = in_sizes[2];          // 100000
    const int E = in_sizes[1] / 2;      // 3.2M
    const int G = 128;
    const int* row = ei;
    const int* col = ei + E;
    const int NB = DIV_UP(N, BNODES);   // 782 buckets

    // workspace layout
    float* ws    = (float*)d_ws;
    float* dinv  = ws;                              // N floats
    int*   cur   = (int*)(dinv + N);                // N ints
    int*   bhist = cur + N;                         // 1024 ints
    int*   bcur  = bhist + 1024;                    // 1024 ints
    int*   csr   = bcur + 1024;                     // E ints
    float* f16a  = (float*)(csr + E);               // N*16
    float* f16b  = f16a + (size_t)N * 16;           // N*16
    float* f32a  = f16b + (size_t)N * 16;           // N*32 (also part / hb32 / hb64)
    float* f32b  = f32a + (size_t)N * 32;           // N*32
    unsigned* pooled = (unsigned*)(f32b + (size_t)N * 32);  // 512
    int* part = (int*)f32a;                         // dead after csr_build
    unsigned short* hb32 = (unsigned short*)f32a;   // N*32 bf16 (dead after gather32)
    unsigned short* hb64 = (unsigned short*)f32a;   // N*64 bf16 = 32N floats exactly
    float* f4a = f32b;                              // after L3 matmul, f32b free
    float* f4b = f32b + (size_t)N * 4;

    const int B = 256;
    const int gridN = DIV_UP(N, B);
    const int gridM = DIV_UP(N, 64);    // tiled matmul: 64 nodes/block

    // CSR build: hist -> scan -> LDS-ranked partition -> per-bucket (tgt,src-chunk) sort
    zero_int_k<<<DIV_UP(1024, B), B, 0, stream>>>(bhist, 1024);
    bucket_hist_k<<<512, B, 0, stream>>>(col, bhist, E, NB);
    bucket_scan_k<<<1, 256, 0, stream>>>(bhist, bcur, NB);
    partition_k<<<DIV_UP(E, CHUNK_E), PTH, 0, stream>>>(row, col, bcur, part, E, NB);
    csr_build_k<<<NB, 256, 0, stream>>>(part, bcur, cur, dinv, csr, N);

    // L1: y1 = (x@W1)*dinv -> f16b ; gather+bias+relu+scale -> f16a
    matmul_k<128,16,false,false,true,false,false><<<gridM, B, 0, stream>>>(x, W1, nullptr, dinv, f16b, N);
    gather_prop_k<16,1><<<DIV_UP(N*4, B), B, 0, stream>>>(f16b, dinv, cur, csr, b1, f16a, N);

    // L2: gather f16a -> f16b (raw agg) ; matmul 16->32 +b2,relu,*dinv -> hb32 (bf16)
    gather_prop_k<16,0><<<DIV_UP(N*4, B), B, 0, stream>>>(f16a, dinv, cur, csr, nullptr, f16b, N);
    matmul_k<16,32,true,true,true,false,true><<<gridM, B, 0, stream>>>(f16b, W2, b2, dinv, hb32, N);

    // L3: bf16 gather hb32 -> f32b (fp32 agg) ; matmul 32->64 +b3,relu,*dinv -> hb64 (bf16)
    gather32_bf_k<<<DIV_UP(N*4, B), B, 0, stream>>>(hb32, dinv, cur, csr, f32b, N);
    matmul_k<32,64,true,true,true,false,true><<<gridM, B, 0, stream>>>(f32b, W3, b3, dinv, hb64, N);

    // L4: y4 = h3s@W4 (bf16 in) -> f4a (fp32) ; gather raw -> f4b
    matmul_k<64,4,false,false,false,true,false><<<gridM, B, 0, stream>>>(hb64, W4, nullptr, nullptr, f4a, N);
    gather_prop_k<4,0><<<DIV_UP(N, B), B, 0, stream>>>(f4a, dinv, cur, csr, nullptr, f4b, N);

    // pool (adds b4) + log_softmax
    pool_init_k<<<DIV_UP(G*4, B), B, 0, stream>>>(pooled, G*4);
    pool_max_k<<<gridN, B, 0, stream>>>(f4b, b4, batch, pooled, N, G);
    logsoftmax_k<<<1, 128, 0, stream>>>(pooled, (float*)d_out, G);
}

// Round 11
// 259.189 us; speedup vs baseline: 1.8336x; 1.0303x over previous
//
#include <hip/hip_runtime.h>

#define DIV_UP(a,b) (((a)+(b)-1)/(b))

// bucket = tgt >> 7  (128 nodes per bucket)
constexpr int BSHIFT = 7;
constexpr int BNODES = 128;
constexpr int CHUNK_E = 8192;    // edges per partition block (60KB LDS -> 2 blocks/CU)
constexpr int PTH = 256;         // partition block threads
constexpr int SCH = 8;           // source chunks for CSR segment ordering
constexpr int SCSH = 14;         // src >> 14 -> chunk id (16K nodes per chunk)

// ---------------- bf16 helpers (storage only; all math fp32) ----------------
__device__ inline unsigned short f2bf(float f) {
    unsigned u = __float_as_uint(f);
    u = u + 0x7FFFu + ((u >> 16) & 1u);   // round-to-nearest-even
    return (unsigned short)(u >> 16);
}
__device__ inline float bflo(unsigned u) { return __uint_as_float(u << 16); }
__device__ inline float bfhi(unsigned u) { return __uint_as_float(u & 0xFFFF0000u); }

// ---------------- CSR build via bucket counting sort ----------------
__global__ void zero_int_k(int* p, int n) {
    int i = blockIdx.x * blockDim.x + threadIdx.x;
    if (i < n) p[i] = 0;
}

__global__ void bucket_hist_k(const int* __restrict__ col, int* __restrict__ bhist, int E, int nb) {
    __shared__ int lh[1024];
    for (int i = threadIdx.x; i < 1024; i += blockDim.x) lh[i] = 0;
    __syncthreads();
    int stride = gridDim.x * blockDim.x;
    for (int e = blockIdx.x * blockDim.x + threadIdx.x; e < E; e += stride)
        atomicAdd(&lh[col[e] >> BSHIFT], 1);
    __syncthreads();
    for (int i = threadIdx.x; i < nb; i += blockDim.x) {
        int v = lh[i];
        if (v) atomicAdd(&bhist[i], v);
    }
}

// exclusive scan of nb (<=1024) bucket counts -> bcur
__global__ void bucket_scan_k(const int* __restrict__ bhist, int* __restrict__ bcur, int nb) {
    __shared__ int lds[256];
    int base = threadIdx.x * 4;
    int v[4]; int s = 0;
#pragma unroll
    for (int j = 0; j < 4; j++) { v[j] = (base + j < nb) ? bhist[base + j] : 0; s += v[j]; }
    lds[threadIdx.x] = s; __syncthreads();
    for (int off = 1; off < 256; off <<= 1) {
        int t = (threadIdx.x >= off) ? lds[threadIdx.x - off] : 0;
        __syncthreads();
        lds[threadIdx.x] += t;
        __syncthreads();
    }
    int excl = lds[threadIdx.x] - s;
#pragma unroll
    for (int j = 0; j < 4; j++) {
        if (base + j < nb) bcur[base + j] = excl;
        excl += v[j];
    }
}

// LDS-ranked partition (counting-sort pass): hist -> local scan -> bulk reserve ->
// rank into LDS-sorted chunk -> coalesced linear sweep to global.
__global__ void __launch_bounds__(PTH) partition_k(
        const int* __restrict__ row, const int* __restrict__ col,
        int* __restrict__ bcur, int* __restrict__ part, int E, int nb) {
    __shared__ int lh[1024];               // counts -> cursors
    __shared__ int lbase[1024];            // local exclusive bases
    __shared__ int delta[1024];            // scan temp (256) -> global_base - local_base
    __shared__ unsigned sorted[CHUNK_E];   // 32 KB
    __shared__ unsigned short bid[CHUNK_E];// 16 KB
    int tid = threadIdx.x;
    for (int i = tid; i < 1024; i += PTH) lh[i] = 0;
    __syncthreads();
    int base = blockIdx.x * CHUNK_E;
    int end = min(E, base + CHUNK_E);
    for (int e = base + tid; e < end; e += PTH)
        atomicAdd(&lh[col[e] >> BSHIFT], 1);
    __syncthreads();
    // block-wide exclusive scan of lh[0..1024): 4 cells/thread + HS over 256 partials
    int b4i = tid * 4;
    int c0 = lh[b4i], c1 = lh[b4i+1], c2 = lh[b4i+2], c3 = lh[b4i+3];
    int s = c0 + c1 + c2 + c3;
    delta[tid] = s;
    __syncthreads();
    for (int off = 1; off < 256; off <<= 1) {
        int t = (tid >= off) ? delta[tid - off] : 0;
        __syncthreads();
        delta[tid] += t;
        __syncthreads();
    }
    int excl = delta[tid] - s;
    lbase[b4i]     = excl;
    lbase[b4i + 1] = excl + c0;
    lbase[b4i + 2] = excl + c0 + c1;
    lbase[b4i + 3] = excl + c0 + c1 + c2;
    __syncthreads();
    // bulk-reserve global runs; delta[b] = global_base - local_base; reset cursors
    for (int i = tid; i < nb; i += PTH) {
        int c = lh[i];
        int g = c ? atomicAdd(&bcur[i], c) : 0;
        delta[i] = g - lbase[i];
    }
    __syncthreads();
    for (int i = tid; i < nb; i += PTH) lh[i] = lbase[i];
    __syncthreads();
    // rank into LDS-sorted chunk
    for (int e = base + tid; e < end; e += PTH) {
        int r = row[e], c = col[e];
        int b = c >> BSHIFT;
        int slot = atomicAdd(&lh[b], 1);
        sorted[slot] = (unsigned)((r << BSHIFT) | (c & (BNODES - 1)));
        bid[slot] = (unsigned short)b;
    }
    __syncthreads();
    // coalesced sweep: consecutive i -> consecutive global within each bucket run
    int cnt = end - base;
    for (int i = tid; i < cnt; i += PTH) {
        int b = bid[i];
        part[delta[b] + i] = (int)sorted[i];
    }
}

// one block per bucket: (target, src-chunk) counting sort -> csr ordered by src-chunk
__global__ void __launch_bounds__(256) csr_build_k(
        const int* __restrict__ part, const int* __restrict__ bcur,
        int* __restrict__ cur, float* __restrict__ dinv,
        int* __restrict__ csr, int N) {
    __shared__ int cnt[BNODES * SCH];
    __shared__ int scan_t[256];
    __shared__ int ebounds[2];
    int b = blockIdx.x;
    int tid = threadIdx.x;
    if (tid == 0) { ebounds[0] = b ? bcur[b - 1] : 0; ebounds[1] = bcur[b]; }
    for (int i = tid; i < BNODES * SCH; i += 256) cnt[i] = 0;
    __syncthreads();
    int e0 = ebounds[0], e1 = ebounds[1];
    for (int e = e0 + tid; e < e1; e += 256) {
        unsigned v = (unsigned)part[e];
        int cell = (int)(v & (BNODES - 1)) * SCH + (int)(v >> (BSHIFT + SCSH));
        atomicAdd(&cnt[cell], 1);
    }
    __syncthreads();
    int base4 = tid * 4;
    int c0 = cnt[base4], c1 = cnt[base4+1], c2 = cnt[base4+2], c3 = cnt[base4+3];
    int s = c0 + c1 + c2 + c3;
    scan_t[tid] = s;
    __syncthreads();
    for (int off = 1; off < 256; off <<= 1) {
        int t = (tid >= off) ? scan_t[tid - off] : 0;
        __syncthreads();
        scan_t[tid] += t;
        __syncthreads();
    }
    int excl = scan_t[tid] - s;
    cnt[base4]     = excl;
    cnt[base4 + 1] = excl + c0;
    cnt[base4 + 2] = excl + c0 + c1;
    cnt[base4 + 3] = excl + c0 + c1 + c2;
    __syncthreads();
    if (tid < BNODES) {
        int node = b * BNODES + tid;
        int segstart = cnt[tid * SCH];
        int segend   = (tid == BNODES - 1) ? (e1 - e0) : cnt[(tid + 1) * SCH];
        if (node < N) {
            cur[node]  = e0 + segend;
            dinv[node] = rsqrtf(1.0f + (float)(segend - segstart));
        }
    }
    __syncthreads();
    for (int e = e0 + tid; e < e1; e += 256) {
        unsigned v = (unsigned)part[e];
        int cell = (int)(v & (BNODES - 1)) * SCH + (int)(v >> (BSHIFT + SCSH));
        int p = atomicAdd(&cnt[cell], 1);
        csr[e0 + p] = (int)(v >> BSHIFT);
    }
}

// ---------------- gather, bf16 rows, D=16 (row = 32B); 2 threads/node ----------------
// EPI 1: out bf16 = relu(acc*di + b)*di   (feeds next bf16 gather)
// EPI 0: out fp32 = acc*di                (feeds matmul)
template<int EPI>
__global__ void __launch_bounds__(256) gather16_bf_k(
        const unsigned short* __restrict__ hb, const float* __restrict__ dinv,
        const int* __restrict__ cur, const int* __restrict__ csr,
        const float* __restrict__ b, void* __restrict__ outv, int n) {
    int t2 = blockIdx.x * 256 + threadIdx.x;
    int node = t2 >> 1, t = t2 & 1;
    if (node >= n) return;
    const uint4* hb4 = reinterpret_cast<const uint4*>(hb);
    uint4 sv = hb4[(size_t)node * 2 + t];
    float a0 = bflo(sv.x), a1 = bfhi(sv.x), a2 = bflo(sv.y), a3 = bfhi(sv.y);
    float a4 = bflo(sv.z), a5 = bfhi(sv.z), a6 = bflo(sv.w), a7 = bfhi(sv.w);
    int e0 = node ? cur[node - 1] : 0;
    int e1 = cur[node];
    int e = e0;
    for (; e + 1 < e1; e += 2) {
        uint4 v = hb4[(size_t)csr[e] * 2 + t];
        uint4 w = hb4[(size_t)csr[e + 1] * 2 + t];
        a0 += bflo(v.x) + bflo(w.x); a1 += bfhi(v.x) + bfhi(w.x);
        a2 += bflo(v.y) + bflo(w.y); a3 += bfhi(v.y) + bfhi(w.y);
        a4 += bflo(v.z) + bflo(w.z); a5 += bfhi(v.z) + bfhi(w.z);
        a6 += bflo(v.w) + bflo(w.w); a7 += bfhi(v.w) + bfhi(w.w);
    }
    if (e < e1) {
        uint4 v = hb4[(size_t)csr[e] * 2 + t];
        a0 += bflo(v.x); a1 += bfhi(v.x); a2 += bflo(v.y); a3 += bfhi(v.y);
        a4 += bflo(v.z); a5 += bfhi(v.z); a6 += bflo(v.w); a7 += bfhi(v.w);
    }
    float di = dinv[node];
    a0 *= di; a1 *= di; a2 *= di; a3 *= di;
    a4 *= di; a5 *= di; a6 *= di; a7 *= di;
    if constexpr (EPI == 1) {
        int bo = t * 8;
        a0 = fmaxf(a0 + b[bo+0], 0.f) * di; a1 = fmaxf(a1 + b[bo+1], 0.f) * di;
        a2 = fmaxf(a2 + b[bo+2], 0.f) * di; a3 = fmaxf(a3 + b[bo+3], 0.f) * di;
        a4 = fmaxf(a4 + b[bo+4], 0.f) * di; a5 = fmaxf(a5 + b[bo+5], 0.f) * di;
        a6 = fmaxf(a6 + b[bo+6], 0.f) * di; a7 = fmaxf(a7 + b[bo+7], 0.f) * di;
        uint4 pk;
        pk.x = (unsigned)f2bf(a0) | ((unsigned)f2bf(a1) << 16);
        pk.y = (unsigned)f2bf(a2) | ((unsigned)f2bf(a3) << 16);
        pk.z = (unsigned)f2bf(a4) | ((unsigned)f2bf(a5) << 16);
        pk.w = (unsigned)f2bf(a6) | ((unsigned)f2bf(a7) << 16);
        reinterpret_cast<uint4*>(outv)[(size_t)node * 2 + t] = pk;
    } else {
        float* op = (float*)outv + (size_t)node * 16 + t * 8;
        *reinterpret_cast<float4*>(op)     = make_float4(a0, a1, a2, a3);
        *reinterpret_cast<float4*>(op + 4) = make_float4(a4, a5, a6, a7);
    }
}

// ---------------- gather, bf16 rows, D=32 (row = 64B = 1 line); 4 threads/node ------
__global__ void __launch_bounds__(256) gather32_bf_k(
        const unsigned short* __restrict__ hb, const float* __restrict__ dinv,
        const int* __restrict__ cur, const int* __restrict__ csr,
        float* __restrict__ out, int n) {
    int tid4 = blockIdx.x * 256 + threadIdx.x;
    int node = tid4 >> 2, t = tid4 & 3;
    if (node >= n) return;
    const uint4* hb4 = reinterpret_cast<const uint4*>(hb);
    uint4 sv = hb4[(size_t)node * 4 + t];
    float a0 = bflo(sv.x), a1 = bfhi(sv.x), a2 = bflo(sv.y), a3 = bfhi(sv.y);
    float a4 = bflo(sv.z), a5 = bfhi(sv.z), a6 = bflo(sv.w), a7 = bfhi(sv.w);
    int e0 = node ? cur[node - 1] : 0;
    int e1 = cur[node];
    int e = e0;
    for (; e + 1 < e1; e += 2) {
        uint4 v = hb4[(size_t)csr[e] * 4 + t];
        uint4 w = hb4[(size_t)csr[e + 1] * 4 + t];
        a0 += bflo(v.x) + bflo(w.x); a1 += bfhi(v.x) + bfhi(w.x);
        a2 += bflo(v.y) + bflo(w.y); a3 += bfhi(v.y) + bfhi(w.y);
        a4 += bflo(v.z) + bflo(w.z); a5 += bfhi(v.z) + bfhi(w.z);
        a6 += bflo(v.w) + bflo(w.w); a7 += bfhi(v.w) + bfhi(w.w);
    }
    if (e < e1) {
        uint4 v = hb4[(size_t)csr[e] * 4 + t];
        a0 += bflo(v.x); a1 += bfhi(v.x); a2 += bflo(v.y); a3 += bfhi(v.y);
        a4 += bflo(v.z); a5 += bfhi(v.z); a6 += bflo(v.w); a7 += bfhi(v.w);
    }
    float di = dinv[node];
    float* op = out + (size_t)node * 32 + t * 8;
    *reinterpret_cast<float4*>(op)     = make_float4(a0*di, a1*di, a2*di, a3*di);
    *reinterpret_cast<float4*>(op + 4) = make_float4(a4*di, a5*di, a6*di, a7*di);
}

// ---------------- pooling helpers ----------------
__device__ inline unsigned fkey(float x) {
    unsigned u = __float_as_uint(x);
    return (u & 0x80000000u) ? ~u : (u | 0x80000000u);
}
__device__ inline float funkey(unsigned k) {
    unsigned u = (k & 0x80000000u) ? (k & 0x7FFFFFFFu) : ~k;
    return __uint_as_float(u);
}

// ---------------- fused final gather (D=4) + segment-max pool ----------------
__global__ void gather4_pool_k(const float* __restrict__ hs, const float* __restrict__ dinv,
                               const int* __restrict__ cur, const int* __restrict__ csr,
                               const float* __restrict__ b4, const int* __restrict__ batch,
                               unsigned* __restrict__ pooled, int n, int num_graphs) {
    __shared__ unsigned lds[128 * 4];
    for (int i = threadIdx.x; i < num_graphs * 4; i += blockDim.x) lds[i] = 0u;
    __syncthreads();
    int node = blockIdx.x * blockDim.x + threadIdx.x;
    if (node < n) {
        float di = dinv[node];
        float4 acc = reinterpret_cast<const float4*>(hs)[node];
        int e0 = node ? cur[node - 1] : 0;
        int e1 = cur[node];
        int e = e0;
        for (; e + 1 < e1; e += 2) {
            int s0 = csr[e], s1 = csr[e + 1];
            float4 v0 = reinterpret_cast<const float4*>(hs)[s0];
            float4 v1 = reinterpret_cast<const float4*>(hs)[s1];
            acc.x += v0.x + v1.x; acc.y += v0.y + v1.y;
            acc.z += v0.z + v1.z; acc.w += v0.w + v1.w;
        }
        if (e < e1) {
            float4 v0 = reinterpret_cast<const float4*>(hs)[csr[e]];
            acc.x += v0.x; acc.y += v0.y; acc.z += v0.z; acc.w += v0.w;
        }
        int g = batch[node];
        atomicMax(&lds[g*4+0], fkey(acc.x * di + b4[0]));
        atomicMax(&lds[g*4+1], fkey(acc.y * di + b4[1]));
        atomicMax(&lds[g*4+2], fkey(acc.z * di + b4[2]));
        atomicMax(&lds[g*4+3], fkey(acc.w * di + b4[3]));
    }
    __syncthreads();
    for (int i2 = threadIdx.x; i2 < num_graphs * 4; i2 += blockDim.x) {
        unsigned k = lds[i2];
        if (k) atomicMax(&pooled[i2], k);
    }
}

__global__ void pool_init_k(unsigned* pooled, int total) {
    int i = blockIdx.x * blockDim.x + threadIdx.x;
    if (i < total) pooled[i] = 0u;
}

__global__ void logsoftmax_k(const unsigned* __restrict__ pooled, float* __restrict__ out, int G) {
    int g = blockIdx.x * blockDim.x + threadIdx.x;
    if (g >= G) return;
    float v[4];
#pragma unroll
    for (int j = 0; j < 4; j++) v[j] = funkey(pooled[g*4+j]);
    float m = fmaxf(fmaxf(v[0], v[1]), fmaxf(v[2], v[3]));
    float s = 0.f;
#pragma unroll
    for (int j = 0; j < 4; j++) s += expf(v[j] - m);
    float l = logf(s);
#pragma unroll
    for (int j = 0; j < 4; j++) out[g*4+j] = v[j] - m - l;
}

// ---------------- LDS-tiled skinny matmul with optional bf16 in/out ----------------
template<int IN, int OUT, bool RELU, bool BIAS, bool SCALE, bool IBF, bool OBF>
__global__ void __launch_bounds__(256) matmul_k(
        const void* __restrict__ xv, const float* __restrict__ W,
        const float* __restrict__ b, const float* __restrict__ dinv,
        void* __restrict__ yv, int n) {
    constexpr int TN  = 64;
    constexpr int RS  = IN + 4;
    constexpr int OPT = OUT / 4;
    constexpr int NQ  = IN / 4;
    __shared__ float xs[TN * RS];
    __shared__ float Ws[IN * OUT];
    __shared__ float bs[OUT];

    for (int i = threadIdx.x; i < IN * OUT; i += 256) Ws[i] = W[i];
    if (BIAS) for (int i = threadIdx.x; i < OUT; i += 256) bs[i] = b[i];

    int base = blockIdx.x * TN;
    if constexpr (!IBF) {
        const float* x = (const float*)xv;
        for (int i = threadIdx.x; i < TN * NQ; i += 256) {
            int r = i / NQ, c = i % NQ;
            float4 v = make_float4(0.f, 0.f, 0.f, 0.f);
            if (base + r < n) v = reinterpret_cast<const float4*>(x + (size_t)(base + r) * IN)[c];
            *reinterpret_cast<float4*>(&xs[r * RS + c * 4]) = v;
        }
    } else {
        constexpr int NU = IN / 8;   // uint4 (8 bf16) per row
        const uint4* x = (const uint4*)xv;
        for (int i = threadIdx.x; i < TN * NU; i += 256) {
            int r = i / NU, c = i % NU;
            uint4 v = make_uint4(0u, 0u, 0u, 0u);
            if (base + r < n) v = x[(size_t)(base + r) * NU + c];
            float* dst = &xs[r * RS + c * 8];
            dst[0] = bflo(v.x); dst[1] = bfhi(v.x);
            dst[2] = bflo(v.y); dst[3] = bfhi(v.y);
            dst[4] = bflo(v.z); dst[5] = bfhi(v.z);
            dst[6] = bflo(v.w); dst[7] = bfhi(v.w);
        }
    }
    __syncthreads();

    int node = threadIdx.x >> 2;
    int g    = threadIdx.x & 3;
    int j0   = g * OPT;
    int gnode = base + node;
    if (gnode >= n) return;

    float acc[OPT];
#pragma unroll
    for (int jj = 0; jj < OPT; jj++) acc[jj] = 0.f;

    const float* xrow = &xs[node * RS];
#pragma unroll
    for (int k4 = 0; k4 < NQ; k4++) {
        float4 xvv = *reinterpret_cast<const float4*>(&xrow[k4 * 4]);
        float xk[4] = {xvv.x, xvv.y, xvv.z, xvv.w};
#pragma unroll
        for (int kk = 0; kk < 4; kk++) {
            const float* wrow = &Ws[(k4 * 4 + kk) * OUT + j0];
#pragma unroll
            for (int jj = 0; jj < OPT; jj++)
                acc[jj] += xk[kk] * wrow[jj];
        }
    }

    float di = SCALE ? dinv[gnode] : 1.f;
    float vout[OPT];
#pragma unroll
    for (int jj = 0; jj < OPT; jj++) {
        float v = acc[jj] + (BIAS ? bs[j0 + jj] : 0.f);
        if (RELU) v = fmaxf(v, 0.f);
        if (SCALE) v *= di;
        vout[jj] = v;
    }
    if constexpr (OBF) {
        unsigned short* yr = (unsigned short*)yv + (size_t)gnode * OUT + j0;
        if constexpr (OPT % 8 == 0) {
#pragma unroll
            for (int q = 0; q < OPT / 8; q++) {
                uint4 pk;
                pk.x = (unsigned)f2bf(vout[q*8+0]) | ((unsigned)f2bf(vout[q*8+1]) << 16);
                pk.y = (unsigned)f2bf(vout[q*8+2]) | ((unsigned)f2bf(vout[q*8+3]) << 16);
                pk.z = (unsigned)f2bf(vout[q*8+4]) | ((unsigned)f2bf(vout[q*8+5]) << 16);
                pk.w = (unsigned)f2bf(vout[q*8+6]) | ((unsigned)f2bf(vout[q*8+7]) << 16);
                reinterpret_cast<uint4*>(yr)[q] = pk;
            }
        } else {   // OPT == 4
            uint2 pk;
            pk.x = (unsigned)f2bf(vout[0]) | ((unsigned)f2bf(vout[1]) << 16);
            pk.y = (unsigned)f2bf(vout[2]) | ((unsigned)f2bf(vout[3]) << 16);
            *reinterpret_cast<uint2*>(yr) = pk;
        }
    } else {
        float* yr = (float*)yv + (size_t)gnode * OUT + j0;
        if (OPT % 4 == 0) {
#pragma unroll
            for (int q = 0; q < OPT / 4; q++)
                *reinterpret_cast<float4*>(yr + q * 4) =
                    make_float4(vout[q*4+0], vout[q*4+1], vout[q*4+2], vout[q*4+3]);
        } else {
#pragma unroll
            for (int jj = 0; jj < OPT; jj++) yr[jj] = vout[jj];
        }
    }
}

// ---------------- launch ----------------
extern "C" void kernel_launch(void* const* d_in, const int* in_sizes, int n_in,
                              void* d_out, int out_size, void* d_ws, size_t ws_size,
                              hipStream_t stream) {
    const float* x     = (const float*)d_in[0];
    const int*   ei    = (const int*)d_in[1];
    const int*   batch = (const int*)d_in[2];
    const float* W1 = (const float*)d_in[3];
    const float* b1 = (const float*)d_in[4];
    const float* W2 = (const float*)d_in[5];
    const float* b2 = (const float*)d_in[6];
    const float* W3 = (const float*)d_in[7];
    const float* b3 = (const float*)d_in[8];
    const float* W4 = (const float*)d_in[9];
    const float* b4 = (const float*)d_in[10];

    const int N = in_sizes[2];          // 100000
    const int E = in_sizes[1] / 2;      // 3.2M
    const int G = 128;
    const int* row = ei;
    const int* col = ei + E;
    const int NB = DIV_UP(N, BNODES);   // 782 buckets

    // workspace layout
    float* ws    = (float*)d_ws;
    float* dinv  = ws;                              // N floats
    int*   cur   = (int*)(dinv + N);                // N ints
    int*   bhist = cur + N;                         // 1024 ints
    int*   bcur  = bhist + 1024;                    // 1024 ints
    int*   csr   = bcur + 1024;                     // E ints
    float* f16a  = (float*)(csr + E);               // N*16 floats region
    float* f16b  = f16a + (size_t)N * 16;           // N*16 floats region
    float* f32a  = f16b + (size_t)N * 16;           // N*32 floats region
    float* f32b  = f32a + (size_t)N * 32;           // N*32 floats region
    unsigned* pooled = (unsigned*)(f32b + (size_t)N * 32);  // 512
    int* part = (int*)f32a;                         // dead after csr_build
    unsigned short* hb16a = (unsigned short*)f16a;  // N*16 bf16
    unsigned short* hb16b = (unsigned short*)f16b;  // N*16 bf16
    unsigned short* hb32  = (unsigned short*)f32a;  // N*32 bf16 (after part dead)
    unsigned short* hb64  = (unsigned short*)f32a;  // N*64 bf16 = 32N floats exactly
    float* f4a = f32b;                              // after L3 matmul, f32b free
    // f16b fp32 region reused for agg2 (fp32 N*16)

    const int B = 256;
    const int gridN = DIV_UP(N, B);
    const int gridM = DIV_UP(N, 64);    // tiled matmul: 64 nodes/block
    const int grid2 = DIV_UP(2 * N, B); // 2 threads/node gathers

    // CSR build: hist -> scan -> LDS-ranked partition -> per-bucket (tgt,src-chunk) sort
    zero_int_k<<<DIV_UP(1024, B), B, 0, stream>>>(bhist, 1024);
    bucket_hist_k<<<512, B, 0, stream>>>(col, bhist, E, NB);
    bucket_scan_k<<<1, 256, 0, stream>>>(bhist, bcur, NB);
    partition_k<<<DIV_UP(E, CHUNK_E), PTH, 0, stream>>>(row, col, bcur, part, E, NB);
    csr_build_k<<<NB, 256, 0, stream>>>(part, bcur, cur, dinv, csr, N);

    // L1: y1 = (x@W1)*dinv -> hb16b (bf16) ; gather+bias+relu+scale -> hb16a (bf16)
    matmul_k<128,16,false,false,true,false,true><<<gridM, B, 0, stream>>>(x, W1, nullptr, dinv, hb16b, N);
    gather16_bf_k<1><<<grid2, B, 0, stream>>>(hb16b, dinv, cur, csr, b1, hb16a, N);

    // L2: gather hb16a -> agg2 fp32 (reuse f16b region... but hb16b lives there; use f32b)
    gather16_bf_k<0><<<grid2, B, 0, stream>>>(hb16a, dinv, cur, csr, nullptr, f32b, N);
    //     matmul 16->32 +b2,relu,*dinv -> hb32 (bf16, in f32a region after part dead)
    matmul_k<16,32,true,true,true,false,true><<<gridM, B, 0, stream>>>(f32b, W2, b2, dinv, hb32, N);

    // L3: bf16 gather hb32 -> f32b (fp32 agg) ; matmul 32->64 +b3,relu,*dinv -> hb64 (bf16)
    gather32_bf_k<<<DIV_UP(N*4, B), B, 0, stream>>>(hb32, dinv, cur, csr, f32b, N);
    matmul_k<32,64,true,true,true,false,true><<<gridM, B, 0, stream>>>(f32b, W3, b3, dinv, hb64, N);

    // L4: y4 = h3s@W4 (bf16 in) -> f4a (fp32) ; fused gather+pool (adds b4)
    matmul_k<64,4,false,false,false,true,false><<<gridM, B, 0, stream>>>(hb64, W4, nullptr, nullptr, f4a, N);
    pool_init_k<<<DIV_UP(G*4, B), B, 0, stream>>>(pooled, G*4);
    gather4_pool_k<<<gridN, B, 0, stream>>>(f4a, dinv, cur, csr, b4, batch, pooled, N, G);

    // log_softmax
    logsoftmax_k<<<1, 128, 0, stream>>>(pooled, (float*)d_out, G);
}

// Round 12
// 242.864 us; speedup vs baseline: 1.9569x; 1.0672x over previous
//
#include <hip/hip_runtime.h>

#define DIV_UP(a,b) (((a)+(b)-1)/(b))

// bucket = tgt >> 7  (128 nodes per bucket)
constexpr int BSHIFT = 7;
constexpr int BNODES = 128;
constexpr int CHUNK_E = 16384;   // edges per partition block (measured best, r10: 39us)
constexpr int PTH = 512;         // partition block threads
constexpr int SCH = 8;           // source chunks for CSR segment ordering
constexpr int SCSH = 14;         // src >> 14 -> chunk id (16K nodes per chunk)

// ---------------- bf16 helpers (storage only; all math fp32) ----------------
__device__ inline unsigned short f2bf(float f) {
    unsigned u = __float_as_uint(f);
    u = u + 0x7FFFu + ((u >> 16) & 1u);   // round-to-nearest-even
    return (unsigned short)(u >> 16);
}
__device__ inline float bflo(unsigned u) { return __uint_as_float(u << 16); }
__device__ inline float bfhi(unsigned u) { return __uint_as_float(u & 0xFFFF0000u); }

// ---------------- CSR build via bucket counting sort ----------------
__global__ void zero_int_k(int* p, int n) {
    int i = blockIdx.x * blockDim.x + threadIdx.x;
    if (i < n) p[i] = 0;
}

__global__ void bucket_hist_k(const int* __restrict__ col, int* __restrict__ bhist, int E, int nb) {
    __shared__ int lh[1024];
    for (int i = threadIdx.x; i < 1024; i += blockDim.x) lh[i] = 0;
    __syncthreads();
    int stride = gridDim.x * blockDim.x;
    for (int e = blockIdx.x * blockDim.x + threadIdx.x; e < E; e += stride)
        atomicAdd(&lh[col[e] >> BSHIFT], 1);
    __syncthreads();
    for (int i = threadIdx.x; i < nb; i += blockDim.x) {
        int v = lh[i];
        if (v) atomicAdd(&bhist[i], v);
    }
}

// exclusive scan of nb (<=1024) bucket counts -> bcur
__global__ void bucket_scan_k(const int* __restrict__ bhist, int* __restrict__ bcur, int nb) {
    __shared__ int lds[256];
    int base = threadIdx.x * 4;
    int v[4]; int s = 0;
#pragma unroll
    for (int j = 0; j < 4; j++) { v[j] = (base + j < nb) ? bhist[base + j] : 0; s += v[j]; }
    lds[threadIdx.x] = s; __syncthreads();
    for (int off = 1; off < 256; off <<= 1) {
        int t = (threadIdx.x >= off) ? lds[threadIdx.x - off] : 0;
        __syncthreads();
        lds[threadIdx.x] += t;
        __syncthreads();
    }
    int excl = lds[threadIdx.x] - s;
#pragma unroll
    for (int j = 0; j < 4; j++) {
        if (base + j < nb) bcur[base + j] = excl;
        excl += v[j];
    }
}

// LDS-ranked partition (counting-sort pass): hist -> local scan -> bulk reserve ->
// rank into LDS-sorted chunk -> coalesced linear sweep to global.
__global__ void __launch_bounds__(PTH) partition_k(
        const int* __restrict__ row, const int* __restrict__ col,
        int* __restrict__ bcur, int* __restrict__ part, int E, int nb) {
    __shared__ int lh[1024];               // counts -> cursors
    __shared__ int lbase[1024];            // local exclusive bases
    __shared__ int delta[1024];            // scan temp (512) -> global_base - local_base
    __shared__ unsigned sorted[CHUNK_E];   // 64 KB
    __shared__ unsigned short bid[CHUNK_E];// 32 KB
    int tid = threadIdx.x;
    for (int i = tid; i < 1024; i += PTH) lh[i] = 0;
    __syncthreads();
    int base = blockIdx.x * CHUNK_E;
    int end = min(E, base + CHUNK_E);
    for (int e = base + tid; e < end; e += PTH)
        atomicAdd(&lh[col[e] >> BSHIFT], 1);
    __syncthreads();
    // block-wide exclusive scan of lh[0..1024): 2 elems/thread + HS over 512 partials
    int v0 = lh[2 * tid], v1 = lh[2 * tid + 1];
    int s = v0 + v1;
    delta[tid] = s;
    __syncthreads();
    for (int off = 1; off < PTH; off <<= 1) {
        int t = (tid >= off) ? delta[tid - off] : 0;
        __syncthreads();
        delta[tid] += t;
        __syncthreads();
    }
    int excl = delta[tid] - s;
    lbase[2 * tid] = excl;
    lbase[2 * tid + 1] = excl + v0;
    __syncthreads();
    // bulk-reserve global runs; delta[b] = global_base - local_base; reset cursors
    for (int i = tid; i < nb; i += PTH) {
        int c = lh[i];
        int g = c ? atomicAdd(&bcur[i], c) : 0;
        delta[i] = g - lbase[i];
    }
    __syncthreads();
    for (int i = tid; i < nb; i += PTH) lh[i] = lbase[i];
    __syncthreads();
    // rank into LDS-sorted chunk
    for (int e = base + tid; e < end; e += PTH) {
        int r = row[e], c = col[e];
        int b = c >> BSHIFT;
        int slot = atomicAdd(&lh[b], 1);
        sorted[slot] = (unsigned)((r << BSHIFT) | (c & (BNODES - 1)));
        bid[slot] = (unsigned short)b;
    }
    __syncthreads();
    // coalesced sweep: consecutive i -> consecutive global within each bucket run
    int cnt = end - base;
    for (int i = tid; i < cnt; i += PTH) {
        int b = bid[i];
        part[delta[b] + i] = (int)sorted[i];
    }
}

// one block per bucket: (target, src-chunk) counting sort -> csr ordered by src-chunk
__global__ void __launch_bounds__(256) csr_build_k(
        const int* __restrict__ part, const int* __restrict__ bcur,
        int* __restrict__ cur, float* __restrict__ dinv,
        int* __restrict__ csr, int N) {
    __shared__ int cnt[BNODES * SCH];
    __shared__ int scan_t[256];
    __shared__ int ebounds[2];
    int b = blockIdx.x;
    int tid = threadIdx.x;
    if (tid == 0) { ebounds[0] = b ? bcur[b - 1] : 0; ebounds[1] = bcur[b]; }
    for (int i = tid; i < BNODES * SCH; i += 256) cnt[i] = 0;
    __syncthreads();
    int e0 = ebounds[0], e1 = ebounds[1];
    for (int e = e0 + tid; e < e1; e += 256) {
        unsigned v = (unsigned)part[e];
        int cell = (int)(v & (BNODES - 1)) * SCH + (int)(v >> (BSHIFT + SCSH));
        atomicAdd(&cnt[cell], 1);
    }
    __syncthreads();
    int base4 = tid * 4;
    int c0 = cnt[base4], c1 = cnt[base4+1], c2 = cnt[base4+2], c3 = cnt[base4+3];
    int s = c0 + c1 + c2 + c3;
    scan_t[tid] = s;
    __syncthreads();
    for (int off = 1; off < 256; off <<= 1) {
        int t = (tid >= off) ? scan_t[tid - off] : 0;
        __syncthreads();
        scan_t[tid] += t;
        __syncthreads();
    }
    int excl = scan_t[tid] - s;
    cnt[base4]     = excl;
    cnt[base4 + 1] = excl + c0;
    cnt[base4 + 2] = excl + c0 + c1;
    cnt[base4 + 3] = excl + c0 + c1 + c2;
    __syncthreads();
    if (tid < BNODES) {
        int node = b * BNODES + tid;
        int segstart = cnt[tid * SCH];
        int segend   = (tid == BNODES - 1) ? (e1 - e0) : cnt[(tid + 1) * SCH];
        if (node < N) {
            cur[node]  = e0 + segend;
            dinv[node] = rsqrtf(1.0f + (float)(segend - segstart));
        }
    }
    __syncthreads();
    for (int e = e0 + tid; e < e1; e += 256) {
        unsigned v = (unsigned)part[e];
        int cell = (int)(v & (BNODES - 1)) * SCH + (int)(v >> (BSHIFT + SCSH));
        int p = atomicAdd(&cnt[cell], 1);
        csr[e0 + p] = (int)(v >> BSHIFT);
    }
}

// ---------------- gather, bf16 rows, D=16 (row = 32B); 2 threads/node ----------------
// EPI 1: out bf16 = relu(acc*di + b)*di ; EPI 0: out fp32 = acc*di
template<int EPI>
__global__ void __launch_bounds__(256) gather16_bf_k(
        const unsigned short* __restrict__ hb, const float* __restrict__ dinv,
        const int* __restrict__ cur, const int* __restrict__ csr,
        const float* __restrict__ b, void* __restrict__ outv, int n) {
    int t2 = blockIdx.x * 256 + threadIdx.x;
    int node = t2 >> 1, t = t2 & 1;
    if (node >= n) return;
    const uint4* hb4 = reinterpret_cast<const uint4*>(hb);
    uint4 sv = hb4[(size_t)node * 2 + t];
    float a0 = bflo(sv.x), a1 = bfhi(sv.x), a2 = bflo(sv.y), a3 = bfhi(sv.y);
    float a4 = bflo(sv.z), a5 = bfhi(sv.z), a6 = bflo(sv.w), a7 = bfhi(sv.w);
    int e0 = node ? cur[node - 1] : 0;
    int e1 = cur[node];
    int e = e0;
    for (; e + 3 < e1; e += 4) {          // 4-way: 4 random loads in flight
        int s0 = csr[e], s1 = csr[e+1], s2 = csr[e+2], s3 = csr[e+3];
        uint4 v0 = hb4[(size_t)s0 * 2 + t];
        uint4 v1 = hb4[(size_t)s1 * 2 + t];
        uint4 v2 = hb4[(size_t)s2 * 2 + t];
        uint4 v3 = hb4[(size_t)s3 * 2 + t];
        a0 += (bflo(v0.x) + bflo(v1.x)) + (bflo(v2.x) + bflo(v3.x));
        a1 += (bfhi(v0.x) + bfhi(v1.x)) + (bfhi(v2.x) + bfhi(v3.x));
        a2 += (bflo(v0.y) + bflo(v1.y)) + (bflo(v2.y) + bflo(v3.y));
        a3 += (bfhi(v0.y) + bfhi(v1.y)) + (bfhi(v2.y) + bfhi(v3.y));
        a4 += (bflo(v0.z) + bflo(v1.z)) + (bflo(v2.z) + bflo(v3.z));
        a5 += (bfhi(v0.z) + bfhi(v1.z)) + (bfhi(v2.z) + bfhi(v3.z));
        a6 += (bflo(v0.w) + bflo(v1.w)) + (bflo(v2.w) + bflo(v3.w));
        a7 += (bfhi(v0.w) + bfhi(v1.w)) + (bfhi(v2.w) + bfhi(v3.w));
    }
    for (; e < e1; e++) {
        uint4 v = hb4[(size_t)csr[e] * 2 + t];
        a0 += bflo(v.x); a1 += bfhi(v.x); a2 += bflo(v.y); a3 += bfhi(v.y);
        a4 += bflo(v.z); a5 += bfhi(v.z); a6 += bflo(v.w); a7 += bfhi(v.w);
    }
    float di = dinv[node];
    a0 *= di; a1 *= di; a2 *= di; a3 *= di;
    a4 *= di; a5 *= di; a6 *= di; a7 *= di;
    if constexpr (EPI == 1) {
        int bo = t * 8;
        a0 = fmaxf(a0 + b[bo+0], 0.f) * di; a1 = fmaxf(a1 + b[bo+1], 0.f) * di;
        a2 = fmaxf(a2 + b[bo+2], 0.f) * di; a3 = fmaxf(a3 + b[bo+3], 0.f) * di;
        a4 = fmaxf(a4 + b[bo+4], 0.f) * di; a5 = fmaxf(a5 + b[bo+5], 0.f) * di;
        a6 = fmaxf(a6 + b[bo+6], 0.f) * di; a7 = fmaxf(a7 + b[bo+7], 0.f) * di;
        uint4 pk;
        pk.x = (unsigned)f2bf(a0) | ((unsigned)f2bf(a1) << 16);
        pk.y = (unsigned)f2bf(a2) | ((unsigned)f2bf(a3) << 16);
        pk.z = (unsigned)f2bf(a4) | ((unsigned)f2bf(a5) << 16);
        pk.w = (unsigned)f2bf(a6) | ((unsigned)f2bf(a7) << 16);
        reinterpret_cast<uint4*>(outv)[(size_t)node * 2 + t] = pk;
    } else {
        float* op = (float*)outv + (size_t)node * 16 + t * 8;
        *reinterpret_cast<float4*>(op)     = make_float4(a0, a1, a2, a3);
        *reinterpret_cast<float4*>(op + 4) = make_float4(a4, a5, a6, a7);
    }
}

// ---------------- gather, bf16 rows, D=32 (row = 64B = 1 line); 4 threads/node ------
__global__ void __launch_bounds__(256) gather32_bf_k(
        const unsigned short* __restrict__ hb, const float* __restrict__ dinv,
        const int* __restrict__ cur, const int* __restrict__ csr,
        float* __restrict__ out, int n) {
    int tid4 = blockIdx.x * 256 + threadIdx.x;
    int node = tid4 >> 2, t = tid4 & 3;
    if (node >= n) return;
    const uint4* hb4 = reinterpret_cast<const uint4*>(hb);
    uint4 sv = hb4[(size_t)node * 4 + t];
    float a0 = bflo(sv.x), a1 = bfhi(sv.x), a2 = bflo(sv.y), a3 = bfhi(sv.y);
    float a4 = bflo(sv.z), a5 = bfhi(sv.z), a6 = bflo(sv.w), a7 = bfhi(sv.w);
    int e0 = node ? cur[node - 1] : 0;
    int e1 = cur[node];
    int e = e0;
    for (; e + 3 < e1; e += 4) {
        int s0 = csr[e], s1 = csr[e+1], s2 = csr[e+2], s3 = csr[e+3];
        uint4 v0 = hb4[(size_t)s0 * 4 + t];
        uint4 v1 = hb4[(size_t)s1 * 4 + t];
        uint4 v2 = hb4[(size_t)s2 * 4 + t];
        uint4 v3 = hb4[(size_t)s3 * 4 + t];
        a0 += (bflo(v0.x) + bflo(v1.x)) + (bflo(v2.x) + bflo(v3.x));
        a1 += (bfhi(v0.x) + bfhi(v1.x)) + (bfhi(v2.x) + bfhi(v3.x));
        a2 += (bflo(v0.y) + bflo(v1.y)) + (bflo(v2.y) + bflo(v3.y));
        a3 += (bfhi(v0.y) + bfhi(v1.y)) + (bfhi(v2.y) + bfhi(v3.y));
        a4 += (bflo(v0.z) + bflo(v1.z)) + (bflo(v2.z) + bflo(v3.z));
        a5 += (bfhi(v0.z) + bfhi(v1.z)) + (bfhi(v2.z) + bfhi(v3.z));
        a6 += (bflo(v0.w) + bflo(v1.w)) + (bflo(v2.w) + bflo(v3.w));
        a7 += (bfhi(v0.w) + bfhi(v1.w)) + (bfhi(v2.w) + bfhi(v3.w));
    }
    for (; e < e1; e++) {
        uint4 v = hb4[(size_t)csr[e] * 4 + t];
        a0 += bflo(v.x); a1 += bfhi(v.x); a2 += bflo(v.y); a3 += bfhi(v.y);
        a4 += bflo(v.z); a5 += bfhi(v.z); a6 += bflo(v.w); a7 += bfhi(v.w);
    }
    float di = dinv[node];
    float* op = out + (size_t)node * 32 + t * 8;
    *reinterpret_cast<float4*>(op)     = make_float4(a0*di, a1*di, a2*di, a3*di);
    *reinterpret_cast<float4*>(op + 4) = make_float4(a4*di, a5*di, a6*di, a7*di);
}

// ---------------- pooling helpers ----------------
__device__ inline unsigned fkey(float x) {
    unsigned u = __float_as_uint(x);
    return (u & 0x80000000u) ? ~u : (u | 0x80000000u);
}
__device__ inline float funkey(unsigned k) {
    unsigned u = (k & 0x80000000u) ? (k & 0x7FFFFFFFu) : ~k;
    return __uint_as_float(u);
}

// ---------------- fused final gather (D=4) + segment-max pool ----------------
__global__ void gather4_pool_k(const float* __restrict__ hs, const float* __restrict__ dinv,
                               const int* __restrict__ cur, const int* __restrict__ csr,
                               const float* __restrict__ b4, const int* __restrict__ batch,
                               unsigned* __restrict__ pooled, int n, int num_graphs) {
    __shared__ unsigned lds[128 * 4];
    for (int i = threadIdx.x; i < num_graphs * 4; i += blockDim.x) lds[i] = 0u;
    __syncthreads();
    int node = blockIdx.x * blockDim.x + threadIdx.x;
    if (node < n) {
        float di = dinv[node];
        float4 acc = reinterpret_cast<const float4*>(hs)[node];
        int e0 = node ? cur[node - 1] : 0;
        int e1 = cur[node];
        int e = e0;
        for (; e + 3 < e1; e += 4) {
            int s0 = csr[e], s1 = csr[e+1], s2 = csr[e+2], s3 = csr[e+3];
            float4 v0 = reinterpret_cast<const float4*>(hs)[s0];
            float4 v1 = reinterpret_cast<const float4*>(hs)[s1];
            float4 v2 = reinterpret_cast<const float4*>(hs)[s2];
            float4 v3 = reinterpret_cast<const float4*>(hs)[s3];
            acc.x += (v0.x + v1.x) + (v2.x + v3.x);
            acc.y += (v0.y + v1.y) + (v2.y + v3.y);
            acc.z += (v0.z + v1.z) + (v2.z + v3.z);
            acc.w += (v0.w + v1.w) + (v2.w + v3.w);
        }
        for (; e < e1; e++) {
            float4 v0 = reinterpret_cast<const float4*>(hs)[csr[e]];
            acc.x += v0.x; acc.y += v0.y; acc.z += v0.z; acc.w += v0.w;
        }
        int g = batch[node];
        atomicMax(&lds[g*4+0], fkey(acc.x * di + b4[0]));
        atomicMax(&lds[g*4+1], fkey(acc.y * di + b4[1]));
        atomicMax(&lds[g*4+2], fkey(acc.z * di + b4[2]));
        atomicMax(&lds[g*4+3], fkey(acc.w * di + b4[3]));
    }
    __syncthreads();
    for (int i2 = threadIdx.x; i2 < num_graphs * 4; i2 += blockDim.x) {
        unsigned k = lds[i2];
        if (k) atomicMax(&pooled[i2], k);
    }
}

__global__ void pool_init_k(unsigned* pooled, int total) {
    int i = blockIdx.x * blockDim.x + threadIdx.x;
    if (i < total) pooled[i] = 0u;
}

__global__ void logsoftmax_k(const unsigned* __restrict__ pooled, float* __restrict__ out, int G) {
    int g = blockIdx.x * blockDim.x + threadIdx.x;
    if (g >= G) return;
    float v[4];
#pragma unroll
    for (int j = 0; j < 4; j++) v[j] = funkey(pooled[g*4+j]);
    float m = fmaxf(fmaxf(v[0], v[1]), fmaxf(v[2], v[3]));
    float s = 0.f;
#pragma unroll
    for (int j = 0; j < 4; j++) s += expf(v[j] - m);
    float l = logf(s);
#pragma unroll
    for (int j = 0; j < 4; j++) out[g*4+j] = v[j] - m - l;
}

// ---------------- LDS-tiled skinny matmul with optional bf16 in/out ----------------
template<int IN, int OUT, bool RELU, bool BIAS, bool SCALE, bool IBF, bool OBF>
__global__ void __launch_bounds__(256) matmul_k(
        const void* __restrict__ xv, const float* __restrict__ W,
        const float* __restrict__ b, const float* __restrict__ dinv,
        void* __restrict__ yv, int n) {
    constexpr int TN  = 64;
    constexpr int RS  = IN + 4;
    constexpr int OPT = OUT / 4;
    constexpr int NQ  = IN / 4;
    __shared__ float xs[TN * RS];
    __shared__ float Ws[IN * OUT];
    __shared__ float bs[OUT];

    for (int i = threadIdx.x; i < IN * OUT; i += 256) Ws[i] = W[i];
    if (BIAS) for (int i = threadIdx.x; i < OUT; i += 256) bs[i] = b[i];

    int base = blockIdx.x * TN;
    if constexpr (!IBF) {
        const float* x = (const float*)xv;
        for (int i = threadIdx.x; i < TN * NQ; i += 256) {
            int r = i / NQ, c = i % NQ;
            float4 v = make_float4(0.f, 0.f, 0.f, 0.f);
            if (base + r < n) v = reinterpret_cast<const float4*>(x + (size_t)(base + r) * IN)[c];
            *reinterpret_cast<float4*>(&xs[r * RS + c * 4]) = v;
        }
    } else {
        constexpr int NU = IN / 8;   // uint4 (8 bf16) per row
        const uint4* x = (const uint4*)xv;
        for (int i = threadIdx.x; i < TN * NU; i += 256) {
            int r = i / NU, c = i % NU;
            uint4 v = make_uint4(0u, 0u, 0u, 0u);
            if (base + r < n) v = x[(size_t)(base + r) * NU + c];
            float* dst = &xs[r * RS + c * 8];
            dst[0] = bflo(v.x); dst[1] = bfhi(v.x);
            dst[2] = bflo(v.y); dst[3] = bfhi(v.y);
            dst[4] = bflo(v.z); dst[5] = bfhi(v.z);
            dst[6] = bflo(v.w); dst[7] = bfhi(v.w);
        }
    }
    __syncthreads();

    int node = threadIdx.x >> 2;
    int g    = threadIdx.x & 3;
    int j0   = g * OPT;
    int gnode = base + node;
    if (gnode >= n) return;

    float acc[OPT];
#pragma unroll
    for (int jj = 0; jj < OPT; jj++) acc[jj] = 0.f;

    const float* xrow = &xs[node * RS];
#pragma unroll
    for (int k4 = 0; k4 < NQ; k4++) {
        float4 xvv = *reinterpret_cast<const float4*>(&xrow[k4 * 4]);
        float xk[4] = {xvv.x, xvv.y, xvv.z, xvv.w};
#pragma unroll
        for (int kk = 0; kk < 4; kk++) {
            const float* wrow = &Ws[(k4 * 4 + kk) * OUT + j0];
#pragma unroll
            for (int jj = 0; jj < OPT; jj++)
                acc[jj] += xk[kk] * wrow[jj];
        }
    }

    float di = SCALE ? dinv[gnode] : 1.f;
    float vout[OPT];
#pragma unroll
    for (int jj = 0; jj < OPT; jj++) {
        float v = acc[jj] + (BIAS ? bs[j0 + jj] : 0.f);
        if (RELU) v = fmaxf(v, 0.f);
        if (SCALE) v *= di;
        vout[jj] = v;
    }
    if constexpr (OBF) {
        unsigned short* yr = (unsigned short*)yv + (size_t)gnode * OUT + j0;
        if constexpr (OPT % 8 == 0) {
#pragma unroll
            for (int q = 0; q < OPT / 8; q++) {
                uint4 pk;
                pk.x = (unsigned)f2bf(vout[q*8+0]) | ((unsigned)f2bf(vout[q*8+1]) << 16);
                pk.y = (unsigned)f2bf(vout[q*8+2]) | ((unsigned)f2bf(vout[q*8+3]) << 16);
                pk.z = (unsigned)f2bf(vout[q*8+4]) | ((unsigned)f2bf(vout[q*8+5]) << 16);
                pk.w = (unsigned)f2bf(vout[q*8+6]) | ((unsigned)f2bf(vout[q*8+7]) << 16);
                reinterpret_cast<uint4*>(yr)[q] = pk;
            }
        } else {   // OPT == 4
            uint2 pk;
            pk.x = (unsigned)f2bf(vout[0]) | ((unsigned)f2bf(vout[1]) << 16);
            pk.y = (unsigned)f2bf(vout[2]) | ((unsigned)f2bf(vout[3]) << 16);
            *reinterpret_cast<uint2*>(yr) = pk;
        }
    } else {
        float* yr = (float*)yv + (size_t)gnode * OUT + j0;
        if (OPT % 4 == 0) {
#pragma unroll
            for (int q = 0; q < OPT / 4; q++)
                *reinterpret_cast<float4*>(yr + q * 4) =
                    make_float4(vout[q*4+0], vout[q*4+1], vout[q*4+2], vout[q*4+3]);
        } else {
#pragma unroll
            for (int jj = 0; jj < OPT; jj++) yr[jj] = vout[jj];
        }
    }
}

// ---------------- launch ----------------
extern "C" void kernel_launch(void* const* d_in, const int* in_sizes, int n_in,
                              void* d_out, int out_size, void* d_ws, size_t ws_size,
                              hipStream_t stream) {
    const float* x     = (const float*)d_in[0];
    const int*   ei    = (const int*)d_in[1];
    const int*   batch = (const int*)d_in[2];
    const float* W1 = (const float*)d_in[3];
    const float* b1 = (const float*)d_in[4];
    const float* W2 = (const float*)d_in[5];
    const float* b2 = (const float*)d_in[6];
    const float* W3 = (const float*)d_in[7];
    const float* b3 = (const float*)d_in[8];
    const float* W4 = (const float*)d_in[9];
    const float* b4 = (const float*)d_in[10];

    const int N = in_sizes[2];          // 100000
    const int E = in_sizes[1] / 2;      // 3.2M
    const int G = 128;
    const int* row = ei;
    const int* col = ei + E;
    const int NB = DIV_UP(N, BNODES);   // 782 buckets

    // workspace layout
    float* ws    = (float*)d_ws;
    float* dinv  = ws;                              // N floats
    int*   cur   = (int*)(dinv + N);                // N ints
    int*   bhist = cur + N;                         // 1024 ints
    int*   bcur  = bhist + 1024;                    // 1024 ints
    int*   csr   = bcur + 1024;                     // E ints
    float* f16a  = (float*)(csr + E);               // N*16 floats region
    float* f16b  = f16a + (size_t)N * 16;           // N*16 floats region
    float* f32a  = f16b + (size_t)N * 16;           // N*32 floats region
    float* f32b  = f32a + (size_t)N * 32;           // N*32 floats region
    unsigned* pooled = (unsigned*)(f32b + (size_t)N * 32);  // 512
    int* part = (int*)f32a;                         // dead after csr_build
    unsigned short* hb16a = (unsigned short*)f16a;  // N*16 bf16
    unsigned short* hb16b = (unsigned short*)f16b;  // N*16 bf16
    unsigned short* hb32  = (unsigned short*)f32a;  // N*32 bf16 (after part dead)
    unsigned short* hb64  = (unsigned short*)f32a;  // N*64 bf16 = 32N floats exactly
    float* f4a = f32b;                              // after L3 matmul, f32b free

    const int B = 256;
    const int gridN = DIV_UP(N, B);
    const int gridM = DIV_UP(N, 64);    // tiled matmul: 64 nodes/block
    const int grid2 = DIV_UP(2 * N, B); // 2 threads/node gathers

    // CSR build: hist -> scan -> LDS-ranked partition -> per-bucket (tgt,src-chunk) sort
    zero_int_k<<<DIV_UP(1024, B), B, 0, stream>>>(bhist, 1024);
    bucket_hist_k<<<512, B, 0, stream>>>(col, bhist, E, NB);
    bucket_scan_k<<<1, 256, 0, stream>>>(bhist, bcur, NB);
    partition_k<<<DIV_UP(E, CHUNK_E), PTH, 0, stream>>>(row, col, bcur, part, E, NB);
    csr_build_k<<<NB, 256, 0, stream>>>(part, bcur, cur, dinv, csr, N);

    // L1: y1 = (x@W1)*dinv -> hb16b (bf16) ; gather+bias+relu+scale -> hb16a (bf16)
    matmul_k<128,16,false,false,true,false,true><<<gridM, B, 0, stream>>>(x, W1, nullptr, dinv, hb16b, N);
    gather16_bf_k<1><<<grid2, B, 0, stream>>>(hb16b, dinv, cur, csr, b1, hb16a, N);

    // L2: gather hb16a -> f32b (fp32 agg) ; matmul 16->32 +b2,relu,*dinv -> hb32 (bf16)
    gather16_bf_k<0><<<grid2, B, 0, stream>>>(hb16a, dinv, cur, csr, nullptr, f32b, N);
    matmul_k<16,32,true,true,true,false,true><<<gridM, B, 0, stream>>>(f32b, W2, b2, dinv, hb32, N);

    // L3: bf16 gather hb32 -> f32b (fp32 agg) ; matmul 32->64 +b3,relu,*dinv -> hb64 (bf16)
    gather32_bf_k<<<DIV_UP(N*4, B), B, 0, stream>>>(hb32, dinv, cur, csr, f32b, N);
    matmul_k<32,64,true,true,true,false,true><<<gridM, B, 0, stream>>>(f32b, W3, b3, dinv, hb64, N);

    // L4: y4 = h3s@W4 (bf16 in) -> f4a (fp32) ; fused gather+pool (adds b4)
    matmul_k<64,4,false,false,false,true,false><<<gridM, B, 0, stream>>>(hb64, W4, nullptr, nullptr, f4a, N);
    pool_init_k<<<DIV_UP(G*4, B), B, 0, stream>>>(pooled, G*4);
    gather4_pool_k<<<gridN, B, 0, stream>>>(f4a, dinv, cur, csr, b4, batch, pooled, N, G);

    // log_softmax
    logsoftmax_k<<<1, 128, 0, stream>>>(pooled, (float*)d_out, G);
}

// Round 13
// 228.186 us; speedup vs baseline: 2.0827x; 1.0643x over previous
//
#include <hip/hip_runtime.h>

#define DIV_UP(a,b) (((a)+(b)-1)/(b))

// bucket = tgt >> 7  (128 nodes per bucket)
constexpr int BSHIFT = 7;
constexpr int BNODES = 128;
constexpr int CHUNK_E = 16384;   // edges per partition block (measured best)
constexpr int PTH = 512;         // partition block threads
constexpr int SCH = 8;           // source chunks for CSR segment ordering
constexpr int SCSH = 14;         // src >> 14 -> chunk id (16K nodes per chunk)

// ---------------- bf16 helpers (storage only; all math fp32) ----------------
__device__ inline unsigned short f2bf(float f) {
    unsigned u = __float_as_uint(f);
    u = u + 0x7FFFu + ((u >> 16) & 1u);   // round-to-nearest-even
    return (unsigned short)(u >> 16);
}
__device__ inline float bflo(unsigned u) { return __uint_as_float(u << 16); }
__device__ inline float bfhi(unsigned u) { return __uint_as_float(u & 0xFFFF0000u); }

// ---------------- CSR build ----------------
__global__ void zero_int_k(int* p, int n) {
    int i = blockIdx.x * blockDim.x + threadIdx.x;
    if (i < n) p[i] = 0;
}

__global__ void bucket_hist_k(const int* __restrict__ col, int* __restrict__ bhist, int E, int nb) {
    __shared__ int lh[1024];
    for (int i = threadIdx.x; i < 1024; i += blockDim.x) lh[i] = 0;
    __syncthreads();
    int stride = gridDim.x * blockDim.x;
    for (int e = blockIdx.x * blockDim.x + threadIdx.x; e < E; e += stride)
        atomicAdd(&lh[col[e] >> BSHIFT], 1);
    __syncthreads();
    for (int i = threadIdx.x; i < nb; i += blockDim.x) {
        int v = lh[i];
        if (v) atomicAdd(&bhist[i], v);
    }
}

__global__ void bucket_scan_k(const int* __restrict__ bhist, int* __restrict__ bcur, int nb) {
    __shared__ int lds[256];
    int base = threadIdx.x * 4;
    int v[4]; int s = 0;
#pragma unroll
    for (int j = 0; j < 4; j++) { v[j] = (base + j < nb) ? bhist[base + j] : 0; s += v[j]; }
    lds[threadIdx.x] = s; __syncthreads();
    for (int off = 1; off < 256; off <<= 1) {
        int t = (threadIdx.x >= off) ? lds[threadIdx.x - off] : 0;
        __syncthreads();
        lds[threadIdx.x] += t;
        __syncthreads();
    }
    int excl = lds[threadIdx.x] - s;
#pragma unroll
    for (int j = 0; j < 4; j++) {
        if (base + j < nb) bcur[base + j] = excl;
        excl += v[j];
    }
}

__global__ void __launch_bounds__(PTH) partition_k(
        const int* __restrict__ row, const int* __restrict__ col,
        int* __restrict__ bcur, int* __restrict__ part, int E, int nb) {
    __shared__ int lh[1024];
    __shared__ int lbase[1024];
    __shared__ int delta[1024];
    __shared__ unsigned sorted[CHUNK_E];
    __shared__ unsigned short bid[CHUNK_E];
    int tid = threadIdx.x;
    for (int i = tid; i < 1024; i += PTH) lh[i] = 0;
    __syncthreads();
    int base = blockIdx.x * CHUNK_E;
    int end = min(E, base + CHUNK_E);
    for (int e = base + tid; e < end; e += PTH)
        atomicAdd(&lh[col[e] >> BSHIFT], 1);
    __syncthreads();
    int v0 = lh[2 * tid], v1 = lh[2 * tid + 1];
    int s = v0 + v1;
    delta[tid] = s;
    __syncthreads();
    for (int off = 1; off < PTH; off <<= 1) {
        int t = (tid >= off) ? delta[tid - off] : 0;
        __syncthreads();
        delta[tid] += t;
        __syncthreads();
    }
    int excl = delta[tid] - s;
    lbase[2 * tid] = excl;
    lbase[2 * tid + 1] = excl + v0;
    __syncthreads();
    for (int i = tid; i < nb; i += PTH) {
        int c = lh[i];
        int g = c ? atomicAdd(&bcur[i], c) : 0;
        delta[i] = g - lbase[i];
    }
    __syncthreads();
    for (int i = tid; i < nb; i += PTH) lh[i] = lbase[i];
    __syncthreads();
    for (int e = base + tid; e < end; e += PTH) {
        int r = row[e], c = col[e];
        int b = c >> BSHIFT;
        int slot = atomicAdd(&lh[b], 1);
        sorted[slot] = (unsigned)((r << BSHIFT) | (c & (BNODES - 1)));
        bid[slot] = (unsigned short)b;
    }
    __syncthreads();
    int cnt = end - base;
    for (int i = tid; i < cnt; i += PTH) {
        int b = bid[i];
        part[delta[b] + i] = (int)sorted[i];
    }
}

__global__ void __launch_bounds__(256) csr_build_k(
        const int* __restrict__ part, const int* __restrict__ bcur,
        int* __restrict__ cur, float* __restrict__ dinv,
        int* __restrict__ csr, int N) {
    __shared__ int cnt[BNODES * SCH];
    __shared__ int scan_t[256];
    __shared__ int ebounds[2];
    int b = blockIdx.x;
    int tid = threadIdx.x;
    if (tid == 0) { ebounds[0] = b ? bcur[b - 1] : 0; ebounds[1] = bcur[b]; }
    for (int i = tid; i < BNODES * SCH; i += 256) cnt[i] = 0;
    __syncthreads();
    int e0 = ebounds[0], e1 = ebounds[1];
    for (int e = e0 + tid; e < e1; e += 256) {
        unsigned v = (unsigned)part[e];
        int cell = (int)(v & (BNODES - 1)) * SCH + (int)(v >> (BSHIFT + SCSH));
        atomicAdd(&cnt[cell], 1);
    }
    __syncthreads();
    int base4 = tid * 4;
    int c0 = cnt[base4], c1 = cnt[base4+1], c2 = cnt[base4+2], c3 = cnt[base4+3];
    int s = c0 + c1 + c2 + c3;
    scan_t[tid] = s;
    __syncthreads();
    for (int off = 1; off < 256; off <<= 1) {
        int t = (tid >= off) ? scan_t[tid - off] : 0;
        __syncthreads();
        scan_t[tid] += t;
        __syncthreads();
    }
    int excl = scan_t[tid] - s;
    cnt[base4]     = excl;
    cnt[base4 + 1] = excl + c0;
    cnt[base4 + 2] = excl + c0 + c1;
    cnt[base4 + 3] = excl + c0 + c1 + c2;
    __syncthreads();
    if (tid < BNODES) {
        int node = b * BNODES + tid;
        int segstart = cnt[tid * SCH];
        int segend   = (tid == BNODES - 1) ? (e1 - e0) : cnt[(tid + 1) * SCH];
        if (node < N) {
            cur[node]  = e0 + segend;
            dinv[node] = rsqrtf(1.0f + (float)(segend - segstart));
        }
    }
    __syncthreads();
    for (int e = e0 + tid; e < e1; e += 256) {
        unsigned v = (unsigned)part[e];
        int cell = (int)(v & (BNODES - 1)) * SCH + (int)(v >> (BSHIFT + SCSH));
        int p = atomicAdd(&cnt[cell], 1);
        csr[e0 + p] = (int)(v >> BSHIFT);
    }
}

// ---------------- standalone gather, bf16 D=16, EPI1 (relu+bias+scale, bf16 out) ------
__global__ void __launch_bounds__(256) gather16_bf_k(
        const unsigned short* __restrict__ hb, const float* __restrict__ dinv,
        const int* __restrict__ cur, const int* __restrict__ csr,
        const float* __restrict__ b, unsigned short* __restrict__ outb, int n) {
    int t2 = blockIdx.x * 256 + threadIdx.x;
    int node = t2 >> 1, t = t2 & 1;
    if (node >= n) return;
    const uint4* hb4 = reinterpret_cast<const uint4*>(hb);
    uint4 sv = hb4[(size_t)node * 2 + t];
    float a0 = bflo(sv.x), a1 = bfhi(sv.x), a2 = bflo(sv.y), a3 = bfhi(sv.y);
    float a4 = bflo(sv.z), a5 = bfhi(sv.z), a6 = bflo(sv.w), a7 = bfhi(sv.w);
    int e0 = node ? cur[node - 1] : 0;
    int e1 = cur[node];
    int e = e0;
    for (; e + 3 < e1; e += 4) {
        int s0 = csr[e], s1 = csr[e+1], s2 = csr[e+2], s3 = csr[e+3];
        uint4 v0 = hb4[(size_t)s0 * 2 + t];
        uint4 v1 = hb4[(size_t)s1 * 2 + t];
        uint4 v2 = hb4[(size_t)s2 * 2 + t];
        uint4 v3 = hb4[(size_t)s3 * 2 + t];
        a0 += (bflo(v0.x) + bflo(v1.x)) + (bflo(v2.x) + bflo(v3.x));
        a1 += (bfhi(v0.x) + bfhi(v1.x)) + (bfhi(v2.x) + bfhi(v3.x));
        a2 += (bflo(v0.y) + bflo(v1.y)) + (bflo(v2.y) + bflo(v3.y));
        a3 += (bfhi(v0.y) + bfhi(v1.y)) + (bfhi(v2.y) + bfhi(v3.y));
        a4 += (bflo(v0.z) + bflo(v1.z)) + (bflo(v2.z) + bflo(v3.z));
        a5 += (bfhi(v0.z) + bfhi(v1.z)) + (bfhi(v2.z) + bfhi(v3.z));
        a6 += (bflo(v0.w) + bflo(v1.w)) + (bflo(v2.w) + bflo(v3.w));
        a7 += (bfhi(v0.w) + bfhi(v1.w)) + (bfhi(v2.w) + bfhi(v3.w));
    }
    for (; e < e1; e++) {
        uint4 v = hb4[(size_t)csr[e] * 2 + t];
        a0 += bflo(v.x); a1 += bfhi(v.x); a2 += bflo(v.y); a3 += bfhi(v.y);
        a4 += bflo(v.z); a5 += bfhi(v.z); a6 += bflo(v.w); a7 += bfhi(v.w);
    }
    float di = dinv[node];
    int bo = t * 8;
    a0 = fmaxf(a0 * di + b[bo+0], 0.f) * di; a1 = fmaxf(a1 * di + b[bo+1], 0.f) * di;
    a2 = fmaxf(a2 * di + b[bo+2], 0.f) * di; a3 = fmaxf(a3 * di + b[bo+3], 0.f) * di;
    a4 = fmaxf(a4 * di + b[bo+4], 0.f) * di; a5 = fmaxf(a5 * di + b[bo+5], 0.f) * di;
    a6 = fmaxf(a6 * di + b[bo+6], 0.f) * di; a7 = fmaxf(a7 * di + b[bo+7], 0.f) * di;
    uint4 pk;
    pk.x = (unsigned)f2bf(a0) | ((unsigned)f2bf(a1) << 16);
    pk.y = (unsigned)f2bf(a2) | ((unsigned)f2bf(a3) << 16);
    pk.z = (unsigned)f2bf(a4) | ((unsigned)f2bf(a5) << 16);
    pk.w = (unsigned)f2bf(a6) | ((unsigned)f2bf(a7) << 16);
    reinterpret_cast<uint4*>(outb)[(size_t)node * 2 + t] = pk;
}

// ---------------- FUSED gather(D=16) + matmul 16->32 (+b2, relu, *dinv) -> bf16 -------
__global__ void __launch_bounds__(256) gmm16_32_k(
        const unsigned short* __restrict__ hb, const float* __restrict__ dinv,
        const int* __restrict__ cur, const int* __restrict__ csr,
        const float* __restrict__ W, const float* __restrict__ b,
        unsigned short* __restrict__ yb, int n) {
    constexpr int TN = 128, RS = 20;
    __shared__ float xs[TN * RS];     // 10 KB
    __shared__ float Ws[16 * 32];     // 2 KB
    __shared__ float bs[32];
    for (int i = threadIdx.x; i < 16 * 32; i += 256) Ws[i] = W[i];
    if (threadIdx.x < 32) bs[threadIdx.x] = b[threadIdx.x];
    int base = blockIdx.x * TN;
    // gather phase: 2 threads/node
    {
        int nl = threadIdx.x >> 1, t = threadIdx.x & 1;
        int node = base + nl;
        if (node < n) {
            const uint4* hb4 = reinterpret_cast<const uint4*>(hb);
            uint4 sv = hb4[(size_t)node * 2 + t];
            float a0 = bflo(sv.x), a1 = bfhi(sv.x), a2 = bflo(sv.y), a3 = bfhi(sv.y);
            float a4 = bflo(sv.z), a5 = bfhi(sv.z), a6 = bflo(sv.w), a7 = bfhi(sv.w);
            int e0 = node ? cur[node - 1] : 0;
            int e1 = cur[node];
            int e = e0;
            for (; e + 3 < e1; e += 4) {
                int s0 = csr[e], s1 = csr[e+1], s2 = csr[e+2], s3 = csr[e+3];
                uint4 v0 = hb4[(size_t)s0 * 2 + t];
                uint4 v1 = hb4[(size_t)s1 * 2 + t];
                uint4 v2 = hb4[(size_t)s2 * 2 + t];
                uint4 v3 = hb4[(size_t)s3 * 2 + t];
                a0 += (bflo(v0.x) + bflo(v1.x)) + (bflo(v2.x) + bflo(v3.x));
                a1 += (bfhi(v0.x) + bfhi(v1.x)) + (bfhi(v2.x) + bfhi(v3.x));
                a2 += (bflo(v0.y) + bflo(v1.y)) + (bflo(v2.y) + bflo(v3.y));
                a3 += (bfhi(v0.y) + bfhi(v1.y)) + (bfhi(v2.y) + bfhi(v3.y));
                a4 += (bflo(v0.z) + bflo(v1.z)) + (bflo(v2.z) + bflo(v3.z));
                a5 += (bfhi(v0.z) + bfhi(v1.z)) + (bfhi(v2.z) + bfhi(v3.z));
                a6 += (bflo(v0.w) + bflo(v1.w)) + (bflo(v2.w) + bflo(v3.w));
                a7 += (bfhi(v0.w) + bfhi(v1.w)) + (bfhi(v2.w) + bfhi(v3.w));
            }
            for (; e < e1; e++) {
                uint4 v = hb4[(size_t)csr[e] * 2 + t];
                a0 += bflo(v.x); a1 += bfhi(v.x); a2 += bflo(v.y); a3 += bfhi(v.y);
                a4 += bflo(v.z); a5 += bfhi(v.z); a6 += bflo(v.w); a7 += bfhi(v.w);
            }
            float di = dinv[node];
            float* dst = &xs[nl * RS + t * 8];
            dst[0] = a0*di; dst[1] = a1*di; dst[2] = a2*di; dst[3] = a3*di;
            dst[4] = a4*di; dst[5] = a5*di; dst[6] = a6*di; dst[7] = a7*di;
        }
    }
    __syncthreads();
    // matmul phase: 2 threads/node, 16 outputs each
    int nl = threadIdx.x >> 1, g = threadIdx.x & 1;
    int node = base + nl;
    if (node >= n) return;
    int j0 = g * 16;
    float acc[16];
#pragma unroll
    for (int j = 0; j < 16; j++) acc[j] = 0.f;
    const float* xrow = &xs[nl * RS];
#pragma unroll
    for (int k4 = 0; k4 < 4; k4++) {
        float4 xv = *reinterpret_cast<const float4*>(&xrow[k4 * 4]);
        float xk[4] = {xv.x, xv.y, xv.z, xv.w};
#pragma unroll
        for (int kk = 0; kk < 4; kk++) {
            const float* wrow = &Ws[(k4*4+kk) * 32 + j0];
#pragma unroll
            for (int j = 0; j < 16; j++) acc[j] += xk[kk] * wrow[j];
        }
    }
    float di = dinv[node];
    unsigned short* yr = yb + (size_t)node * 32 + j0;
#pragma unroll
    for (int q = 0; q < 2; q++) {
        float o[8];
#pragma unroll
        for (int j = 0; j < 8; j++)
            o[j] = fmaxf(acc[q*8+j] + bs[j0 + q*8 + j], 0.f) * di;
        uint4 pk;
        pk.x = (unsigned)f2bf(o[0]) | ((unsigned)f2bf(o[1]) << 16);
        pk.y = (unsigned)f2bf(o[2]) | ((unsigned)f2bf(o[3]) << 16);
        pk.z = (unsigned)f2bf(o[4]) | ((unsigned)f2bf(o[5]) << 16);
        pk.w = (unsigned)f2bf(o[6]) | ((unsigned)f2bf(o[7]) << 16);
        reinterpret_cast<uint4*>(yr)[q] = pk;
    }
}

// ---------------- FUSED gather(D=32) + matmul 32->64 (+b3, relu, *dinv) -> bf16 -------
__global__ void __launch_bounds__(256) gmm32_64_k(
        const unsigned short* __restrict__ hb, const float* __restrict__ dinv,
        const int* __restrict__ cur, const int* __restrict__ csr,
        const float* __restrict__ W, const float* __restrict__ b,
        unsigned short* __restrict__ yb, int n) {
    constexpr int TN = 64, RS = 36;
    __shared__ float xs[TN * RS];     // 9 KB
    __shared__ float Ws[32 * 64];     // 8 KB
    __shared__ float bs[64];
    for (int i = threadIdx.x; i < 32 * 64; i += 256) Ws[i] = W[i];
    if (threadIdx.x < 64) bs[threadIdx.x] = b[threadIdx.x];
    int base = blockIdx.x * TN;
    // gather phase: 4 threads/node
    {
        int nl = threadIdx.x >> 2, t = threadIdx.x & 3;
        int node = base + nl;
        if (node < n) {
            const uint4* hb4 = reinterpret_cast<const uint4*>(hb);
            uint4 sv = hb4[(size_t)node * 4 + t];
            float a0 = bflo(sv.x), a1 = bfhi(sv.x), a2 = bflo(sv.y), a3 = bfhi(sv.y);
            float a4 = bflo(sv.z), a5 = bfhi(sv.z), a6 = bflo(sv.w), a7 = bfhi(sv.w);
            int e0 = node ? cur[node - 1] : 0;
            int e1 = cur[node];
            int e = e0;
            for (; e + 3 < e1; e += 4) {
                int s0 = csr[e], s1 = csr[e+1], s2 = csr[e+2], s3 = csr[e+3];
                uint4 v0 = hb4[(size_t)s0 * 4 + t];
                uint4 v1 = hb4[(size_t)s1 * 4 + t];
                uint4 v2 = hb4[(size_t)s2 * 4 + t];
                uint4 v3 = hb4[(size_t)s3 * 4 + t];
                a0 += (bflo(v0.x) + bflo(v1.x)) + (bflo(v2.x) + bflo(v3.x));
                a1 += (bfhi(v0.x) + bfhi(v1.x)) + (bfhi(v2.x) + bfhi(v3.x));
                a2 += (bflo(v0.y) + bflo(v1.y)) + (bflo(v2.y) + bflo(v3.y));
                a3 += (bfhi(v0.y) + bfhi(v1.y)) + (bfhi(v2.y) + bfhi(v3.y));
                a4 += (bflo(v0.z) + bflo(v1.z)) + (bflo(v2.z) + bflo(v3.z));
                a5 += (bfhi(v0.z) + bfhi(v1.z)) + (bfhi(v2.z) + bfhi(v3.z));
                a6 += (bflo(v0.w) + bflo(v1.w)) + (bflo(v2.w) + bflo(v3.w));
                a7 += (bfhi(v0.w) + bfhi(v1.w)) + (bfhi(v2.w) + bfhi(v3.w));
            }
            for (; e < e1; e++) {
                uint4 v = hb4[(size_t)csr[e] * 4 + t];
                a0 += bflo(v.x); a1 += bfhi(v.x); a2 += bflo(v.y); a3 += bfhi(v.y);
                a4 += bflo(v.z); a5 += bfhi(v.z); a6 += bflo(v.w); a7 += bfhi(v.w);
            }
            float di = dinv[node];
            float* dst = &xs[nl * RS + t * 8];
            dst[0] = a0*di; dst[1] = a1*di; dst[2] = a2*di; dst[3] = a3*di;
            dst[4] = a4*di; dst[5] = a5*di; dst[6] = a6*di; dst[7] = a7*di;
        }
    }
    __syncthreads();
    // matmul phase: 4 threads/node, 16 outputs each
    int nl = threadIdx.x >> 2, g = threadIdx.x & 3;
    int node = base + nl;
    if (node >= n) return;
    int j0 = g * 16;
    float acc[16];
#pragma unroll
    for (int j = 0; j < 16; j++) acc[j] = 0.f;
    const float* xrow = &xs[nl * RS];
#pragma unroll
    for (int k4 = 0; k4 < 8; k4++) {
        float4 xv = *reinterpret_cast<const float4*>(&xrow[k4 * 4]);
        float xk[4] = {xv.x, xv.y, xv.z, xv.w};
#pragma unroll
        for (int kk = 0; kk < 4; kk++) {
            const float* wrow = &Ws[(k4*4+kk) * 64 + j0];
#pragma unroll
            for (int j = 0; j < 16; j++) acc[j] += xk[kk] * wrow[j];
        }
    }
    float di = dinv[node];
    unsigned short* yr = yb + (size_t)node * 64 + j0;
#pragma unroll
    for (int q = 0; q < 2; q++) {
        float o[8];
#pragma unroll
        for (int j = 0; j < 8; j++)
            o[j] = fmaxf(acc[q*8+j] + bs[j0 + q*8 + j], 0.f) * di;
        uint4 pk;
        pk.x = (unsigned)f2bf(o[0]) | ((unsigned)f2bf(o[1]) << 16);
        pk.y = (unsigned)f2bf(o[2]) | ((unsigned)f2bf(o[3]) << 16);
        pk.z = (unsigned)f2bf(o[4]) | ((unsigned)f2bf(o[5]) << 16);
        pk.w = (unsigned)f2bf(o[6]) | ((unsigned)f2bf(o[7]) << 16);
        reinterpret_cast<uint4*>(yr)[q] = pk;
    }
}

// ---------------- pooling helpers ----------------
__device__ inline unsigned fkey(float x) {
    unsigned u = __float_as_uint(x);
    return (u & 0x80000000u) ? ~u : (u | 0x80000000u);
}
__device__ inline float funkey(unsigned k) {
    unsigned u = (k & 0x80000000u) ? (k & 0x7FFFFFFFu) : ~k;
    return __uint_as_float(u);
}

// ---------------- fused final gather (D=4) + segment-max pool ----------------
__global__ void gather4_pool_k(const float* __restrict__ hs, const float* __restrict__ dinv,
                               const int* __restrict__ cur, const int* __restrict__ csr,
                               const float* __restrict__ b4, const int* __restrict__ batch,
                               unsigned* __restrict__ pooled, int n, int num_graphs) {
    __shared__ unsigned lds[128 * 4];
    for (int i = threadIdx.x; i < num_graphs * 4; i += blockDim.x) lds[i] = 0u;
    __syncthreads();
    int node = blockIdx.x * blockDim.x + threadIdx.x;
    if (node < n) {
        float di = dinv[node];
        float4 acc = reinterpret_cast<const float4*>(hs)[node];
        int e0 = node ? cur[node - 1] : 0;
        int e1 = cur[node];
        int e = e0;
        for (; e + 3 < e1; e += 4) {
            int s0 = csr[e], s1 = csr[e+1], s2 = csr[e+2], s3 = csr[e+3];
            float4 v0 = reinterpret_cast<const float4*>(hs)[s0];
            float4 v1 = reinterpret_cast<const float4*>(hs)[s1];
            float4 v2 = reinterpret_cast<const float4*>(hs)[s2];
            float4 v3 = reinterpret_cast<const float4*>(hs)[s3];
            acc.x += (v0.x + v1.x) + (v2.x + v3.x);
            acc.y += (v0.y + v1.y) + (v2.y + v3.y);
            acc.z += (v0.z + v1.z) + (v2.z + v3.z);
            acc.w += (v0.w + v1.w) + (v2.w + v3.w);
        }
        for (; e < e1; e++) {
            float4 v0 = reinterpret_cast<const float4*>(hs)[csr[e]];
            acc.x += v0.x; acc.y += v0.y; acc.z += v0.z; acc.w += v0.w;
        }
        int g = batch[node];
        atomicMax(&lds[g*4+0], fkey(acc.x * di + b4[0]));
        atomicMax(&lds[g*4+1], fkey(acc.y * di + b4[1]));
        atomicMax(&lds[g*4+2], fkey(acc.z * di + b4[2]));
        atomicMax(&lds[g*4+3], fkey(acc.w * di + b4[3]));
    }
    __syncthreads();
    for (int i2 = threadIdx.x; i2 < num_graphs * 4; i2 += blockDim.x) {
        unsigned k = lds[i2];
        if (k) atomicMax(&pooled[i2], k);
    }
}

__global__ void pool_init_k(unsigned* pooled, int total) {
    int i = blockIdx.x * blockDim.x + threadIdx.x;
    if (i < total) pooled[i] = 0u;
}

__global__ void logsoftmax_k(const unsigned* __restrict__ pooled, float* __restrict__ out, int G) {
    int g = blockIdx.x * blockDim.x + threadIdx.x;
    if (g >= G) return;
    float v[4];
#pragma unroll
    for (int j = 0; j < 4; j++) v[j] = funkey(pooled[g*4+j]);
    float m = fmaxf(fmaxf(v[0], v[1]), fmaxf(v[2], v[3]));
    float s = 0.f;
#pragma unroll
    for (int j = 0; j < 4; j++) s += expf(v[j] - m);
    float l = logf(s);
#pragma unroll
    for (int j = 0; j < 4; j++) out[g*4+j] = v[j] - m - l;
}

// ---------------- LDS-tiled skinny matmul with optional bf16 in/out ----------------
template<int IN, int OUT, bool RELU, bool BIAS, bool SCALE, bool IBF, bool OBF>
__global__ void __launch_bounds__(256) matmul_k(
        const void* __restrict__ xv, const float* __restrict__ W,
        const float* __restrict__ b, const float* __restrict__ dinv,
        void* __restrict__ yv, int n) {
    constexpr int TN  = 64;
    constexpr int RS  = IN + 4;
    constexpr int OPT = OUT / 4;
    constexpr int NQ  = IN / 4;
    __shared__ float xs[TN * RS];
    __shared__ float Ws[IN * OUT];
    __shared__ float bs[OUT];

    for (int i = threadIdx.x; i < IN * OUT; i += 256) Ws[i] = W[i];
    if (BIAS) for (int i = threadIdx.x; i < OUT; i += 256) bs[i] = b[i];

    int base = blockIdx.x * TN;
    if constexpr (!IBF) {
        const float* x = (const float*)xv;
        for (int i = threadIdx.x; i < TN * NQ; i += 256) {
            int r = i / NQ, c = i % NQ;
            float4 v = make_float4(0.f, 0.f, 0.f, 0.f);
            if (base + r < n) v = reinterpret_cast<const float4*>(x + (size_t)(base + r) * IN)[c];
            *reinterpret_cast<float4*>(&xs[r * RS + c * 4]) = v;
        }
    } else {
        constexpr int NU = IN / 8;
        const uint4* x = (const uint4*)xv;
        for (int i = threadIdx.x; i < TN * NU; i += 256) {
            int r = i / NU, c = i % NU;
            uint4 v = make_uint4(0u, 0u, 0u, 0u);
            if (base + r < n) v = x[(size_t)(base + r) * NU + c];
            float* dst = &xs[r * RS + c * 8];
            dst[0] = bflo(v.x); dst[1] = bfhi(v.x);
            dst[2] = bflo(v.y); dst[3] = bfhi(v.y);
            dst[4] = bflo(v.z); dst[5] = bfhi(v.z);
            dst[6] = bflo(v.w); dst[7] = bfhi(v.w);
        }
    }
    __syncthreads();

    int node = threadIdx.x >> 2;
    int g    = threadIdx.x & 3;
    int j0   = g * OPT;
    int gnode = base + node;
    if (gnode >= n) return;

    float acc[OPT];
#pragma unroll
    for (int jj = 0; jj < OPT; jj++) acc[jj] = 0.f;

    const float* xrow = &xs[node * RS];
#pragma unroll
    for (int k4 = 0; k4 < NQ; k4++) {
        float4 xvv = *reinterpret_cast<const float4*>(&xrow[k4 * 4]);
        float xk[4] = {xvv.x, xvv.y, xvv.z, xvv.w};
#pragma unroll
        for (int kk = 0; kk < 4; kk++) {
            const float* wrow = &Ws[(k4 * 4 + kk) * OUT + j0];
#pragma unroll
            for (int jj = 0; jj < OPT; jj++)
                acc[jj] += xk[kk] * wrow[jj];
        }
    }

    float di = SCALE ? dinv[gnode] : 1.f;
    float vout[OPT];
#pragma unroll
    for (int jj = 0; jj < OPT; jj++) {
        float v = acc[jj] + (BIAS ? bs[j0 + jj] : 0.f);
        if (RELU) v = fmaxf(v, 0.f);
        if (SCALE) v *= di;
        vout[jj] = v;
    }
    if constexpr (OBF) {
        unsigned short* yr = (unsigned short*)yv + (size_t)gnode * OUT + j0;
        if constexpr (OPT % 8 == 0) {
#pragma unroll
            for (int q = 0; q < OPT / 8; q++) {
                uint4 pk;
                pk.x = (unsigned)f2bf(vout[q*8+0]) | ((unsigned)f2bf(vout[q*8+1]) << 16);
                pk.y = (unsigned)f2bf(vout[q*8+2]) | ((unsigned)f2bf(vout[q*8+3]) << 16);
                pk.z = (unsigned)f2bf(vout[q*8+4]) | ((unsigned)f2bf(vout[q*8+5]) << 16);
                pk.w = (unsigned)f2bf(vout[q*8+6]) | ((unsigned)f2bf(vout[q*8+7]) << 16);
                reinterpret_cast<uint4*>(yr)[q] = pk;
            }
        } else {
            uint2 pk;
            pk.x = (unsigned)f2bf(vout[0]) | ((unsigned)f2bf(vout[1]) << 16);
            pk.y = (unsigned)f2bf(vout[2]) | ((unsigned)f2bf(vout[3]) << 16);
            *reinterpret_cast<uint2*>(yr) = pk;
        }
    } else {
        float* yr = (float*)yv + (size_t)gnode * OUT + j0;
        if (OPT % 4 == 0) {
#pragma unroll
            for (int q = 0; q < OPT / 4; q++)
                *reinterpret_cast<float4*>(yr + q * 4) =
                    make_float4(vout[q*4+0], vout[q*4+1], vout[q*4+2], vout[q*4+3]);
        } else {
#pragma unroll
            for (int jj = 0; jj < OPT; jj++) yr[jj] = vout[jj];
        }
    }
}

// ---------------- launch ----------------
extern "C" void kernel_launch(void* const* d_in, const int* in_sizes, int n_in,
                              void* d_out, int out_size, void* d_ws, size_t ws_size,
                              hipStream_t stream) {
    const float* x     = (const float*)d_in[0];
    const int*   ei    = (const int*)d_in[1];
    const int*   batch = (const int*)d_in[2];
    const float* W1 = (const float*)d_in[3];
    const float* b1 = (const float*)d_in[4];
    const float* W2 = (const float*)d_in[5];
    const float* b2 = (const float*)d_in[6];
    const float* W3 = (const float*)d_in[7];
    const float* b3 = (const float*)d_in[8];
    const float* W4 = (const float*)d_in[9];
    const float* b4 = (const float*)d_in[10];

    const int N = in_sizes[2];          // 100000
    const int E = in_sizes[1] / 2;      // 3.2M
    const int G = 128;
    const int* row = ei;
    const int* col = ei + E;
    const int NB = DIV_UP(N, BNODES);   // 782 buckets

    // workspace layout
    float* ws    = (float*)d_ws;
    float* dinv  = ws;                              // N floats
    int*   cur   = (int*)(dinv + N);                // N ints
    int*   bhist = cur + N;                         // 1024 ints
    int*   bcur  = bhist + 1024;                    // 1024 ints
    int*   csr   = bcur + 1024;                     // E ints
    float* f16a  = (float*)(csr + E);               // N*16 floats region
    float* f16b  = f16a + (size_t)N * 16;           // N*16 floats region
    float* f32a  = f16b + (size_t)N * 16;           // N*32 floats region
    float* f32b  = f32a + (size_t)N * 32;           // N*32 floats region
    unsigned* pooled = (unsigned*)(f32b + (size_t)N * 32);  // 512
    int* part = (int*)f32a;                         // dead after csr_build
    unsigned short* hb16a = (unsigned short*)f16a;  // N*16 bf16
    unsigned short* hb16b = (unsigned short*)f16b;  // N*16 bf16
    unsigned short* hb32  = (unsigned short*)f32a;  // N*32 bf16 (after part dead)
    unsigned short* hb64  = (unsigned short*)f32b;  // N*64 bf16 = f32b region exactly
    float* f4a = f16a;                              // N*4 fp32 (f16a free after gmm16_32)

    const int B = 256;
    const int gridN = DIV_UP(N, B);
    const int gridM = DIV_UP(N, 64);    // tiled matmul / gmm32: 64 nodes/block
    const int grid2 = DIV_UP(2 * N, B); // 2 threads/node gathers
    const int gridF = DIV_UP(N, 128);   // gmm16_32: 128 nodes/block

    // CSR build: hist -> scan -> LDS-ranked partition -> per-bucket (tgt,src-chunk) sort
    zero_int_k<<<DIV_UP(1024, B), B, 0, stream>>>(bhist, 1024);
    bucket_hist_k<<<512, B, 0, stream>>>(col, bhist, E, NB);
    bucket_scan_k<<<1, 256, 0, stream>>>(bhist, bcur, NB);
    partition_k<<<DIV_UP(E, CHUNK_E), PTH, 0, stream>>>(row, col, bcur, part, E, NB);
    csr_build_k<<<NB, 256, 0, stream>>>(part, bcur, cur, dinv, csr, N);

    // L1: y1 = (x@W1)*dinv -> hb16b (bf16) ; gather+bias+relu+scale -> hb16a (bf16)
    matmul_k<128,16,false,false,true,false,true><<<gridM, B, 0, stream>>>(x, W1, nullptr, dinv, hb16b, N);
    gather16_bf_k<<<grid2, B, 0, stream>>>(hb16b, dinv, cur, csr, b1, hb16a, N);

    // L2 fused: gather(hb16a) + matmul 16->32 +b2,relu,*dinv -> hb32 (bf16)
    gmm16_32_k<<<gridF, B, 0, stream>>>(hb16a, dinv, cur, csr, W2, b2, hb32, N);

    // L3 fused: gather(hb32) + matmul 32->64 +b3,relu,*dinv -> hb64 (bf16, f32b region)
    gmm32_64_k<<<gridM, B, 0, stream>>>(hb32, dinv, cur, csr, W3, b3, hb64, N);

    // L4: y4 = h3s@W4 (bf16 in) -> f4a (fp32, f16a region) ; fused gather+pool (adds b4)
    matmul_k<64,4,false,false,false,true,false><<<gridM, B, 0, stream>>>(hb64, W4, nullptr, nullptr, f4a, N);
    pool_init_k<<<DIV_UP(G*4, B), B, 0, stream>>>(pooled, G*4);
    gather4_pool_k<<<gridN, B, 0, stream>>>(f4a, dinv, cur, csr, b4, batch, pooled, N, G);

    // log_softmax
    logsoftmax_k<<<1, 128, 0, stream>>>(pooled, (float*)d_out, G);
}

// Round 14
// 218.652 us; speedup vs baseline: 2.1735x; 1.0436x over previous
//
#include <hip/hip_runtime.h>

#define DIV_UP(a,b) (((a)+(b)-1)/(b))

// bucket = tgt >> 7  (128 nodes per bucket)
constexpr int BSHIFT = 7;
constexpr int BNODES = 128;
constexpr int CHUNK_E = 16384;   // edges per partition block (measured best)
constexpr int PTH = 512;         // partition block threads
constexpr int SCH = 8;           // source chunks for CSR segment ordering
constexpr int SCSH = 14;         // src >> 14 -> chunk id (16K nodes per chunk)

// ---------------- bf16 helpers (storage only; all math fp32) ----------------
__device__ inline unsigned short f2bf(float f) {
    unsigned u = __float_as_uint(f);
    u = u + 0x7FFFu + ((u >> 16) & 1u);   // round-to-nearest-even
    return (unsigned short)(u >> 16);
}
__device__ inline float bflo(unsigned u) { return __uint_as_float(u << 16); }
__device__ inline float bfhi(unsigned u) { return __uint_as_float(u & 0xFFFF0000u); }

// ---------------- CSR build ----------------
__global__ void zero_int_k(int* p, int n) {
    int i = blockIdx.x * blockDim.x + threadIdx.x;
    if (i < n) p[i] = 0;
}

__global__ void bucket_hist_k(const int* __restrict__ col, int* __restrict__ bhist, int E, int nb) {
    __shared__ int lh[1024];
    for (int i = threadIdx.x; i < 1024; i += blockDim.x) lh[i] = 0;
    __syncthreads();
    int stride = gridDim.x * blockDim.x;
    for (int e = blockIdx.x * blockDim.x + threadIdx.x; e < E; e += stride)
        atomicAdd(&lh[col[e] >> BSHIFT], 1);
    __syncthreads();
    for (int i = threadIdx.x; i < nb; i += blockDim.x) {
        int v = lh[i];
        if (v) atomicAdd(&bhist[i], v);
    }
}

__global__ void bucket_scan_k(const int* __restrict__ bhist, int* __restrict__ bcur, int nb) {
    __shared__ int lds[256];
    int base = threadIdx.x * 4;
    int v[4]; int s = 0;
#pragma unroll
    for (int j = 0; j < 4; j++) { v[j] = (base + j < nb) ? bhist[base + j] : 0; s += v[j]; }
    lds[threadIdx.x] = s; __syncthreads();
    for (int off = 1; off < 256; off <<= 1) {
        int t = (threadIdx.x >= off) ? lds[threadIdx.x - off] : 0;
        __syncthreads();
        lds[threadIdx.x] += t;
        __syncthreads();
    }
    int excl = lds[threadIdx.x] - s;
#pragma unroll
    for (int j = 0; j < 4; j++) {
        if (base + j < nb) bcur[base + j] = excl;
        excl += v[j];
    }
}

__global__ void __launch_bounds__(PTH) partition_k(
        const int* __restrict__ row, const int* __restrict__ col,
        int* __restrict__ bcur, int* __restrict__ part, int E, int nb) {
    __shared__ int lh[1024];
    __shared__ int lbase[1024];
    __shared__ int delta[1024];
    __shared__ unsigned sorted[CHUNK_E];
    __shared__ unsigned short bid[CHUNK_E];
    int tid = threadIdx.x;
    for (int i = tid; i < 1024; i += PTH) lh[i] = 0;
    __syncthreads();
    int base = blockIdx.x * CHUNK_E;
    int end = min(E, base + CHUNK_E);
    for (int e = base + tid; e < end; e += PTH)
        atomicAdd(&lh[col[e] >> BSHIFT], 1);
    __syncthreads();
    int v0 = lh[2 * tid], v1 = lh[2 * tid + 1];
    int s = v0 + v1;
    delta[tid] = s;
    __syncthreads();
    for (int off = 1; off < PTH; off <<= 1) {
        int t = (tid >= off) ? delta[tid - off] : 0;
        __syncthreads();
        delta[tid] += t;
        __syncthreads();
    }
    int excl = delta[tid] - s;
    lbase[2 * tid] = excl;
    lbase[2 * tid + 1] = excl + v0;
    __syncthreads();
    for (int i = tid; i < nb; i += PTH) {
        int c = lh[i];
        int g = c ? atomicAdd(&bcur[i], c) : 0;
        delta[i] = g - lbase[i];
    }
    __syncthreads();
    for (int i = tid; i < nb; i += PTH) lh[i] = lbase[i];
    __syncthreads();
    for (int e = base + tid; e < end; e += PTH) {
        int r = row[e], c = col[e];
        int b = c >> BSHIFT;
        int slot = atomicAdd(&lh[b], 1);
        sorted[slot] = (unsigned)((r << BSHIFT) | (c & (BNODES - 1)));
        bid[slot] = (unsigned short)b;
    }
    __syncthreads();
    int cnt = end - base;
    for (int i = tid; i < cnt; i += PTH) {
        int b = bid[i];
        part[delta[b] + i] = (int)sorted[i];
    }
}

__global__ void __launch_bounds__(256) csr_build_k(
        const int* __restrict__ part, const int* __restrict__ bcur,
        int* __restrict__ cur, float* __restrict__ dinv,
        int* __restrict__ csr, int N) {
    __shared__ int cnt[BNODES * SCH];
    __shared__ int scan_t[256];
    __shared__ int ebounds[2];
    int b = blockIdx.x;
    int tid = threadIdx.x;
    if (tid == 0) { ebounds[0] = b ? bcur[b - 1] : 0; ebounds[1] = bcur[b]; }
    for (int i = tid; i < BNODES * SCH; i += 256) cnt[i] = 0;
    __syncthreads();
    int e0 = ebounds[0], e1 = ebounds[1];
    for (int e = e0 + tid; e < e1; e += 256) {
        unsigned v = (unsigned)part[e];
        int cell = (int)(v & (BNODES - 1)) * SCH + (int)(v >> (BSHIFT + SCSH));
        atomicAdd(&cnt[cell], 1);
    }
    __syncthreads();
    int base4 = tid * 4;
    int c0 = cnt[base4], c1 = cnt[base4+1], c2 = cnt[base4+2], c3 = cnt[base4+3];
    int s = c0 + c1 + c2 + c3;
    scan_t[tid] = s;
    __syncthreads();
    for (int off = 1; off < 256; off <<= 1) {
        int t = (tid >= off) ? scan_t[tid - off] : 0;
        __syncthreads();
        scan_t[tid] += t;
        __syncthreads();
    }
    int excl = scan_t[tid] - s;
    cnt[base4]     = excl;
    cnt[base4 + 1] = excl + c0;
    cnt[base4 + 2] = excl + c0 + c1;
    cnt[base4 + 3] = excl + c0 + c1 + c2;
    __syncthreads();
    if (tid < BNODES) {
        int node = b * BNODES + tid;
        int segstart = cnt[tid * SCH];
        int segend   = (tid == BNODES - 1) ? (e1 - e0) : cnt[(tid + 1) * SCH];
        if (node < N) {
            cur[node]  = e0 + segend;
            dinv[node] = rsqrtf(1.0f + (float)(segend - segstart));
        }
    }
    __syncthreads();
    for (int e = e0 + tid; e < e1; e += 256) {
        unsigned v = (unsigned)part[e];
        int cell = (int)(v & (BNODES - 1)) * SCH + (int)(v >> (BSHIFT + SCSH));
        int p = atomicAdd(&cnt[cell], 1);
        csr[e0 + p] = (int)(v >> BSHIFT);
    }
}

// ---------------- gather, bf16 D=16, EPI1; 8 threads/node (4 edge slices) ------------
__global__ void __launch_bounds__(256) gather16_bf_k(
        const unsigned short* __restrict__ hb, const float* __restrict__ dinv,
        const int* __restrict__ cur, const int* __restrict__ csr,
        const float* __restrict__ b, unsigned short* __restrict__ outb, int n) {
    int tid = blockIdx.x * 256 + threadIdx.x;
    int node = tid >> 3, sub = tid & 7;
    int rh = sub & 1, p = sub >> 1;       // row half (16B), edge slice 0..3
    if (node >= n) return;
    const uint4* hb4 = reinterpret_cast<const uint4*>(hb);
    float a0 = 0.f, a1 = 0.f, a2 = 0.f, a3 = 0.f, a4 = 0.f, a5 = 0.f, a6 = 0.f, a7 = 0.f;
    if (p == 0) {
        uint4 sv = hb4[(size_t)node * 2 + rh];
        a0 = bflo(sv.x); a1 = bfhi(sv.x); a2 = bflo(sv.y); a3 = bfhi(sv.y);
        a4 = bflo(sv.z); a5 = bfhi(sv.z); a6 = bflo(sv.w); a7 = bfhi(sv.w);
    }
    int e0 = node ? cur[node - 1] : 0;
    int e1 = cur[node];
    int e = e0 + p;
    for (; e + 12 < e1; e += 16) {        // 4 loads in flight per slice
        int s0 = csr[e], s1 = csr[e+4], s2 = csr[e+8], s3 = csr[e+12];
        uint4 v0 = hb4[(size_t)s0 * 2 + rh];
        uint4 v1 = hb4[(size_t)s1 * 2 + rh];
        uint4 v2 = hb4[(size_t)s2 * 2 + rh];
        uint4 v3 = hb4[(size_t)s3 * 2 + rh];
        a0 += (bflo(v0.x) + bflo(v1.x)) + (bflo(v2.x) + bflo(v3.x));
        a1 += (bfhi(v0.x) + bfhi(v1.x)) + (bfhi(v2.x) + bfhi(v3.x));
        a2 += (bflo(v0.y) + bflo(v1.y)) + (bflo(v2.y) + bflo(v3.y));
        a3 += (bfhi(v0.y) + bfhi(v1.y)) + (bfhi(v2.y) + bfhi(v3.y));
        a4 += (bflo(v0.z) + bflo(v1.z)) + (bflo(v2.z) + bflo(v3.z));
        a5 += (bfhi(v0.z) + bfhi(v1.z)) + (bfhi(v2.z) + bfhi(v3.z));
        a6 += (bflo(v0.w) + bflo(v1.w)) + (bflo(v2.w) + bflo(v3.w));
        a7 += (bfhi(v0.w) + bfhi(v1.w)) + (bfhi(v2.w) + bfhi(v3.w));
    }
    for (; e < e1; e += 4) {
        uint4 v = hb4[(size_t)csr[e] * 2 + rh];
        a0 += bflo(v.x); a1 += bfhi(v.x); a2 += bflo(v.y); a3 += bfhi(v.y);
        a4 += bflo(v.z); a5 += bfhi(v.z); a6 += bflo(v.w); a7 += bfhi(v.w);
    }
    // reduce over edge slices (lanes differing in bits 1,2 of tid)
    a0 += __shfl_xor(a0, 2); a1 += __shfl_xor(a1, 2); a2 += __shfl_xor(a2, 2); a3 += __shfl_xor(a3, 2);
    a4 += __shfl_xor(a4, 2); a5 += __shfl_xor(a5, 2); a6 += __shfl_xor(a6, 2); a7 += __shfl_xor(a7, 2);
    a0 += __shfl_xor(a0, 4); a1 += __shfl_xor(a1, 4); a2 += __shfl_xor(a2, 4); a3 += __shfl_xor(a3, 4);
    a4 += __shfl_xor(a4, 4); a5 += __shfl_xor(a5, 4); a6 += __shfl_xor(a6, 4); a7 += __shfl_xor(a7, 4);
    if (p != 0) return;
    float di = dinv[node];
    int bo = rh * 8;
    a0 = fmaxf(a0 * di + b[bo+0], 0.f) * di; a1 = fmaxf(a1 * di + b[bo+1], 0.f) * di;
    a2 = fmaxf(a2 * di + b[bo+2], 0.f) * di; a3 = fmaxf(a3 * di + b[bo+3], 0.f) * di;
    a4 = fmaxf(a4 * di + b[bo+4], 0.f) * di; a5 = fmaxf(a5 * di + b[bo+5], 0.f) * di;
    a6 = fmaxf(a6 * di + b[bo+6], 0.f) * di; a7 = fmaxf(a7 * di + b[bo+7], 0.f) * di;
    uint4 pk;
    pk.x = (unsigned)f2bf(a0) | ((unsigned)f2bf(a1) << 16);
    pk.y = (unsigned)f2bf(a2) | ((unsigned)f2bf(a3) << 16);
    pk.z = (unsigned)f2bf(a4) | ((unsigned)f2bf(a5) << 16);
    pk.w = (unsigned)f2bf(a6) | ((unsigned)f2bf(a7) << 16);
    reinterpret_cast<uint4*>(outb)[(size_t)node * 2 + rh] = pk;
}

// ---------------- FUSED gather(D=16) + matmul 16->32 ; 4 thr/node, TN=64 --------------
__global__ void __launch_bounds__(256) gmm16_32_k(
        const unsigned short* __restrict__ hb, const float* __restrict__ dinv,
        const int* __restrict__ cur, const int* __restrict__ csr,
        const float* __restrict__ W, const float* __restrict__ b,
        unsigned short* __restrict__ yb, int n) {
    constexpr int TN = 64, RS = 20;
    __shared__ float xs[TN * RS];
    __shared__ float Ws[16 * 32];
    __shared__ float bs[32];
    for (int i = threadIdx.x; i < 16 * 32; i += 256) Ws[i] = W[i];
    if (threadIdx.x < 32) bs[threadIdx.x] = b[threadIdx.x];
    int base = blockIdx.x * TN;
    {
        int nl = threadIdx.x >> 2, sub = threadIdx.x & 3;
        int rh = sub & 1, p = sub >> 1;   // row half, edge parity
        int node = base + nl;
        if (node < n) {
            const uint4* hb4 = reinterpret_cast<const uint4*>(hb);
            float a0 = 0.f, a1 = 0.f, a2 = 0.f, a3 = 0.f, a4 = 0.f, a5 = 0.f, a6 = 0.f, a7 = 0.f;
            if (p == 0) {
                uint4 sv = hb4[(size_t)node * 2 + rh];
                a0 = bflo(sv.x); a1 = bfhi(sv.x); a2 = bflo(sv.y); a3 = bfhi(sv.y);
                a4 = bflo(sv.z); a5 = bfhi(sv.z); a6 = bflo(sv.w); a7 = bfhi(sv.w);
            }
            int e0 = node ? cur[node - 1] : 0;
            int e1 = cur[node];
            int e = e0 + p;
            for (; e + 6 < e1; e += 8) {
                int s0 = csr[e], s1 = csr[e+2], s2 = csr[e+4], s3 = csr[e+6];
                uint4 v0 = hb4[(size_t)s0 * 2 + rh];
                uint4 v1 = hb4[(size_t)s1 * 2 + rh];
                uint4 v2 = hb4[(size_t)s2 * 2 + rh];
                uint4 v3 = hb4[(size_t)s3 * 2 + rh];
                a0 += (bflo(v0.x) + bflo(v1.x)) + (bflo(v2.x) + bflo(v3.x));
                a1 += (bfhi(v0.x) + bfhi(v1.x)) + (bfhi(v2.x) + bfhi(v3.x));
                a2 += (bflo(v0.y) + bflo(v1.y)) + (bflo(v2.y) + bflo(v3.y));
                a3 += (bfhi(v0.y) + bfhi(v1.y)) + (bfhi(v2.y) + bfhi(v3.y));
                a4 += (bflo(v0.z) + bflo(v1.z)) + (bflo(v2.z) + bflo(v3.z));
                a5 += (bfhi(v0.z) + bfhi(v1.z)) + (bfhi(v2.z) + bfhi(v3.z));
                a6 += (bflo(v0.w) + bflo(v1.w)) + (bflo(v2.w) + bflo(v3.w));
                a7 += (bfhi(v0.w) + bfhi(v1.w)) + (bfhi(v2.w) + bfhi(v3.w));
            }
            for (; e < e1; e += 2) {
                uint4 v = hb4[(size_t)csr[e] * 2 + rh];
                a0 += bflo(v.x); a1 += bfhi(v.x); a2 += bflo(v.y); a3 += bfhi(v.y);
                a4 += bflo(v.z); a5 += bfhi(v.z); a6 += bflo(v.w); a7 += bfhi(v.w);
            }
            a0 += __shfl_xor(a0, 2); a1 += __shfl_xor(a1, 2); a2 += __shfl_xor(a2, 2); a3 += __shfl_xor(a3, 2);
            a4 += __shfl_xor(a4, 2); a5 += __shfl_xor(a5, 2); a6 += __shfl_xor(a6, 2); a7 += __shfl_xor(a7, 2);
            if (p == 0) {
                float di = dinv[node];
                float* dst = &xs[nl * RS + rh * 8];
                dst[0] = a0*di; dst[1] = a1*di; dst[2] = a2*di; dst[3] = a3*di;
                dst[4] = a4*di; dst[5] = a5*di; dst[6] = a6*di; dst[7] = a7*di;
            }
        }
    }
    __syncthreads();
    // matmul: 4 threads/node, 8 outputs each
    int nl = threadIdx.x >> 2, g = threadIdx.x & 3;
    int node = base + nl;
    if (node >= n) return;
    int j0 = g * 8;
    float acc[8];
#pragma unroll
    for (int j = 0; j < 8; j++) acc[j] = 0.f;
    const float* xrow = &xs[nl * RS];
#pragma unroll
    for (int k4 = 0; k4 < 4; k4++) {
        float4 xv = *reinterpret_cast<const float4*>(&xrow[k4 * 4]);
        float xk[4] = {xv.x, xv.y, xv.z, xv.w};
#pragma unroll
        for (int kk = 0; kk < 4; kk++) {
            const float* wrow = &Ws[(k4*4+kk) * 32 + j0];
#pragma unroll
            for (int j = 0; j < 8; j++) acc[j] += xk[kk] * wrow[j];
        }
    }
    float di = dinv[node];
    float o[8];
#pragma unroll
    for (int j = 0; j < 8; j++) o[j] = fmaxf(acc[j] + bs[j0 + j], 0.f) * di;
    uint4 pk;
    pk.x = (unsigned)f2bf(o[0]) | ((unsigned)f2bf(o[1]) << 16);
    pk.y = (unsigned)f2bf(o[2]) | ((unsigned)f2bf(o[3]) << 16);
    pk.z = (unsigned)f2bf(o[4]) | ((unsigned)f2bf(o[5]) << 16);
    pk.w = (unsigned)f2bf(o[6]) | ((unsigned)f2bf(o[7]) << 16);
    *reinterpret_cast<uint4*>(yb + (size_t)node * 32 + j0) = pk;
}

// ---------------- FUSED gather(D=32) + matmul 32->64 ; 8 thr/node, TN=32 --------------
__global__ void __launch_bounds__(256) gmm32_64_k(
        const unsigned short* __restrict__ hb, const float* __restrict__ dinv,
        const int* __restrict__ cur, const int* __restrict__ csr,
        const float* __restrict__ W, const float* __restrict__ b,
        unsigned short* __restrict__ yb, int n) {
    constexpr int TN = 32, RS = 36;
    __shared__ float xs[TN * RS];     // 4.6 KB
    __shared__ float Ws[32 * 64];     // 8 KB
    __shared__ float bs[64];
    for (int i = threadIdx.x; i < 32 * 64; i += 256) Ws[i] = W[i];
    if (threadIdx.x < 64) bs[threadIdx.x] = b[threadIdx.x];
    int base = blockIdx.x * TN;
    {
        int nl = threadIdx.x >> 3, sub = threadIdx.x & 7;
        int rq = sub & 3, p = sub >> 2;   // row quarter (16B), edge parity
        int node = base + nl;
        if (node < n) {
            const uint4* hb4 = reinterpret_cast<const uint4*>(hb);
            float a0 = 0.f, a1 = 0.f, a2 = 0.f, a3 = 0.f, a4 = 0.f, a5 = 0.f, a6 = 0.f, a7 = 0.f;
            if (p == 0) {
                uint4 sv = hb4[(size_t)node * 4 + rq];
                a0 = bflo(sv.x); a1 = bfhi(sv.x); a2 = bflo(sv.y); a3 = bfhi(sv.y);
                a4 = bflo(sv.z); a5 = bfhi(sv.z); a6 = bflo(sv.w); a7 = bfhi(sv.w);
            }
            int e0 = node ? cur[node - 1] : 0;
            int e1 = cur[node];
            int e = e0 + p;
            for (; e + 6 < e1; e += 8) {
                int s0 = csr[e], s1 = csr[e+2], s2 = csr[e+4], s3 = csr[e+6];
                uint4 v0 = hb4[(size_t)s0 * 4 + rq];
                uint4 v1 = hb4[(size_t)s1 * 4 + rq];
                uint4 v2 = hb4[(size_t)s2 * 4 + rq];
                uint4 v3 = hb4[(size_t)s3 * 4 + rq];
                a0 += (bflo(v0.x) + bflo(v1.x)) + (bflo(v2.x) + bflo(v3.x));
                a1 += (bfhi(v0.x) + bfhi(v1.x)) + (bfhi(v2.x) + bfhi(v3.x));
                a2 += (bflo(v0.y) + bflo(v1.y)) + (bflo(v2.y) + bflo(v3.y));
                a3 += (bfhi(v0.y) + bfhi(v1.y)) + (bfhi(v2.y) + bfhi(v3.y));
                a4 += (bflo(v0.z) + bflo(v1.z)) + (bflo(v2.z) + bflo(v3.z));
                a5 += (bfhi(v0.z) + bfhi(v1.z)) + (bfhi(v2.z) + bfhi(v3.z));
                a6 += (bflo(v0.w) + bflo(v1.w)) + (bflo(v2.w) + bflo(v3.w));
                a7 += (bfhi(v0.w) + bfhi(v1.w)) + (bfhi(v2.w) + bfhi(v3.w));
            }
            for (; e < e1; e += 2) {
                uint4 v = hb4[(size_t)csr[e] * 4 + rq];
                a0 += bflo(v.x); a1 += bfhi(v.x); a2 += bflo(v.y); a3 += bfhi(v.y);
                a4 += bflo(v.z); a5 += bfhi(v.z); a6 += bflo(v.w); a7 += bfhi(v.w);
            }
            a0 += __shfl_xor(a0, 4); a1 += __shfl_xor(a1, 4); a2 += __shfl_xor(a2, 4); a3 += __shfl_xor(a3, 4);
            a4 += __shfl_xor(a4, 4); a5 += __shfl_xor(a5, 4); a6 += __shfl_xor(a6, 4); a7 += __shfl_xor(a7, 4);
            if (p == 0) {
                float di = dinv[node];
                float* dst = &xs[nl * RS + rq * 8];
                dst[0] = a0*di; dst[1] = a1*di; dst[2] = a2*di; dst[3] = a3*di;
                dst[4] = a4*di; dst[5] = a5*di; dst[6] = a6*di; dst[7] = a7*di;
            }
        }
    }
    __syncthreads();
    // matmul: 8 threads/node, 8 outputs each
    int nl = threadIdx.x >> 3, g = threadIdx.x & 7;
    int node = base + nl;
    if (node >= n) return;
    int j0 = g * 8;
    float acc[8];
#pragma unroll
    for (int j = 0; j < 8; j++) acc[j] = 0.f;
    const float* xrow = &xs[nl * RS];
#pragma unroll
    for (int k4 = 0; k4 < 8; k4++) {
        float4 xv = *reinterpret_cast<const float4*>(&xrow[k4 * 4]);
        float xk[4] = {xv.x, xv.y, xv.z, xv.w};
#pragma unroll
        for (int kk = 0; kk < 4; kk++) {
            const float* wrow = &Ws[(k4*4+kk) * 64 + j0];
#pragma unroll
            for (int j = 0; j < 8; j++) acc[j] += xk[kk] * wrow[j];
        }
    }
    float di = dinv[node];
    float o[8];
#pragma unroll
    for (int j = 0; j < 8; j++) o[j] = fmaxf(acc[j] + bs[j0 + j], 0.f) * di;
    uint4 pk;
    pk.x = (unsigned)f2bf(o[0]) | ((unsigned)f2bf(o[1]) << 16);
    pk.y = (unsigned)f2bf(o[2]) | ((unsigned)f2bf(o[3]) << 16);
    pk.z = (unsigned)f2bf(o[4]) | ((unsigned)f2bf(o[5]) << 16);
    pk.w = (unsigned)f2bf(o[6]) | ((unsigned)f2bf(o[7]) << 16);
    *reinterpret_cast<uint4*>(yb + (size_t)node * 64 + j0) = pk;
}

// ---------------- pooling helpers ----------------
__device__ inline unsigned fkey(float x) {
    unsigned u = __float_as_uint(x);
    return (u & 0x80000000u) ? ~u : (u | 0x80000000u);
}
__device__ inline float funkey(unsigned k) {
    unsigned u = (k & 0x80000000u) ? (k & 0x7FFFFFFFu) : ~k;
    return __uint_as_float(u);
}

// ---------------- fused final gather (D=4) + segment-max pool ; 8 thr/node -----------
__global__ void gather4_pool_k(const float* __restrict__ hs, const float* __restrict__ dinv,
                               const int* __restrict__ cur, const int* __restrict__ csr,
                               const float* __restrict__ b4, const int* __restrict__ batch,
                               unsigned* __restrict__ pooled, int n, int num_graphs) {
    __shared__ unsigned lds[128 * 4];
    for (int i = threadIdx.x; i < num_graphs * 4; i += blockDim.x) lds[i] = 0u;
    __syncthreads();
    int tid = blockIdx.x * blockDim.x + threadIdx.x;
    int node = tid >> 3, p = tid & 7;     // 8 edge slices
    if (node < n) {
        float4 acc = make_float4(0.f, 0.f, 0.f, 0.f);
        if (p == 0) acc = reinterpret_cast<const float4*>(hs)[node];
        int e0 = node ? cur[node - 1] : 0;
        int e1 = cur[node];
        int e = e0 + p;
        for (; e + 8 < e1; e += 16) {
            float4 v0 = reinterpret_cast<const float4*>(hs)[csr[e]];
            float4 v1 = reinterpret_cast<const float4*>(hs)[csr[e + 8]];
            acc.x += v0.x + v1.x; acc.y += v0.y + v1.y;
            acc.z += v0.z + v1.z; acc.w += v0.w + v1.w;
        }
        for (; e < e1; e += 8) {
            float4 v0 = reinterpret_cast<const float4*>(hs)[csr[e]];
            acc.x += v0.x; acc.y += v0.y; acc.z += v0.z; acc.w += v0.w;
        }
#pragma unroll
        for (int m = 1; m <= 4; m <<= 1) {
            acc.x += __shfl_xor(acc.x, m);
            acc.y += __shfl_xor(acc.y, m);
            acc.z += __shfl_xor(acc.z, m);
            acc.w += __shfl_xor(acc.w, m);
        }
        if (p == 0) {
            float di = dinv[node];
            int g = batch[node];
            atomicMax(&lds[g*4+0], fkey(acc.x * di + b4[0]));
            atomicMax(&lds[g*4+1], fkey(acc.y * di + b4[1]));
            atomicMax(&lds[g*4+2], fkey(acc.z * di + b4[2]));
            atomicMax(&lds[g*4+3], fkey(acc.w * di + b4[3]));
        }
    }
    __syncthreads();
    for (int i2 = threadIdx.x; i2 < num_graphs * 4; i2 += blockDim.x) {
        unsigned k = lds[i2];
        if (k) atomicMax(&pooled[i2], k);
    }
}

__global__ void pool_init_k(unsigned* pooled, int total) {
    int i = blockIdx.x * blockDim.x + threadIdx.x;
    if (i < total) pooled[i] = 0u;
}

__global__ void logsoftmax_k(const unsigned* __restrict__ pooled, float* __restrict__ out, int G) {
    int g = blockIdx.x * blockDim.x + threadIdx.x;
    if (g >= G) return;
    float v[4];
#pragma unroll
    for (int j = 0; j < 4; j++) v[j] = funkey(pooled[g*4+j]);
    float m = fmaxf(fmaxf(v[0], v[1]), fmaxf(v[2], v[3]));
    float s = 0.f;
#pragma unroll
    for (int j = 0; j < 4; j++) s += expf(v[j] - m);
    float l = logf(s);
#pragma unroll
    for (int j = 0; j < 4; j++) out[g*4+j] = v[j] - m - l;
}

// ---------------- LDS-tiled skinny matmul with optional bf16 in/out ----------------
template<int IN, int OUT, bool RELU, bool BIAS, bool SCALE, bool IBF, bool OBF>
__global__ void __launch_bounds__(256) matmul_k(
        const void* __restrict__ xv, const float* __restrict__ W,
        const float* __restrict__ b, const float* __restrict__ dinv,
        void* __restrict__ yv, int n) {
    constexpr int TN  = 64;
    constexpr int RS  = IN + 4;
    constexpr int OPT = OUT / 4;
    constexpr int NQ  = IN / 4;
    __shared__ float xs[TN * RS];
    __shared__ float Ws[IN * OUT];
    __shared__ float bs[OUT];

    for (int i = threadIdx.x; i < IN * OUT; i += 256) Ws[i] = W[i];
    if (BIAS) for (int i = threadIdx.x; i < OUT; i += 256) bs[i] = b[i];

    int base = blockIdx.x * TN;
    if constexpr (!IBF) {
        const float* x = (const float*)xv;
        for (int i = threadIdx.x; i < TN * NQ; i += 256) {
            int r = i / NQ, c = i % NQ;
            float4 v = make_float4(0.f, 0.f, 0.f, 0.f);
            if (base + r < n) v = reinterpret_cast<const float4*>(x + (size_t)(base + r) * IN)[c];
            *reinterpret_cast<float4*>(&xs[r * RS + c * 4]) = v;
        }
    } else {
        constexpr int NU = IN / 8;
        const uint4* x = (const uint4*)xv;
        for (int i = threadIdx.x; i < TN * NU; i += 256) {
            int r = i / NU, c = i % NU;
            uint4 v = make_uint4(0u, 0u, 0u, 0u);
            if (base + r < n) v = x[(size_t)(base + r) * NU + c];
            float* dst = &xs[r * RS + c * 8];
            dst[0] = bflo(v.x); dst[1] = bfhi(v.x);
            dst[2] = bflo(v.y); dst[3] = bfhi(v.y);
            dst[4] = bflo(v.z); dst[5] = bfhi(v.z);
            dst[6] = bflo(v.w); dst[7] = bfhi(v.w);
        }
    }
    __syncthreads();

    int node = threadIdx.x >> 2;
    int g    = threadIdx.x & 3;
    int j0   = g * OPT;
    int gnode = base + node;
    if (gnode >= n) return;

    float acc[OPT];
#pragma unroll
    for (int jj = 0; jj < OPT; jj++) acc[jj] = 0.f;

    const float* xrow = &xs[node * RS];
#pragma unroll
    for (int k4 = 0; k4 < NQ; k4++) {
        float4 xvv = *reinterpret_cast<const float4*>(&xrow[k4 * 4]);
        float xk[4] = {xvv.x, xvv.y, xvv.z, xvv.w};
#pragma unroll
        for (int kk = 0; kk < 4; kk++) {
            const float* wrow = &Ws[(k4 * 4 + kk) * OUT + j0];
#pragma unroll
            for (int jj = 0; jj < OPT; jj++)
                acc[jj] += xk[kk] * wrow[jj];
        }
    }

    float di = SCALE ? dinv[gnode] : 1.f;
    float vout[OPT];
#pragma unroll
    for (int jj = 0; jj < OPT; jj++) {
        float v = acc[jj] + (BIAS ? bs[j0 + jj] : 0.f);
        if (RELU) v = fmaxf(v, 0.f);
        if (SCALE) v *= di;
        vout[jj] = v;
    }
    if constexpr (OBF) {
        unsigned short* yr = (unsigned short*)yv + (size_t)gnode * OUT + j0;
        if constexpr (OPT % 8 == 0) {
#pragma unroll
            for (int q = 0; q < OPT / 8; q++) {
                uint4 pk;
                pk.x = (unsigned)f2bf(vout[q*8+0]) | ((unsigned)f2bf(vout[q*8+1]) << 16);
                pk.y = (unsigned)f2bf(vout[q*8+2]) | ((unsigned)f2bf(vout[q*8+3]) << 16);
                pk.z = (unsigned)f2bf(vout[q*8+4]) | ((unsigned)f2bf(vout[q*8+5]) << 16);
                pk.w = (unsigned)f2bf(vout[q*8+6]) | ((unsigned)f2bf(vout[q*8+7]) << 16);
                reinterpret_cast<uint4*>(yr)[q] = pk;
            }
        } else {
            uint2 pk;
            pk.x = (unsigned)f2bf(vout[0]) | ((unsigned)f2bf(vout[1]) << 16);
            pk.y = (unsigned)f2bf(vout[2]) | ((unsigned)f2bf(vout[3]) << 16);
            *reinterpret_cast<uint2*>(yr) = pk;
        }
    } else {
        float* yr = (float*)yv + (size_t)gnode * OUT + j0;
        if (OPT % 4 == 0) {
#pragma unroll
            for (int q = 0; q < OPT / 4; q++)
                *reinterpret_cast<float4*>(yr + q * 4) =
                    make_float4(vout[q*4+0], vout[q*4+1], vout[q*4+2], vout[q*4+3]);
        } else {
#pragma unroll
            for (int jj = 0; jj < OPT; jj++) yr[jj] = vout[jj];
        }
    }
}

// ---------------- launch ----------------
extern "C" void kernel_launch(void* const* d_in, const int* in_sizes, int n_in,
                              void* d_out, int out_size, void* d_ws, size_t ws_size,
                              hipStream_t stream) {
    const float* x     = (const float*)d_in[0];
    const int*   ei    = (const int*)d_in[1];
    const int*   batch = (const int*)d_in[2];
    const float* W1 = (const float*)d_in[3];
    const float* b1 = (const float*)d_in[4];
    const float* W2 = (const float*)d_in[5];
    const float* b2 = (const float*)d_in[6];
    const float* W3 = (const float*)d_in[7];
    const float* b3 = (const float*)d_in[8];
    const float* W4 = (const float*)d_in[9];
    const float* b4 = (const float*)d_in[10];

    const int N = in_sizes[2];          // 100000
    const int E = in_sizes[1] / 2;      // 3.2M
    const int G = 128;
    const int* row = ei;
    const int* col = ei + E;
    const int NB = DIV_UP(N, BNODES);   // 782 buckets

    // workspace layout
    float* ws    = (float*)d_ws;
    float* dinv  = ws;                              // N floats
    int*   cur   = (int*)(dinv + N);                // N ints
    int*   bhist = cur + N;                         // 1024 ints
    int*   bcur  = bhist + 1024;                    // 1024 ints
    int*   csr   = bcur + 1024;                     // E ints
    float* f16a  = (float*)(csr + E);               // N*16 floats region
    float* f16b  = f16a + (size_t)N * 16;           // N*16 floats region
    float* f32a  = f16b + (size_t)N * 16;           // N*32 floats region
    float* f32b  = f32a + (size_t)N * 32;           // N*32 floats region
    unsigned* pooled = (unsigned*)(f32b + (size_t)N * 32);  // 512
    int* part = (int*)f32a;                         // dead after csr_build
    unsigned short* hb16a = (unsigned short*)f16a;  // N*16 bf16
    unsigned short* hb16b = (unsigned short*)f16b;  // N*16 bf16
    unsigned short* hb32  = (unsigned short*)f32a;  // N*32 bf16 (after part dead)
    unsigned short* hb64  = (unsigned short*)f32b;  // N*64 bf16 = f32b region
    float* f4a = f16a;                              // N*4 fp32 (f16a free after gmm16_32)

    const int B = 256;
    const int gridM  = DIV_UP(N, 64);     // matmul_k / gmm16_32: 64 nodes/block
    const int grid32 = DIV_UP(N, 32);     // gmm32_64: 32 nodes/block
    const int grid8  = DIV_UP(8 * N, B);  // 8 threads/node kernels

    // CSR build: hist -> scan -> LDS-ranked partition -> per-bucket (tgt,src-chunk) sort
    zero_int_k<<<DIV_UP(1024, B), B, 0, stream>>>(bhist, 1024);
    bucket_hist_k<<<512, B, 0, stream>>>(col, bhist, E, NB);
    bucket_scan_k<<<1, 256, 0, stream>>>(bhist, bcur, NB);
    partition_k<<<DIV_UP(E, CHUNK_E), PTH, 0, stream>>>(row, col, bcur, part, E, NB);
    csr_build_k<<<NB, 256, 0, stream>>>(part, bcur, cur, dinv, csr, N);

    // L1: y1 = (x@W1)*dinv -> hb16b (bf16) ; gather+bias+relu+scale -> hb16a (bf16)
    matmul_k<128,16,false,false,true,false,true><<<gridM, B, 0, stream>>>(x, W1, nullptr, dinv, hb16b, N);
    gather16_bf_k<<<grid8, B, 0, stream>>>(hb16b, dinv, cur, csr, b1, hb16a, N);

    // L2 fused: gather(hb16a) + matmul 16->32 +b2,relu,*dinv -> hb32 (bf16)
    gmm16_32_k<<<gridM, B, 0, stream>>>(hb16a, dinv, cur, csr, W2, b2, hb32, N);

    // L3 fused: gather(hb32) + matmul 32->64 +b3,relu,*dinv -> hb64 (bf16)
    gmm32_64_k<<<grid32, B, 0, stream>>>(hb32, dinv, cur, csr, W3, b3, hb64, N);

    // L4: y4 = h3s@W4 (bf16 in) -> f4a (fp32) ; fused gather+pool (adds b4)
    matmul_k<64,4,false,false,false,true,false><<<gridM, B, 0, stream>>>(hb64, W4, nullptr, nullptr, f4a, N);
    pool_init_k<<<DIV_UP(G*4, B), B, 0, stream>>>(pooled, G*4);
    gather4_pool_k<<<grid8, B, 0, stream>>>(f4a, dinv, cur, csr, b4, batch, pooled, N, G);

    // log_softmax
    logsoftmax_k<<<1, 128, 0, stream>>>(pooled, (float*)d_out, G);
}